// Round 8
// baseline (249.665 us; speedup 1.0000x reference)
//
#include <hip/hip_runtime.h>

// Round 18: DIAGNOSTIC SPLIT. Three attacks on pairA's 46-50us all failed
// identically; counters can't attribute it between {ext gather, tile path}.
// conv1-ext moves back to its own order-free dispatch k_extA2 (4096 waves,
// 1 entry/wave, 4-acc FMA chains) -> pairA is tile-only. pairB keeps merged
// ext (control). The two dispatch durations attribute the 48us decisively.
// Semantics unchanged: atomic Sum/SumSq merge is order-free (R15 scheme).

typedef short bf16x4 __attribute__((ext_vector_type(4)));
typedef short bf16x8 __attribute__((ext_vector_type(8)));
typedef float f32x16 __attribute__((ext_vector_type(16)));

#define ROWM 0xFFFFF
#define RFLAG (1 << 30)

__device__ __forceinline__ short f2bf(float f) {
    unsigned u = __float_as_uint(f);
    u += 0x7fffu + ((u >> 16) & 1u);
    return (short)(u >> 16);
}
__device__ __forceinline__ float bf2f(short s) {
    return __uint_as_float(((unsigned)(unsigned short)s) << 16);
}

// ---------------- setup: geometry + {wupp, f1bf} pack (vec8) ----------------
__global__ __launch_bounds__(256) void k_setup(
    const float* __restrict__ w_up, const float* __restrict__ f1,
    const int* __restrict__ up_kidx,
    short* __restrict__ wupp, short* __restrict__ f1bf,
    int* __restrict__ pmask, int* __restrict__ perm_rows,
    int* __restrict__ rank, int* __restrict__ cnt,
    int n1, int nbGeom)
{
    int tid = threadIdx.x;
    int bid = blockIdx.x;
    if (bid < nbGeom) {
        int p = bid * 256 + tid;
        if (p >= n1) return;
        int4 kd = *(const int4*)(up_kidx + 4 * p);
        int a = kd.x * 4 + 0, b = kd.y * 4 + 1, c = kd.z * 4 + 2, d = kd.w * 4 + 3;
        int t;
        if (a > b) { t = a; a = b; b = t; }
        if (c > d) { t = c; c = d; d = t; }
        if (a > c) { t = a; a = c; c = t; }
        if (b > d) { t = b; b = d; d = t; }
        if (b > c) { t = b; b = c; c = t; }
        perm_rows[4 * p + 0] = 4 * p + (a & 3);
        perm_rows[4 * p + 1] = 4 * p + (b & 3);
        perm_rows[4 * p + 2] = 4 * p + (c & 3);
        perm_rows[4 * p + 3] = 4 * p + (d & 3);
        int mask = (1 << (a >> 2)) | (1 << (b >> 2)) | (1 << (c >> 2)) | (1 << (d >> 2));
        pmask[p] = mask;
        rank[p] = atomicAdd(&cnt[mask], 1);
    } else {
        const int nup8 = 8192;
        int tot = nup8 + n1 * 16;
        int gs = (gridDim.x - nbGeom) * 256;
        for (int e8 = (bid - nbGeom) * 256 + tid; e8 < tot; e8 += gs) {
            if (e8 < nup8) {        // Wcat[128][512] -> [ks8][nt16][64][8]
                int l = e8 & 63, nt = (e8 >> 6) & 15, ks = e8 >> 10;
                int kb = ks * 16 + (l >> 5) * 8;
                int col = nt * 32 + (l & 31);
                const float* src = w_up + (size_t)(col >> 6) * 8192 + (size_t)kb * 64 + (col & 63);
                bf16x8 o;
                #pragma unroll
                for (int j = 0; j < 8; ++j) o[j] = f2bf(src[(size_t)j * 64]);
                *(bf16x8*)(wupp + (size_t)e8 * 8) = o;
            } else {
                int g = e8 - nup8;
                const float* src = f1 + (size_t)g * 8;
                float4 a = *(const float4*)src;
                float4 b = *(const float4*)(src + 4);
                bf16x8 o;
                o[0] = f2bf(a.x); o[1] = f2bf(a.y); o[2] = f2bf(a.z); o[3] = f2bf(a.w);
                o[4] = f2bf(b.x); o[5] = f2bf(b.y); o[6] = f2bf(b.z); o[7] = f2bf(b.w);
                *(bf16x8*)(f1bf + (size_t)g * 8) = o;
            }
        }
    }
}

// ------- dense up-GEMM + masked BN stats; block 0 = scan; aux role-blocks ----
__global__ __launch_bounds__(256) void k_up(
    const short* __restrict__ f1bf, const short* __restrict__ wupp,
    const int* __restrict__ pmask, const int* __restrict__ cnt,
    const int* __restrict__ rank, int* __restrict__ perm_par,
    int4* __restrict__ tiles, int* __restrict__ ntl,
    short* __restrict__ yup8, float* __restrict__ stats,
    const float* __restrict__ w1, const float* __restrict__ w2,
    short* __restrict__ w1p, short* __restrict__ w2p,
    const int* __restrict__ nbr, int2* __restrict__ ext,
    int* __restrict__ extc, unsigned* __restrict__ flagbits,
    float* __restrict__ y1, float* __restrict__ y2,
    int n1, int n2, int nt, int nbExt)
{
    int gemmEnd = 1 + 2 * nt;
    if (blockIdx.x == 0) {
        __shared__ int sA[256], sB[256], bb[256];
        int t = threadIdx.x;
        int c = cnt[t], tc = (c + 31) >> 5;
        sA[t] = c; sB[t] = tc;
        __syncthreads();
        for (int off = 1; off < 256; off <<= 1) {
            int a = (t >= off) ? sA[t - off] : 0;
            int b = (t >= off) ? sB[t - off] : 0;
            __syncthreads();
            sA[t] += a; sB[t] += b;
            __syncthreads();
        }
        int base = sA[t] - c, toff = sB[t] - tc;
        bb[t] = base;
        for (int j = 0; j < tc; ++j) tiles[toff + j] = make_int4(t, base, j * 32, c);
        if (t == 255) ntl[0] = sB[255];
        __syncthreads();
        for (int p = t; p < n1; p += 256)
            perm_par[bb[pmask[p]] + rank[p]] = p;
        return;
    }
    if (blockIdx.x >= gemmEnd) {
        int ab = blockIdx.x - gemmEnd;
        int tid = threadIdx.x;
        if (ab < 256) {
            long long tot = (long long)n2 * 16;
            float4 z = make_float4(0.f, 0.f, 0.f, 0.f);
            for (long long e = (long long)ab * 256 + tid; e < tot; e += 256LL * 256) {
                ((float4*)y1)[e] = z;
                ((float4*)y2)[e] = z;
            }
        } else if (ab < 320) {
            const int nw18 = 27648, tot = 27648 + 13824;
            for (int e8 = (ab - 256) * 256 + tid; e8 < tot; e8 += 64 * 256) {
                if (e8 < nw18) {     // [27][8][2][64][8]
                    int l = e8 & 63, ch = (e8 >> 6) & 1, ks = (e8 >> 7) & 7, t = e8 >> 10;
                    int kb = ks * 16 + (l >> 5) * 8;
                    int col = ch * 32 + (l & 31);
                    const float* src = w1 + (size_t)t * 8192 + (size_t)kb * 64 + col;
                    bf16x8 o;
                    #pragma unroll
                    for (int j = 0; j < 8; ++j) o[j] = f2bf(src[(size_t)j * 64]);
                    *(bf16x8*)(w1p + (size_t)e8 * 8) = o;
                } else {             // [27][4][2][64][8]
                    int g = e8 - nw18;
                    int l = g & 63, ch = (g >> 6) & 1, ks = (g >> 7) & 3, t = g >> 9;
                    int kb = ks * 16 + (l >> 5) * 8;
                    int col = ch * 32 + (l & 31);
                    const float* src = w2 + (size_t)t * 4096 + (size_t)kb * 64 + col;
                    bf16x8 o;
                    #pragma unroll
                    for (int j = 0; j < 8; ++j) o[j] = f2bf(src[(size_t)j * 64]);
                    *(bf16x8*)(w2p + (size_t)g * 8) = o;
                }
            }
        } else {
            // 27-tap ext scan -> compacted ext list + per-row flag bit
            int i = (ab - 320) * 256 + tid;
            unsigned hm = 0;
            if (i < n2) {
                #pragma unroll
                for (int t = 0; t < 27; ++t) {
                    int s = nbr[(size_t)t * n2 + i];
                    if (s < n2 && (s >> 2) != (i >> 2)) hm |= 1u << t;
                }
            }
            if (hm) atomicOr(&flagbits[i >> 5], 1u << (i & 31));
            __shared__ int lcnt, lbase;
            if (tid == 0) lcnt = 0;
            __syncthreads();
            int nh = __popc(hm);
            int myofs = 0;
            if (nh) myofs = atomicAdd(&lcnt, nh);
            __syncthreads();
            if (tid == 0 && lcnt) lbase = atomicAdd(extc, lcnt);
            __syncthreads();
            if (nh) {
                int pos = lbase + myofs;
                unsigned m = hm;
                while (m) {
                    int t = __ffs(m) - 1;
                    m &= m - 1;
                    int s = nbr[(size_t)t * n2 + i];
                    ext[pos++] = make_int2(i, s | (t << 16));
                }
            }
        }
        return;
    }
    __shared__ short lds[32 * 136];                  // stride 68 words ≡ 4 mod 32
    __shared__ float bs[64], bq[64];
    int bid = blockIdx.x - 1;
    int tile = bid >> 1;
    int w = threadIdx.x >> 6, lane = threadIdx.x & 63;
    int na = (bid & 1) * 8 + w, nb = na + 4;
    if (threadIdx.x < 64) { bs[threadIdx.x] = 0.f; bq[threadIdx.x] = 0.f; }
    #pragma unroll
    for (int it = 0; it < 2; ++it) {
        int c = it * 256 + threadIdx.x;
        int row = c >> 4, col8 = c & 15;
        int gr = tile * 32 + row; if (gr >= n1) gr = n1 - 1;
        int4 g = *(const int4*)(f1bf + (size_t)gr * 128 + col8 * 8);
        short* d = &lds[row * 136 + col8 * 8];
        *(int2*)d = make_int2(g.x, g.y);
        *(int2*)(d + 4) = make_int2(g.z, g.w);
    }
    int m = lane & 31, half = lane >> 5;
    int pm_l = (tile * 32 + m < n1) ? pmask[tile * 32 + m] : 0;
    __syncthreads();
    f32x16 a0, a1;
    #pragma unroll
    for (int i = 0; i < 16; ++i) { a0[i] = 0.f; a1[i] = 0.f; }
    const bf16x8* bp = (const bf16x8*)wupp;
    #pragma unroll
    for (int ks = 0; ks < 8; ++ks) {
        const short* ap = &lds[m * 136 + ks * 16 + half * 8];
        bf16x4 lo = *(const bf16x4*)ap, hi = *(const bf16x4*)(ap + 4);
        bf16x8 a = __builtin_shufflevector(lo, hi, 0, 1, 2, 3, 4, 5, 6, 7);
        bf16x8 b0 = bp[(size_t)(ks * 16 + na) * 64 + lane];
        bf16x8 b1 = bp[(size_t)(ks * 16 + nb) * 64 + lane];
        a0 = __builtin_amdgcn_mfma_f32_32x32x16_bf16(a, b0, a0, 0, 0, 0);
        a1 = __builtin_amdgcn_mfma_f32_32x32x16_bf16(a, b1, a1, 0, 0, 0);
    }
    int col = lane & 31;
    #pragma unroll
    for (int pass = 0; pass < 2; ++pass) {
        const f32x16& acc = pass ? a1 : a0;
        int n = pass ? nb : na;
        int slot = n >> 1, c = (n & 1) * 32 + col;
        float s0 = 0.f, q0 = 0.f;
        #pragma unroll
        for (int reg = 0; reg < 16; ++reg) {
            int r = (reg & 3) + 8 * (reg >> 2) + 4 * half;
            int p = tile * 32 + r;
            float v = acc[reg];
            int mk = __shfl(pm_l, r);
            if (p < n1) {
                yup8[(size_t)p * 512 + n * 32 + col] = f2bf(v);
                if ((mk >> slot) & 1) { s0 += v; q0 += v * v; }
            }
        }
        s0 += __shfl_xor(s0, 32);
        q0 += __shfl_xor(q0, 32);
        if (lane < 32) { atomicAdd(&bs[c], s0); atomicAdd(&bq[c], q0); }
    }
    __syncthreads();
    if (threadIdx.x < 64) {
        atomicAdd(&stats[threadIdx.x], bs[threadIdx.x]);
        atomicAdd(&stats[64 + threadIdx.x], bq[threadIdx.x]);
    }
}

// ---- conv1 ext as standalone order-free dispatch: 1 entry/wave, 4-acc ------
__global__ __launch_bounds__(256) void k_extA2(
    const short* __restrict__ yup8, const float* __restrict__ f2,
    const int* __restrict__ up_kidx, const short* __restrict__ wp,
    const float* __restrict__ gamma, const float* __restrict__ beta,
    const float* __restrict__ stats, const int2* __restrict__ ext,
    const int* __restrict__ extc, float* __restrict__ y,
    float* __restrict__ ostats, int n2)
{
    __shared__ float scs[64], shs[64], bs[64], bq[64];
    int tid = threadIdx.x;
    if (tid < 64) {
        float inv = 1.0f / (float)n2;
        float mean = stats[tid] * inv;
        float var = stats[64 + tid] * inv - mean * mean;
        float s = gamma[tid] * rsqrtf(var + 1e-5f);
        scs[tid] = s; shs[tid] = beta[tid] - mean * s;
        bs[tid] = 0.f; bq[tid] = 0.f;
    }
    __syncthreads();
    int gw = (blockIdx.x * 256 + tid) >> 6;
    int nw = (gridDim.x * 256) >> 6;
    int c = tid & 63;
    int ch = c >> 5, lcol = c & 31;
    int ec = extc[0];
    const bf16x8* wb = (const bf16x8*)wp;
    for (int e = gw; e < ec; e += nw) {
        int2 en = ext[e];
        int i = en.x, s = en.y & 0xFFFF, t = en.y >> 16;
        const short* xr = yup8 + (size_t)(s >> 2) * 512 + up_kidx[s] * 64;
        const float* fr = f2 + (size_t)s * 64;
        float ac[4] = {0.f, 0.f, 0.f, 0.f};
        #pragma unroll
        for (int ks = 0; ks < 8; ++ks) {
            #pragma unroll
            for (int hf = 0; hf < 2; ++hf) {
                int kb = ks * 16 + hf * 8;
                float xv[8];
                if (kb < 64) {            // bn_relu(yup8) half
                    bf16x8 g = *(const bf16x8*)(xr + kb);
                    #pragma unroll
                    for (int j = 0; j < 8; ++j)
                        xv[j] = fmaxf(bf2f(g[j]) * scs[kb + j] + shs[kb + j], 0.f);
                } else {                  // raw f2 half
                    float4 g0 = *(const float4*)(fr + kb - 64);
                    float4 g1 = *(const float4*)(fr + kb - 60);
                    xv[0] = g0.x; xv[1] = g0.y; xv[2] = g0.z; xv[3] = g0.w;
                    xv[4] = g1.x; xv[5] = g1.y; xv[6] = g1.z; xv[7] = g1.w;
                }
                bf16x8 wv = wb[((size_t)(t * 8 + ks) * 2 + ch) * 64 + hf * 32 + lcol];
                float* a = &ac[(ks * 2 + hf) & 3];
                #pragma unroll
                for (int j = 0; j < 8; ++j)
                    *a += xv[j] * bf2f(wv[j]);
            }
        }
        float acc = (ac[0] + ac[1]) + (ac[2] + ac[3]);
        float old = atomicAdd(&y[(size_t)i * 64 + c], acc);
        atomicAdd(&bs[c], acc);
        atomicAdd(&bq[c], acc * (acc + 2.f * old));
    }
    __syncthreads();
    if (tid < 64) {
        atomicAdd(&ostats[tid], bs[tid]);
        atomicAdd(&ostats[64 + tid], bq[tid]);
    }
}

// ---- conv epilogue (1 acc/wave): overwrite unflagged; atomic+q-corr flagged -
__device__ __forceinline__ void pair_epi1(const f32x16& av, int outrow,
                                          int lane, int ch,
                                          float* __restrict__ y,
                                          float* __restrict__ bs,
                                          float* __restrict__ bq)
{
    int col = lane & 31;
    int c = ch * 32 + col;
    float s0 = 0.f, q0 = 0.f;
    #pragma unroll
    for (int reg = 0; reg < 16; ++reg) {
        int r = (reg & 3) + 8 * (reg >> 2) + 4 * (lane >> 5);
        int r0 = __shfl(outrow, r);
        if (r0 >= 0) {
            float v = av[reg];
            size_t ad = (size_t)(r0 & ROWM) * 64 + c;
            if (r0 & RFLAG) {
                float old = atomicAdd(&y[ad], v);
                s0 += v; q0 += v * (v + 2.f * old);
            } else {
                y[ad] = v; s0 += v; q0 += v * v;
            }
        }
    }
    s0 += __shfl_xor(s0, 32);
    q0 += __shfl_xor(q0, 32);
    if (lane < 32) { atomicAdd(&bs[c], s0); atomicAdd(&bq[c], q0); }
}

__device__ __forceinline__ int tap27(int pa, int pb) {
    int di = ((pb >> 2) & 1) - ((pa >> 2) & 1);
    int dj = ((pb >> 1) & 1) - ((pa >> 1) & 1);
    int dk = (pb & 1) - (pa & 1);
    return (di + 1) * 9 + (dj + 1) * 3 + (dk + 1);
}

// conv1: tile-only (ext split out to k_extA2); 8-wave MFMA tiles
__global__ __launch_bounds__(512) void k_pairA(
    const short* __restrict__ yup8, const float* __restrict__ f2,
    const int* __restrict__ up_kidx, const short* __restrict__ wp,
    const float* __restrict__ gamma, const float* __restrict__ beta,
    const float* __restrict__ stats, const int* __restrict__ perm_par,
    const int* __restrict__ perm_rows, const int4* __restrict__ tiles,
    const int* __restrict__ n_tiles, const unsigned* __restrict__ flagbits,
    float* __restrict__ y, float* __restrict__ ostats, int n2)
{
    constexpr int LP = 520;                   // 260 words ≡ 4 mod 32: b128-clean
    __shared__ short lds[32 * LP];
    __shared__ int srows[128], soff[128];
    __shared__ float scs[64], shs[64], bs[64], bq[64];
    int tid = threadIdx.x;
    int bt = blockIdx.x;
    if (bt >= n_tiles[0]) return;
    int4 td = tiles[bt];
    int mask = td.x, p_start = td.y, lt = td.z, cntb = td.w;
    if (tid < 128) {
        int li = lt + (tid >> 2);
        int pid = perm_par[p_start + ((li < cntb) ? li : 0)];
        int i = perm_rows[pid * 4 + (tid & 3)];
        unsigned fb = (flagbits[i >> 5] >> (i & 31)) & 1u;
        srows[tid] = i | (int)(fb << 30);
        soff[tid] = (i >> 2) * 512 + up_kidx[i] * 64;
    } else if (tid < 192) {
        int cc = tid - 128;
        float inv = 1.0f / (float)n2;
        float mean = stats[cc] * inv;
        float var = stats[64 + cc] * inv - mean * mean;
        float s = gamma[cc] * rsqrtf(var + 1e-5f);
        scs[cc] = s; shs[cc] = beta[cc] - mean * s;
    } else if (tid < 256) {
        int cc = tid - 192;
        bs[cc] = 0.f; bq[cc] = 0.f;
    }
    __syncthreads();
    #pragma unroll
    for (int it = 0; it < 4; ++it) {
        int c0 = it * 512 + tid;
        int pl = c0 >> 6, w8 = c0 & 63;
        int j = w8 >> 4, col8 = w8 & 15;
        short* d = &lds[pl * LP + j * 128 + col8 * 8];
        if (col8 < 8) {
            bf16x8 g = *(const bf16x8*)(yup8 + (size_t)soff[pl * 4 + j] + col8 * 8);
            short o[8];
            #pragma unroll
            for (int u = 0; u < 8; ++u) {
                int cc = col8 * 8 + u;
                o[u] = f2bf(fmaxf(bf2f(g[u]) * scs[cc] + shs[cc], 0.f));
            }
            *(int2*)d = make_int2(((int)(unsigned short)o[0]) | ((int)o[1] << 16),
                                  ((int)(unsigned short)o[2]) | ((int)o[3] << 16));
            *(int2*)(d + 4) = make_int2(((int)(unsigned short)o[4]) | ((int)o[5] << 16),
                                        ((int)(unsigned short)o[6]) | ((int)o[7] << 16));
        } else {
            const float* fr = f2 + (size_t)(srows[pl * 4 + j] & ROWM) * 64 + (col8 - 8) * 8;
            float4 f0 = *(const float4*)fr;
            float4 f1v = *(const float4*)(fr + 4);
            short o[8] = {f2bf(f0.x), f2bf(f0.y), f2bf(f0.z), f2bf(f0.w),
                          f2bf(f1v.x), f2bf(f1v.y), f2bf(f1v.z), f2bf(f1v.w)};
            *(int2*)d = make_int2(((int)(unsigned short)o[0]) | ((int)o[1] << 16),
                                  ((int)(unsigned short)o[2]) | ((int)o[3] << 16));
            *(int2*)(d + 4) = make_int2(((int)(unsigned short)o[4]) | ((int)o[5] << 16),
                                        ((int)(unsigned short)o[6]) | ((int)o[7] << 16));
        }
    }
    int p0 = -1, p1 = -1, p2 = -1, p3 = -1;
    #pragma unroll
    for (int b = 7; b >= 0; --b)
        if ((mask >> b) & 1) { p3 = p2; p2 = p1; p1 = p0; p0 = b; }
    int w = tid >> 6, lane = tid & 63;
    int asub = w >> 1, ch = w & 1;
    int pa = (asub == 0) ? p0 : (asub == 1) ? p1 : (asub == 2) ? p2 : p3;
    int t0 = tap27(pa, p0), t1 = tap27(pa, p1), t2 = tap27(pa, p2), t3 = tap27(pa, p3);
    int m = lane & 31, half = lane >> 5;
    int li = lt + m;
    bool vp = li < cntb;
    int outrow = vp ? srows[m * 4 + asub] : -1;
    __syncthreads();
    f32x16 acc;
    #pragma unroll
    for (int i = 0; i < 16; ++i) acc[i] = 0.f;
    const bf16x8* bp = (const bf16x8*)wp;
    #pragma unroll
    for (int b = 0; b < 4; ++b) {
        int tb = (b == 0) ? t0 : (b == 1) ? t1 : (b == 2) ? t2 : t3;
        #pragma unroll
        for (int kk = 0; kk < 8; ++kk) {
            int ks = b * 8 + kk;
            const short* ap = &lds[m * LP + ks * 16 + half * 8];
            bf16x4 lo = *(const bf16x4*)ap, hi = *(const bf16x4*)(ap + 4);
            bf16x8 a = __builtin_shufflevector(lo, hi, 0, 1, 2, 3, 4, 5, 6, 7);
            bf16x8 b0 = bp[((size_t)(tb * 8 + kk) * 2 + ch) * 64 + lane];
            acc = __builtin_amdgcn_mfma_f32_32x32x16_bf16(a, b0, acc, 0, 0, 0);
        }
    }
    pair_epi1(acc, outrow, lane, ch, y, bs, bq);
    __syncthreads();
    if (tid < 64) {
        atomicAdd(&ostats[tid], bs[tid]);
        atomicAdd(&ostats[64 + tid], bq[tid]);
    }
}

// conv2: blocks [0,nExtB) = vectorized ext gather (control); rest = tiles
__global__ __launch_bounds__(512) void k_pairB(
    const float* __restrict__ y1, const short* __restrict__ wp,
    const float* __restrict__ gamma, const float* __restrict__ beta,
    const float* __restrict__ stats, const int* __restrict__ perm_par,
    const int* __restrict__ perm_rows, const int4* __restrict__ tiles,
    const int* __restrict__ n_tiles, const int2* __restrict__ ext,
    const int* __restrict__ extc, const unsigned* __restrict__ flagbits,
    float* __restrict__ y, float* __restrict__ ostats, int n2, int nExtB)
{
    constexpr int LP = 264;                   // 132 words ≡ 4 mod 32
    __shared__ short lds[32 * LP];
    __shared__ int srows[128];
    __shared__ float scs[64], shs[64], bs[64], bq[64];
    int tid = threadIdx.x;
    if (blockIdx.x < nExtB) {                 // ---- ext role (order-free) ----
        if (tid < 64) {
            float inv = 1.0f / (float)n2;
            float mean = stats[tid] * inv;
            float var = stats[64 + tid] * inv - mean * mean;
            float s = gamma[tid] * rsqrtf(var + 1e-5f);
            scs[tid] = s; shs[tid] = beta[tid] - mean * s;
            bs[tid] = 0.f; bq[tid] = 0.f;
        }
        __syncthreads();
        int gw = (blockIdx.x * 512 + tid) >> 6;
        int nw = nExtB * 8;
        int c = tid & 63;
        int ch = c >> 5, lcol = c & 31;
        int ec = extc[0];
        const bf16x8* wb = (const bf16x8*)wp;
        for (int e = gw; e < ec; e += nw) {
            int2 en = ext[e];
            int i = en.x, s = en.y & 0xFFFF, t = en.y >> 16;
            const float* hr = y1 + (size_t)s * 64;
            float acc = 0.f;
            #pragma unroll
            for (int ks = 0; ks < 4; ++ks) {
                #pragma unroll
                for (int hf = 0; hf < 2; ++hf) {
                    int kb = ks * 16 + hf * 8;
                    float4 g0 = *(const float4*)(hr + kb);
                    float4 g1 = *(const float4*)(hr + kb + 4);
                    float xv[8];
                    xv[0] = g0.x; xv[1] = g0.y; xv[2] = g0.z; xv[3] = g0.w;
                    xv[4] = g1.x; xv[5] = g1.y; xv[6] = g1.z; xv[7] = g1.w;
                    #pragma unroll
                    for (int j = 0; j < 8; ++j)
                        xv[j] = fmaxf(xv[j] * scs[kb + j] + shs[kb + j], 0.f);
                    bf16x8 wv = wb[((size_t)(t * 4 + ks) * 2 + ch) * 64 + hf * 32 + lcol];
                    #pragma unroll
                    for (int j = 0; j < 8; ++j)
                        acc += xv[j] * bf2f(wv[j]);
                }
            }
            float old = atomicAdd(&y[(size_t)i * 64 + c], acc);
            atomicAdd(&bs[c], acc);
            atomicAdd(&bq[c], acc * (acc + 2.f * old));
        }
        __syncthreads();
        if (tid < 64) {
            atomicAdd(&ostats[tid], bs[tid]);
            atomicAdd(&ostats[64 + tid], bq[tid]);
        }
        return;
    }
    int bt = blockIdx.x - nExtB;
    if (bt >= n_tiles[0]) return;
    int4 td = tiles[bt];
    int mask = td.x, p_start = td.y, lt = td.z, cntb = td.w;
    if (tid < 128) {
        int li = lt + (tid >> 2);
        int pid = perm_par[p_start + ((li < cntb) ? li : 0)];
        int i = perm_rows[pid * 4 + (tid & 3)];
        unsigned fb = (flagbits[i >> 5] >> (i & 31)) & 1u;
        srows[tid] = i | (int)(fb << 30);
    } else if (tid < 192) {
        int cc = tid - 128;
        float inv = 1.0f / (float)n2;
        float mean = stats[cc] * inv;
        float var = stats[64 + cc] * inv - mean * mean;
        float s = gamma[cc] * rsqrtf(var + 1e-5f);
        scs[cc] = s; shs[cc] = beta[cc] - mean * s;
    } else if (tid < 256) {
        int cc = tid - 192;
        bs[cc] = 0.f; bq[cc] = 0.f;
    }
    __syncthreads();
    #pragma unroll
    for (int it = 0; it < 2; ++it) {
        int c0 = it * 512 + tid;
        int pl = c0 >> 5, w8 = c0 & 31;
        int j = w8 >> 3, col8 = w8 & 7;
        const float* fr = y1 + (size_t)(srows[pl * 4 + j] & ROWM) * 64 + col8 * 8;
        float4 f0 = *(const float4*)fr;
        float4 f1v = *(const float4*)(fr + 4);
        short o[8];
        #pragma unroll
        for (int u = 0; u < 4; ++u) {
            int cc = col8 * 8 + u;
            float v = (u == 0) ? f0.x : (u == 1) ? f0.y : (u == 2) ? f0.z : f0.w;
            o[u] = f2bf(fmaxf(v * scs[cc] + shs[cc], 0.f));
        }
        #pragma unroll
        for (int u = 0; u < 4; ++u) {
            int cc = col8 * 8 + 4 + u;
            float v = (u == 0) ? f1v.x : (u == 1) ? f1v.y : (u == 2) ? f1v.z : f1v.w;
            o[4 + u] = f2bf(fmaxf(v * scs[cc] + shs[cc], 0.f));
        }
        short* d = &lds[pl * LP + j * 64 + col8 * 8];
        *(int2*)d = make_int2(((int)(unsigned short)o[0]) | ((int)o[1] << 16),
                              ((int)(unsigned short)o[2]) | ((int)o[3] << 16));
        *(int2*)(d + 4) = make_int2(((int)(unsigned short)o[4]) | ((int)o[5] << 16),
                                    ((int)(unsigned short)o[6]) | ((int)o[7] << 16));
    }
    int p0 = -1, p1 = -1, p2 = -1, p3 = -1;
    #pragma unroll
    for (int b = 7; b >= 0; --b)
        if ((mask >> b) & 1) { p3 = p2; p2 = p1; p1 = p0; p0 = b; }
    int w = tid >> 6, lane = tid & 63;
    int asub = w >> 1, ch = w & 1;
    int pa = (asub == 0) ? p0 : (asub == 1) ? p1 : (asub == 2) ? p2 : p3;
    int t0 = tap27(pa, p0), t1 = tap27(pa, p1), t2 = tap27(pa, p2), t3 = tap27(pa, p3);
    int m = lane & 31, half = lane >> 5;
    int li = lt + m;
    bool vp = li < cntb;
    int outrow = vp ? srows[m * 4 + asub] : -1;
    __syncthreads();
    f32x16 acc;
    #pragma unroll
    for (int i = 0; i < 16; ++i) acc[i] = 0.f;
    const bf16x8* bp = (const bf16x8*)wp;
    #pragma unroll
    for (int b = 0; b < 4; ++b) {
        int tb = (b == 0) ? t0 : (b == 1) ? t1 : (b == 2) ? t2 : t3;
        #pragma unroll
        for (int kk = 0; kk < 4; ++kk) {
            int ks = b * 4 + kk;
            const short* ap = &lds[m * LP + ks * 16 + half * 8];
            bf16x4 lo = *(const bf16x4*)ap, hi = *(const bf16x4*)(ap + 4);
            bf16x8 a = __builtin_shufflevector(lo, hi, 0, 1, 2, 3, 4, 5, 6, 7);
            bf16x8 b0 = bp[((size_t)(tb * 4 + kk) * 2 + ch) * 64 + lane];
            acc = __builtin_amdgcn_mfma_f32_32x32x16_bf16(a, b0, acc, 0, 0, 0);
        }
    }
    pair_epi1(acc, outrow, lane, ch, y, bs, bq);
    __syncthreads();
    if (tid < 64) {
        atomicAdd(&ostats[tid], bs[tid]);
        atomicAdd(&ostats[64 + tid], bq[tid]);
    }
}

// ---------------- BN finalize + ReLU -> f32 output ---------------------------
__global__ __launch_bounds__(256) void k_final(
    const float* __restrict__ y, const float* __restrict__ gamma,
    const float* __restrict__ beta, const float* __restrict__ stats,
    float* __restrict__ out, int n2)
{
    __shared__ float sc[64], sh[64];
    int tid = threadIdx.x;
    if (tid < 64) {
        float inv = 1.0f / (float)n2;
        float mean = stats[tid] * inv;
        float var = stats[64 + tid] * inv - mean * mean;
        float s = gamma[tid] * rsqrtf(var + 1e-5f);
        sc[tid] = s;
        sh[tid] = beta[tid] - mean * s;
    }
    __syncthreads();
    long long total = (long long)n2 * 16;
    long long stride = (long long)gridDim.x * blockDim.x;
    for (long long idx = (long long)blockIdx.x * blockDim.x + tid; idx < total; idx += stride) {
        int i = (int)(idx >> 4);
        int c4 = ((int)idx & 15) * 4;
        const float* src = y + (size_t)i * 64 + c4;
        float4 o;
        o.x = fmaxf(src[0] * sc[c4 + 0] + sh[c4 + 0], 0.f);
        o.y = fmaxf(src[1] * sc[c4 + 1] + sh[c4 + 1], 0.f);
        o.z = fmaxf(src[2] * sc[c4 + 2] + sh[c4 + 2], 0.f);
        o.w = fmaxf(src[3] * sc[c4 + 3] + sh[c4 + 3], 0.f);
        *(float4*)(out + (size_t)i * 64 + c4) = o;
    }
}

extern "C" void kernel_launch(void* const* d_in, const int* in_sizes, int n_in,
                              void* d_out, int out_size, void* d_ws, size_t ws_size,
                              hipStream_t stream)
{
    const float* feats1   = (const float*)d_in[0];
    const float* feats2   = (const float*)d_in[1];
    const float* w_up     = (const float*)d_in[2];
    const float* gamma_up = (const float*)d_in[3];
    const float* beta_up  = (const float*)d_in[4];
    const float* w1       = (const float*)d_in[5];
    const float* gamma1   = (const float*)d_in[6];
    const float* beta1    = (const float*)d_in[7];
    const float* w2       = (const float*)d_in[8];
    const float* gamma2   = (const float*)d_in[9];
    const float* beta2    = (const float*)d_in[10];
    const int* up_src     = (const int*)d_in[11];  (void)up_src;
    const int* up_kidx    = (const int*)d_in[12];
    const int* nbr_src    = (const int*)d_in[13];
    // d_in[14] nbr_dst unused: nbr_dst[t,i] ∈ {i, N2} by construction

    int n1 = in_sizes[0] / 128;
    int n2 = in_sizes[1] / 64;

    char* p = (char*)d_ws;
    auto alloc = [&](size_t bytes) {
        char* r = p;
        p += (bytes + 255) & ~(size_t)255;
        return r;
    };
    float* stats    = (float*)alloc(384 * 4);
    int*   cnt      = (int*)alloc(256 * 4);
    int*   extc     = (int*)alloc(16);
    int*   ntl      = (int*)alloc(16);
    unsigned* flagbits = (unsigned*)alloc(((size_t)(n2 + 31) / 32) * 4);
    size_t headBytes = (size_t)(p - (char*)d_ws);
    int maxTiles    = (n1 + 31) / 32 + 80;
    int4*  tiles    = (int4*)alloc((size_t)maxTiles * 16);
    short* wupp     = (short*)alloc((size_t)65536 * 2);
    short* w1p      = (short*)alloc((size_t)221184 * 2);
    short* w2p      = (short*)alloc((size_t)110592 * 2);
    short* f1bf     = (short*)alloc((size_t)n1 * 128 * 2);
    int*   pmask    = (int*)alloc((size_t)n1 * 4);
    int*   rank     = (int*)alloc((size_t)n1 * 4);
    int*   perm_par = (int*)alloc((size_t)n1 * 4);
    int*   perm_rows= (int*)alloc((size_t)4 * n1 * 4);
    int2*  ext      = (int2*)alloc((size_t)27 * n2 * 8);
    short* yup8     = (short*)alloc((size_t)n1 * 512 * 2);
    float* y1       = (float*)alloc((size_t)n2 * 64 * 4);
    float* y2       = (float*)alloc((size_t)n2 * 64 * 4);

    int nbExt  = (n2 + 255) / 256;
    int nbGeom = (n1 + 255) / 256;
    int nbPack = 128;
    int nbSetup = nbGeom + nbPack;
    int nt = (n1 + 31) / 32;
    int upBlocks = 1 + 2 * nt + 256 + 64 + nbExt;
    int ewBlocks16 = (int)(((long long)n2 * 16 + 255) / 256);
    const int EXTB = 128;

    hipMemsetAsync(d_ws, 0, headBytes, stream);
    k_setup<<<nbSetup, 256, 0, stream>>>(w_up, feats1, up_kidx, wupp, f1bf,
                                         pmask, perm_rows, rank, cnt,
                                         n1, nbGeom);
    k_up<<<upBlocks, 256, 0, stream>>>(f1bf, wupp, pmask, cnt, rank, perm_par,
                                       tiles, ntl, yup8, stats,
                                       w1, w2, w1p, w2p, nbr_src, ext, extc,
                                       flagbits, y1, y2, n1, n2, nt, nbExt);
    k_extA2<<<1024, 256, 0, stream>>>(yup8, feats2, up_kidx, w1p, gamma_up,
                                      beta_up, stats, ext, extc, y1,
                                      stats + 128, n2);
    k_pairA<<<maxTiles, 512, 0, stream>>>(yup8, feats2, up_kidx, w1p,
                                          gamma_up, beta_up, stats,
                                          perm_par, perm_rows, tiles, ntl,
                                          flagbits, y1, stats + 128, n2);
    k_pairB<<<EXTB + maxTiles, 512, 0, stream>>>(y1, w2p, gamma1, beta1,
                                                 stats + 128, perm_par,
                                                 perm_rows, tiles, ntl,
                                                 ext, extc, flagbits,
                                                 y2, stats + 256, n2, EXTB);
    k_final<<<ewBlocks16, 256, 0, stream>>>(y2, gamma2, beta2, stats + 256,
                                            (float*)d_out, n2);
}

// Round 12
// 235.359 us; speedup vs baseline: 1.0608x; 1.0608x over previous
//
#include <hip/hip_runtime.h>

// Round 21: revert to R17 (best verified, 222.6us) after two failed
// cooperative-mega rounds (R19/R20 absmax 6.4375 == max|ref| -> the
// cooperative launch silently never ran under the harness). Single tweak
// vs R17: EXTB 128 -> 256 (ext role waves 1024 -> 2048, ~2 entries/wave)
// to shorten the suspected ext tail in the pair dispatches. All kernel
// bodies are verbatim R17.

typedef short bf16x4 __attribute__((ext_vector_type(4)));
typedef short bf16x8 __attribute__((ext_vector_type(8)));
typedef float f32x16 __attribute__((ext_vector_type(16)));

#define ROWM 0xFFFFF
#define RFLAG (1 << 30)

__device__ __forceinline__ short f2bf(float f) {
    unsigned u = __float_as_uint(f);
    u += 0x7fffu + ((u >> 16) & 1u);
    return (short)(u >> 16);
}
__device__ __forceinline__ float bf2f(short s) {
    return __uint_as_float(((unsigned)(unsigned short)s) << 16);
}

// ---------------- setup: geometry + {wupp, f1bf} pack (vec8) ----------------
__global__ __launch_bounds__(256) void k_setup(
    const float* __restrict__ w_up, const float* __restrict__ f1,
    const int* __restrict__ up_kidx,
    short* __restrict__ wupp, short* __restrict__ f1bf,
    int* __restrict__ pmask, int* __restrict__ perm_rows,
    int* __restrict__ rank, int* __restrict__ cnt,
    int n1, int nbGeom)
{
    int tid = threadIdx.x;
    int bid = blockIdx.x;
    if (bid < nbGeom) {
        int p = bid * 256 + tid;
        if (p >= n1) return;
        int4 kd = *(const int4*)(up_kidx + 4 * p);
        int a = kd.x * 4 + 0, b = kd.y * 4 + 1, c = kd.z * 4 + 2, d = kd.w * 4 + 3;
        int t;
        if (a > b) { t = a; a = b; b = t; }
        if (c > d) { t = c; c = d; d = t; }
        if (a > c) { t = a; a = c; c = t; }
        if (b > d) { t = b; b = d; d = t; }
        if (b > c) { t = b; b = c; c = t; }
        perm_rows[4 * p + 0] = 4 * p + (a & 3);
        perm_rows[4 * p + 1] = 4 * p + (b & 3);
        perm_rows[4 * p + 2] = 4 * p + (c & 3);
        perm_rows[4 * p + 3] = 4 * p + (d & 3);
        int mask = (1 << (a >> 2)) | (1 << (b >> 2)) | (1 << (c >> 2)) | (1 << (d >> 2));
        pmask[p] = mask;
        rank[p] = atomicAdd(&cnt[mask], 1);
    } else {
        const int nup8 = 8192;
        int tot = nup8 + n1 * 16;
        int gs = (gridDim.x - nbGeom) * 256;
        for (int e8 = (bid - nbGeom) * 256 + tid; e8 < tot; e8 += gs) {
            if (e8 < nup8) {        // Wcat[128][512] -> [ks8][nt16][64][8]
                int l = e8 & 63, nt = (e8 >> 6) & 15, ks = e8 >> 10;
                int kb = ks * 16 + (l >> 5) * 8;
                int col = nt * 32 + (l & 31);
                const float* src = w_up + (size_t)(col >> 6) * 8192 + (size_t)kb * 64 + (col & 63);
                bf16x8 o;
                #pragma unroll
                for (int j = 0; j < 8; ++j) o[j] = f2bf(src[(size_t)j * 64]);
                *(bf16x8*)(wupp + (size_t)e8 * 8) = o;
            } else {
                int g = e8 - nup8;
                const float* src = f1 + (size_t)g * 8;
                float4 a = *(const float4*)src;
                float4 b = *(const float4*)(src + 4);
                bf16x8 o;
                o[0] = f2bf(a.x); o[1] = f2bf(a.y); o[2] = f2bf(a.z); o[3] = f2bf(a.w);
                o[4] = f2bf(b.x); o[5] = f2bf(b.y); o[6] = f2bf(b.z); o[7] = f2bf(b.w);
                *(bf16x8*)(f1bf + (size_t)g * 8) = o;
            }
        }
    }
}

// ------- dense up-GEMM + masked BN stats; block 0 = scan; aux role-blocks ----
__global__ __launch_bounds__(256) void k_up(
    const short* __restrict__ f1bf, const short* __restrict__ wupp,
    const int* __restrict__ pmask, const int* __restrict__ cnt,
    const int* __restrict__ rank, int* __restrict__ perm_par,
    int4* __restrict__ tiles, int* __restrict__ ntl,
    short* __restrict__ yup8, float* __restrict__ stats,
    const float* __restrict__ w1, const float* __restrict__ w2,
    short* __restrict__ w1p, short* __restrict__ w2p,
    const int* __restrict__ nbr, int2* __restrict__ ext,
    int* __restrict__ extc, unsigned* __restrict__ flagbits,
    float* __restrict__ y1, float* __restrict__ y2,
    int n1, int n2, int nt, int nbExt)
{
    int gemmEnd = 1 + 2 * nt;
    if (blockIdx.x == 0) {
        __shared__ int sA[256], sB[256], bb[256];
        int t = threadIdx.x;
        int c = cnt[t], tc = (c + 31) >> 5;
        sA[t] = c; sB[t] = tc;
        __syncthreads();
        for (int off = 1; off < 256; off <<= 1) {
            int a = (t >= off) ? sA[t - off] : 0;
            int b = (t >= off) ? sB[t - off] : 0;
            __syncthreads();
            sA[t] += a; sB[t] += b;
            __syncthreads();
        }
        int base = sA[t] - c, toff = sB[t] - tc;
        bb[t] = base;
        for (int j = 0; j < tc; ++j) tiles[toff + j] = make_int4(t, base, j * 32, c);
        if (t == 255) ntl[0] = sB[255];
        __syncthreads();
        for (int p = t; p < n1; p += 256)
            perm_par[bb[pmask[p]] + rank[p]] = p;
        return;
    }
    if (blockIdx.x >= gemmEnd) {
        int ab = blockIdx.x - gemmEnd;
        int tid = threadIdx.x;
        if (ab < 256) {
            long long tot = (long long)n2 * 16;
            float4 z = make_float4(0.f, 0.f, 0.f, 0.f);
            for (long long e = (long long)ab * 256 + tid; e < tot; e += 256LL * 256) {
                ((float4*)y1)[e] = z;
                ((float4*)y2)[e] = z;
            }
        } else if (ab < 320) {
            const int nw18 = 27648, tot = 27648 + 13824;
            for (int e8 = (ab - 256) * 256 + tid; e8 < tot; e8 += 64 * 256) {
                if (e8 < nw18) {     // [27][8][2][64][8]
                    int l = e8 & 63, ch = (e8 >> 6) & 1, ks = (e8 >> 7) & 7, t = e8 >> 10;
                    int kb = ks * 16 + (l >> 5) * 8;
                    int col = ch * 32 + (l & 31);
                    const float* src = w1 + (size_t)t * 8192 + (size_t)kb * 64 + col;
                    bf16x8 o;
                    #pragma unroll
                    for (int j = 0; j < 8; ++j) o[j] = f2bf(src[(size_t)j * 64]);
                    *(bf16x8*)(w1p + (size_t)e8 * 8) = o;
                } else {             // [27][4][2][64][8]
                    int g = e8 - nw18;
                    int l = g & 63, ch = (g >> 6) & 1, ks = (g >> 7) & 3, t = g >> 9;
                    int kb = ks * 16 + (l >> 5) * 8;
                    int col = ch * 32 + (l & 31);
                    const float* src = w2 + (size_t)t * 4096 + (size_t)kb * 64 + col;
                    bf16x8 o;
                    #pragma unroll
                    for (int j = 0; j < 8; ++j) o[j] = f2bf(src[(size_t)j * 64]);
                    *(bf16x8*)(w2p + (size_t)g * 8) = o;
                }
            }
        } else {
            // 27-tap ext scan -> compacted ext list + per-row flag bit
            int i = (ab - 320) * 256 + tid;
            unsigned hm = 0;
            if (i < n2) {
                #pragma unroll
                for (int t = 0; t < 27; ++t) {
                    int s = nbr[(size_t)t * n2 + i];
                    if (s < n2 && (s >> 2) != (i >> 2)) hm |= 1u << t;
                }
            }
            if (hm) atomicOr(&flagbits[i >> 5], 1u << (i & 31));
            __shared__ int lcnt, lbase;
            if (tid == 0) lcnt = 0;
            __syncthreads();
            int nh = __popc(hm);
            int myofs = 0;
            if (nh) myofs = atomicAdd(&lcnt, nh);
            __syncthreads();
            if (tid == 0 && lcnt) lbase = atomicAdd(extc, lcnt);
            __syncthreads();
            if (nh) {
                int pos = lbase + myofs;
                unsigned m = hm;
                while (m) {
                    int t = __ffs(m) - 1;
                    m &= m - 1;
                    int s = nbr[(size_t)t * n2 + i];
                    ext[pos++] = make_int2(i, s | (t << 16));
                }
            }
        }
        return;
    }
    __shared__ short lds[32 * 136];                  // stride 68 words ≡ 4 mod 32
    __shared__ float bs[64], bq[64];
    int bid = blockIdx.x - 1;
    int tile = bid >> 1;
    int w = threadIdx.x >> 6, lane = threadIdx.x & 63;
    int na = (bid & 1) * 8 + w, nb = na + 4;
    if (threadIdx.x < 64) { bs[threadIdx.x] = 0.f; bq[threadIdx.x] = 0.f; }
    #pragma unroll
    for (int it = 0; it < 2; ++it) {
        int c = it * 256 + threadIdx.x;
        int row = c >> 4, col8 = c & 15;
        int gr = tile * 32 + row; if (gr >= n1) gr = n1 - 1;
        int4 g = *(const int4*)(f1bf + (size_t)gr * 128 + col8 * 8);
        short* d = &lds[row * 136 + col8 * 8];
        *(int2*)d = make_int2(g.x, g.y);
        *(int2*)(d + 4) = make_int2(g.z, g.w);
    }
    int m = lane & 31, half = lane >> 5;
    int pm_l = (tile * 32 + m < n1) ? pmask[tile * 32 + m] : 0;
    __syncthreads();
    f32x16 a0, a1;
    #pragma unroll
    for (int i = 0; i < 16; ++i) { a0[i] = 0.f; a1[i] = 0.f; }
    const bf16x8* bp = (const bf16x8*)wupp;
    #pragma unroll
    for (int ks = 0; ks < 8; ++ks) {
        const short* ap = &lds[m * 136 + ks * 16 + half * 8];
        bf16x4 lo = *(const bf16x4*)ap, hi = *(const bf16x4*)(ap + 4);
        bf16x8 a = __builtin_shufflevector(lo, hi, 0, 1, 2, 3, 4, 5, 6, 7);
        bf16x8 b0 = bp[(size_t)(ks * 16 + na) * 64 + lane];
        bf16x8 b1 = bp[(size_t)(ks * 16 + nb) * 64 + lane];
        a0 = __builtin_amdgcn_mfma_f32_32x32x16_bf16(a, b0, a0, 0, 0, 0);
        a1 = __builtin_amdgcn_mfma_f32_32x32x16_bf16(a, b1, a1, 0, 0, 0);
    }
    int col = lane & 31;
    #pragma unroll
    for (int pass = 0; pass < 2; ++pass) {
        const f32x16& acc = pass ? a1 : a0;
        int n = pass ? nb : na;
        int slot = n >> 1, c = (n & 1) * 32 + col;
        float s0 = 0.f, q0 = 0.f;
        #pragma unroll
        for (int reg = 0; reg < 16; ++reg) {
            int r = (reg & 3) + 8 * (reg >> 2) + 4 * half;
            int p = tile * 32 + r;
            float v = acc[reg];
            int mk = __shfl(pm_l, r);
            if (p < n1) {
                yup8[(size_t)p * 512 + n * 32 + col] = f2bf(v);
                if ((mk >> slot) & 1) { s0 += v; q0 += v * v; }
            }
        }
        s0 += __shfl_xor(s0, 32);
        q0 += __shfl_xor(q0, 32);
        if (lane < 32) { atomicAdd(&bs[c], s0); atomicAdd(&bq[c], q0); }
    }
    __syncthreads();
    if (threadIdx.x < 64) {
        atomicAdd(&stats[threadIdx.x], bs[threadIdx.x]);
        atomicAdd(&stats[64 + threadIdx.x], bq[threadIdx.x]);
    }
}

// ---- conv epilogue (1 acc/wave): overwrite unflagged; atomic+q-corr flagged -
__device__ __forceinline__ void pair_epi1(const f32x16& av, int outrow,
                                          int lane, int ch,
                                          float* __restrict__ y,
                                          float* __restrict__ bs,
                                          float* __restrict__ bq)
{
    int col = lane & 31;
    int c = ch * 32 + col;
    float s0 = 0.f, q0 = 0.f;
    #pragma unroll
    for (int reg = 0; reg < 16; ++reg) {
        int r = (reg & 3) + 8 * (reg >> 2) + 4 * (lane >> 5);
        int r0 = __shfl(outrow, r);
        if (r0 >= 0) {
            float v = av[reg];
            size_t ad = (size_t)(r0 & ROWM) * 64 + c;
            if (r0 & RFLAG) {
                float old = atomicAdd(&y[ad], v);
                s0 += v; q0 += v * (v + 2.f * old);
            } else {
                y[ad] = v; s0 += v; q0 += v * v;
            }
        }
    }
    s0 += __shfl_xor(s0, 32);
    q0 += __shfl_xor(q0, 32);
    if (lane < 32) { atomicAdd(&bs[c], s0); atomicAdd(&bq[c], q0); }
}

__device__ __forceinline__ int tap27(int pa, int pb) {
    int di = ((pb >> 2) & 1) - ((pa >> 2) & 1);
    int dj = ((pb >> 1) & 1) - ((pa >> 1) & 1);
    int dk = (pb & 1) - (pa & 1);
    return (di + 1) * 9 + (dj + 1) * 3 + (dk + 1);
}

// conv1: blocks [0,nExtB) = vectorized ext gather; rest = 8-wave MFMA tiles
__global__ __launch_bounds__(512) void k_pairA(
    const short* __restrict__ yup8, const float* __restrict__ f2,
    const int* __restrict__ up_kidx, const short* __restrict__ wp,
    const float* __restrict__ gamma, const float* __restrict__ beta,
    const float* __restrict__ stats, const int* __restrict__ perm_par,
    const int* __restrict__ perm_rows, const int4* __restrict__ tiles,
    const int* __restrict__ n_tiles, const int2* __restrict__ ext,
    const int* __restrict__ extc, const unsigned* __restrict__ flagbits,
    float* __restrict__ y, float* __restrict__ ostats, int n2, int nExtB)
{
    constexpr int LP = 520;                   // 260 words ≡ 4 mod 32: b128-clean
    __shared__ short lds[32 * LP];
    __shared__ int srows[128], soff[128];
    __shared__ float scs[64], shs[64], bs[64], bq[64];
    int tid = threadIdx.x;
    if (blockIdx.x < nExtB) {                 // ---- ext role (order-free) ----
        if (tid < 64) {
            float inv = 1.0f / (float)n2;
            float mean = stats[tid] * inv;
            float var = stats[64 + tid] * inv - mean * mean;
            float s = gamma[tid] * rsqrtf(var + 1e-5f);
            scs[tid] = s; shs[tid] = beta[tid] - mean * s;
            bs[tid] = 0.f; bq[tid] = 0.f;
        }
        __syncthreads();
        int gw = (blockIdx.x * 512 + tid) >> 6;
        int nw = nExtB * 8;
        int c = tid & 63;
        int ch = c >> 5, lcol = c & 31;
        int ec = extc[0];
        const bf16x8* wb = (const bf16x8*)wp;
        for (int e = gw; e < ec; e += nw) {
            int2 en = ext[e];
            int i = en.x, s = en.y & 0xFFFF, t = en.y >> 16;
            const short* xr = yup8 + (size_t)(s >> 2) * 512 + up_kidx[s] * 64;
            const float* fr = f2 + (size_t)s * 64;
            float acc = 0.f;
            #pragma unroll
            for (int ks = 0; ks < 8; ++ks) {
                #pragma unroll
                for (int hf = 0; hf < 2; ++hf) {
                    int kb = ks * 16 + hf * 8;
                    float xv[8];
                    if (kb < 64) {            // bn_relu(yup8) half
                        bf16x8 g = *(const bf16x8*)(xr + kb);
                        #pragma unroll
                        for (int j = 0; j < 8; ++j)
                            xv[j] = fmaxf(bf2f(g[j]) * scs[kb + j] + shs[kb + j], 0.f);
                    } else {                  // raw f2 half
                        float4 g0 = *(const float4*)(fr + kb - 64);
                        float4 g1 = *(const float4*)(fr + kb - 60);
                        xv[0] = g0.x; xv[1] = g0.y; xv[2] = g0.z; xv[3] = g0.w;
                        xv[4] = g1.x; xv[5] = g1.y; xv[6] = g1.z; xv[7] = g1.w;
                    }
                    bf16x8 wv = wb[((size_t)(t * 8 + ks) * 2 + ch) * 64 + hf * 32 + lcol];
                    #pragma unroll
                    for (int j = 0; j < 8; ++j)
                        acc += xv[j] * bf2f(wv[j]);
                }
            }
            float old = atomicAdd(&y[(size_t)i * 64 + c], acc);
            atomicAdd(&bs[c], acc);
            atomicAdd(&bq[c], acc * (acc + 2.f * old));
        }
        __syncthreads();
        if (tid < 64) {
            atomicAdd(&ostats[tid], bs[tid]);
            atomicAdd(&ostats[64 + tid], bq[tid]);
        }
        return;
    }
    int bt = blockIdx.x - nExtB;
    if (bt >= n_tiles[0]) return;
    int4 td = tiles[bt];
    int mask = td.x, p_start = td.y, lt = td.z, cntb = td.w;
    if (tid < 128) {
        int li = lt + (tid >> 2);
        int pid = perm_par[p_start + ((li < cntb) ? li : 0)];
        int i = perm_rows[pid * 4 + (tid & 3)];
        unsigned fb = (flagbits[i >> 5] >> (i & 31)) & 1u;
        srows[tid] = i | (int)(fb << 30);
        soff[tid] = (i >> 2) * 512 + up_kidx[i] * 64;
    } else if (tid < 192) {
        int cc = tid - 128;
        float inv = 1.0f / (float)n2;
        float mean = stats[cc] * inv;
        float var = stats[64 + cc] * inv - mean * mean;
        float s = gamma[cc] * rsqrtf(var + 1e-5f);
        scs[cc] = s; shs[cc] = beta[cc] - mean * s;
    } else if (tid < 256) {
        int cc = tid - 192;
        bs[cc] = 0.f; bq[cc] = 0.f;
    }
    __syncthreads();
    #pragma unroll
    for (int it = 0; it < 4; ++it) {
        int c0 = it * 512 + tid;
        int pl = c0 >> 6, w8 = c0 & 63;
        int j = w8 >> 4, col8 = w8 & 15;
        short* d = &lds[pl * LP + j * 128 + col8 * 8];
        if (col8 < 8) {
            bf16x8 g = *(const bf16x8*)(yup8 + (size_t)soff[pl * 4 + j] + col8 * 8);
            short o[8];
            #pragma unroll
            for (int u = 0; u < 8; ++u) {
                int cc = col8 * 8 + u;
                o[u] = f2bf(fmaxf(bf2f(g[u]) * scs[cc] + shs[cc], 0.f));
            }
            *(int2*)d = make_int2(((int)(unsigned short)o[0]) | ((int)o[1] << 16),
                                  ((int)(unsigned short)o[2]) | ((int)o[3] << 16));
            *(int2*)(d + 4) = make_int2(((int)(unsigned short)o[4]) | ((int)o[5] << 16),
                                        ((int)(unsigned short)o[6]) | ((int)o[7] << 16));
        } else {
            const float* fr = f2 + (size_t)(srows[pl * 4 + j] & ROWM) * 64 + (col8 - 8) * 8;
            float4 f0 = *(const float4*)fr;
            float4 f1v = *(const float4*)(fr + 4);
            short o[8] = {f2bf(f0.x), f2bf(f0.y), f2bf(f0.z), f2bf(f0.w),
                          f2bf(f1v.x), f2bf(f1v.y), f2bf(f1v.z), f2bf(f1v.w)};
            *(int2*)d = make_int2(((int)(unsigned short)o[0]) | ((int)o[1] << 16),
                                  ((int)(unsigned short)o[2]) | ((int)o[3] << 16));
            *(int2*)(d + 4) = make_int2(((int)(unsigned short)o[4]) | ((int)o[5] << 16),
                                        ((int)(unsigned short)o[6]) | ((int)o[7] << 16));
        }
    }
    int p0 = -1, p1 = -1, p2 = -1, p3 = -1;
    #pragma unroll
    for (int b = 7; b >= 0; --b)
        if ((mask >> b) & 1) { p3 = p2; p2 = p1; p1 = p0; p0 = b; }
    int w = tid >> 6, lane = tid & 63;
    int asub = w >> 1, ch = w & 1;
    int pa = (asub == 0) ? p0 : (asub == 1) ? p1 : (asub == 2) ? p2 : p3;
    int t0 = tap27(pa, p0), t1 = tap27(pa, p1), t2 = tap27(pa, p2), t3 = tap27(pa, p3);
    int m = lane & 31, half = lane >> 5;
    int li = lt + m;
    bool vp = li < cntb;
    int outrow = vp ? srows[m * 4 + asub] : -1;
    __syncthreads();
    f32x16 acc;
    #pragma unroll
    for (int i = 0; i < 16; ++i) acc[i] = 0.f;
    const bf16x8* bp = (const bf16x8*)wp;
    #pragma unroll
    for (int b = 0; b < 4; ++b) {
        int tb = (b == 0) ? t0 : (b == 1) ? t1 : (b == 2) ? t2 : t3;
        #pragma unroll
        for (int kk = 0; kk < 8; ++kk) {
            int ks = b * 8 + kk;
            const short* ap = &lds[m * LP + ks * 16 + half * 8];
            bf16x4 lo = *(const bf16x4*)ap, hi = *(const bf16x4*)(ap + 4);
            bf16x8 a = __builtin_shufflevector(lo, hi, 0, 1, 2, 3, 4, 5, 6, 7);
            bf16x8 b0 = bp[((size_t)(tb * 8 + kk) * 2 + ch) * 64 + lane];
            acc = __builtin_amdgcn_mfma_f32_32x32x16_bf16(a, b0, acc, 0, 0, 0);
        }
    }
    pair_epi1(acc, outrow, lane, ch, y, bs, bq);
    __syncthreads();
    if (tid < 64) {
        atomicAdd(&ostats[tid], bs[tid]);
        atomicAdd(&ostats[64 + tid], bq[tid]);
    }
}

// conv2: blocks [0,nExtB) = vectorized ext gather; rest = 8-wave MFMA tiles
__global__ __launch_bounds__(512) void k_pairB(
    const float* __restrict__ y1, const short* __restrict__ wp,
    const float* __restrict__ gamma, const float* __restrict__ beta,
    const float* __restrict__ stats, const int* __restrict__ perm_par,
    const int* __restrict__ perm_rows, const int4* __restrict__ tiles,
    const int* __restrict__ n_tiles, const int2* __restrict__ ext,
    const int* __restrict__ extc, const unsigned* __restrict__ flagbits,
    float* __restrict__ y, float* __restrict__ ostats, int n2, int nExtB)
{
    constexpr int LP = 264;                   // 132 words ≡ 4 mod 32
    __shared__ short lds[32 * LP];
    __shared__ int srows[128];
    __shared__ float scs[64], shs[64], bs[64], bq[64];
    int tid = threadIdx.x;
    if (blockIdx.x < nExtB) {                 // ---- ext role (order-free) ----
        if (tid < 64) {
            float inv = 1.0f / (float)n2;
            float mean = stats[tid] * inv;
            float var = stats[64 + tid] * inv - mean * mean;
            float s = gamma[tid] * rsqrtf(var + 1e-5f);
            scs[tid] = s; shs[tid] = beta[tid] - mean * s;
            bs[tid] = 0.f; bq[tid] = 0.f;
        }
        __syncthreads();
        int gw = (blockIdx.x * 512 + tid) >> 6;
        int nw = nExtB * 8;
        int c = tid & 63;
        int ch = c >> 5, lcol = c & 31;
        int ec = extc[0];
        const bf16x8* wb = (const bf16x8*)wp;
        for (int e = gw; e < ec; e += nw) {
            int2 en = ext[e];
            int i = en.x, s = en.y & 0xFFFF, t = en.y >> 16;
            const float* hr = y1 + (size_t)s * 64;
            float acc = 0.f;
            #pragma unroll
            for (int ks = 0; ks < 4; ++ks) {
                #pragma unroll
                for (int hf = 0; hf < 2; ++hf) {
                    int kb = ks * 16 + hf * 8;
                    float4 g0 = *(const float4*)(hr + kb);
                    float4 g1 = *(const float4*)(hr + kb + 4);
                    float xv[8];
                    xv[0] = g0.x; xv[1] = g0.y; xv[2] = g0.z; xv[3] = g0.w;
                    xv[4] = g1.x; xv[5] = g1.y; xv[6] = g1.z; xv[7] = g1.w;
                    #pragma unroll
                    for (int j = 0; j < 8; ++j)
                        xv[j] = fmaxf(xv[j] * scs[kb + j] + shs[kb + j], 0.f);
                    bf16x8 wv = wb[((size_t)(t * 4 + ks) * 2 + ch) * 64 + hf * 32 + lcol];
                    #pragma unroll
                    for (int j = 0; j < 8; ++j)
                        acc += xv[j] * bf2f(wv[j]);
                }
            }
            float old = atomicAdd(&y[(size_t)i * 64 + c], acc);
            atomicAdd(&bs[c], acc);
            atomicAdd(&bq[c], acc * (acc + 2.f * old));
        }
        __syncthreads();
        if (tid < 64) {
            atomicAdd(&ostats[tid], bs[tid]);
            atomicAdd(&ostats[64 + tid], bq[tid]);
        }
        return;
    }
    int bt = blockIdx.x - nExtB;
    if (bt >= n_tiles[0]) return;
    int4 td = tiles[bt];
    int mask = td.x, p_start = td.y, lt = td.z, cntb = td.w;
    if (tid < 128) {
        int li = lt + (tid >> 2);
        int pid = perm_par[p_start + ((li < cntb) ? li : 0)];
        int i = perm_rows[pid * 4 + (tid & 3)];
        unsigned fb = (flagbits[i >> 5] >> (i & 31)) & 1u;
        srows[tid] = i | (int)(fb << 30);
    } else if (tid < 192) {
        int cc = tid - 128;
        float inv = 1.0f / (float)n2;
        float mean = stats[cc] * inv;
        float var = stats[64 + cc] * inv - mean * mean;
        float s = gamma[cc] * rsqrtf(var + 1e-5f);
        scs[cc] = s; shs[cc] = beta[cc] - mean * s;
    } else if (tid < 256) {
        int cc = tid - 192;
        bs[cc] = 0.f; bq[cc] = 0.f;
    }
    __syncthreads();
    #pragma unroll
    for (int it = 0; it < 2; ++it) {
        int c0 = it * 512 + tid;
        int pl = c0 >> 5, w8 = c0 & 31;
        int j = w8 >> 3, col8 = w8 & 7;
        const float* fr = y1 + (size_t)(srows[pl * 4 + j] & ROWM) * 64 + col8 * 8;
        float4 f0 = *(const float4*)fr;
        float4 f1v = *(const float4*)(fr + 4);
        short o[8];
        #pragma unroll
        for (int u = 0; u < 4; ++u) {
            int cc = col8 * 8 + u;
            float v = (u == 0) ? f0.x : (u == 1) ? f0.y : (u == 2) ? f0.z : f0.w;
            o[u] = f2bf(fmaxf(v * scs[cc] + shs[cc], 0.f));
        }
        #pragma unroll
        for (int u = 0; u < 4; ++u) {
            int cc = col8 * 8 + 4 + u;
            float v = (u == 0) ? f1v.x : (u == 1) ? f1v.y : (u == 2) ? f1v.z : f1v.w;
            o[4 + u] = f2bf(fmaxf(v * scs[cc] + shs[cc], 0.f));
        }
        short* d = &lds[pl * LP + j * 64 + col8 * 8];
        *(int2*)d = make_int2(((int)(unsigned short)o[0]) | ((int)o[1] << 16),
                              ((int)(unsigned short)o[2]) | ((int)o[3] << 16));
        *(int2*)(d + 4) = make_int2(((int)(unsigned short)o[4]) | ((int)o[5] << 16),
                                    ((int)(unsigned short)o[6]) | ((int)o[7] << 16));
    }
    int p0 = -1, p1 = -1, p2 = -1, p3 = -1;
    #pragma unroll
    for (int b = 7; b >= 0; --b)
        if ((mask >> b) & 1) { p3 = p2; p2 = p1; p1 = p0; p0 = b; }
    int w = tid >> 6, lane = tid & 63;
    int asub = w >> 1, ch = w & 1;
    int pa = (asub == 0) ? p0 : (asub == 1) ? p1 : (asub == 2) ? p2 : p3;
    int t0 = tap27(pa, p0), t1 = tap27(pa, p1), t2 = tap27(pa, p2), t3 = tap27(pa, p3);
    int m = lane & 31, half = lane >> 5;
    int li = lt + m;
    bool vp = li < cntb;
    int outrow = vp ? srows[m * 4 + asub] : -1;
    __syncthreads();
    f32x16 acc;
    #pragma unroll
    for (int i = 0; i < 16; ++i) acc[i] = 0.f;
    const bf16x8* bp = (const bf16x8*)wp;
    #pragma unroll
    for (int b = 0; b < 4; ++b) {
        int tb = (b == 0) ? t0 : (b == 1) ? t1 : (b == 2) ? t2 : t3;
        #pragma unroll
        for (int kk = 0; kk < 4; ++kk) {
            int ks = b * 4 + kk;
            const short* ap = &lds[m * LP + ks * 16 + half * 8];
            bf16x4 lo = *(const bf16x4*)ap, hi = *(const bf16x4*)(ap + 4);
            bf16x8 a = __builtin_shufflevector(lo, hi, 0, 1, 2, 3, 4, 5, 6, 7);
            bf16x8 b0 = bp[((size_t)(tb * 4 + kk) * 2 + ch) * 64 + lane];
            acc = __builtin_amdgcn_mfma_f32_32x32x16_bf16(a, b0, acc, 0, 0, 0);
        }
    }
    pair_epi1(acc, outrow, lane, ch, y, bs, bq);
    __syncthreads();
    if (tid < 64) {
        atomicAdd(&ostats[tid], bs[tid]);
        atomicAdd(&ostats[64 + tid], bq[tid]);
    }
}

// ---------------- BN finalize + ReLU -> f32 output ---------------------------
__global__ __launch_bounds__(256) void k_final(
    const float* __restrict__ y, const float* __restrict__ gamma,
    const float* __restrict__ beta, const float* __restrict__ stats,
    float* __restrict__ out, int n2)
{
    __shared__ float sc[64], sh[64];
    int tid = threadIdx.x;
    if (tid < 64) {
        float inv = 1.0f / (float)n2;
        float mean = stats[tid] * inv;
        float var = stats[64 + tid] * inv - mean * mean;
        float s = gamma[tid] * rsqrtf(var + 1e-5f);
        sc[tid] = s;
        sh[tid] = beta[tid] - mean * s;
    }
    __syncthreads();
    long long total = (long long)n2 * 16;
    long long stride = (long long)gridDim.x * blockDim.x;
    for (long long idx = (long long)blockIdx.x * blockDim.x + tid; idx < total; idx += stride) {
        int i = (int)(idx >> 4);
        int c4 = ((int)idx & 15) * 4;
        const float* src = y + (size_t)i * 64 + c4;
        float4 o;
        o.x = fmaxf(src[0] * sc[c4 + 0] + sh[c4 + 0], 0.f);
        o.y = fmaxf(src[1] * sc[c4 + 1] + sh[c4 + 1], 0.f);
        o.z = fmaxf(src[2] * sc[c4 + 2] + sh[c4 + 2], 0.f);
        o.w = fmaxf(src[3] * sc[c4 + 3] + sh[c4 + 3], 0.f);
        *(float4*)(out + (size_t)i * 64 + c4) = o;
    }
}

extern "C" void kernel_launch(void* const* d_in, const int* in_sizes, int n_in,
                              void* d_out, int out_size, void* d_ws, size_t ws_size,
                              hipStream_t stream)
{
    const float* feats1   = (const float*)d_in[0];
    const float* feats2   = (const float*)d_in[1];
    const float* w_up     = (const float*)d_in[2];
    const float* gamma_up = (const float*)d_in[3];
    const float* beta_up  = (const float*)d_in[4];
    const float* w1       = (const float*)d_in[5];
    const float* gamma1   = (const float*)d_in[6];
    const float* beta1    = (const float*)d_in[7];
    const float* w2       = (const float*)d_in[8];
    const float* gamma2   = (const float*)d_in[9];
    const float* beta2    = (const float*)d_in[10];
    const int* up_src     = (const int*)d_in[11];  (void)up_src;
    const int* up_kidx    = (const int*)d_in[12];
    const int* nbr_src    = (const int*)d_in[13];
    // d_in[14] nbr_dst unused: nbr_dst[t,i] ∈ {i, N2} by construction

    int n1 = in_sizes[0] / 128;
    int n2 = in_sizes[1] / 64;

    char* p = (char*)d_ws;
    auto alloc = [&](size_t bytes) {
        char* r = p;
        p += (bytes + 255) & ~(size_t)255;
        return r;
    };
    float* stats    = (float*)alloc(384 * 4);
    int*   cnt      = (int*)alloc(256 * 4);
    int*   extc     = (int*)alloc(16);
    int*   ntl      = (int*)alloc(16);
    unsigned* flagbits = (unsigned*)alloc(((size_t)(n2 + 31) / 32) * 4);
    size_t headBytes = (size_t)(p - (char*)d_ws);
    int maxTiles    = (n1 + 31) / 32 + 80;
    int4*  tiles    = (int4*)alloc((size_t)maxTiles * 16);
    short* wupp     = (short*)alloc((size_t)65536 * 2);
    short* w1p      = (short*)alloc((size_t)221184 * 2);
    short* w2p      = (short*)alloc((size_t)110592 * 2);
    short* f1bf     = (short*)alloc((size_t)n1 * 128 * 2);
    int*   pmask    = (int*)alloc((size_t)n1 * 4);
    int*   rank     = (int*)alloc((size_t)n1 * 4);
    int*   perm_par = (int*)alloc((size_t)n1 * 4);
    int*   perm_rows= (int*)alloc((size_t)4 * n1 * 4);
    int2*  ext      = (int2*)alloc((size_t)27 * n2 * 8);
    short* yup8     = (short*)alloc((size_t)n1 * 512 * 2);
    float* y1       = (float*)alloc((size_t)n2 * 64 * 4);
    float* y2       = (float*)alloc((size_t)n2 * 64 * 4);

    int nbExt  = (n2 + 255) / 256;
    int nbGeom = (n1 + 255) / 256;
    int nbPack = 128;
    int nbSetup = nbGeom + nbPack;
    int nt = (n1 + 31) / 32;
    int upBlocks = 1 + 2 * nt + 256 + 64 + nbExt;
    int ewBlocks16 = (int)(((long long)n2 * 16 + 255) / 256);
    const int EXTB = 256;   // R21: 128 -> 256 (ext tail halved)

    hipMemsetAsync(d_ws, 0, headBytes, stream);
    k_setup<<<nbSetup, 256, 0, stream>>>(w_up, feats1, up_kidx, wupp, f1bf,
                                         pmask, perm_rows, rank, cnt,
                                         n1, nbGeom);
    k_up<<<upBlocks, 256, 0, stream>>>(f1bf, wupp, pmask, cnt, rank, perm_par,
                                       tiles, ntl, yup8, stats,
                                       w1, w2, w1p, w2p, nbr_src, ext, extc,
                                       flagbits, y1, y2, n1, n2, nt, nbExt);
    k_pairA<<<EXTB + maxTiles, 512, 0, stream>>>(yup8, feats2, up_kidx, w1p,
                                                 gamma_up, beta_up, stats,
                                                 perm_par, perm_rows, tiles, ntl,
                                                 ext, extc, flagbits,
                                                 y1, stats + 128, n2, EXTB);
    k_pairB<<<EXTB + maxTiles, 512, 0, stream>>>(y1, w2p, gamma1, beta1,
                                                 stats + 128, perm_par,
                                                 perm_rows, tiles, ntl,
                                                 ext, extc, flagbits,
                                                 y2, stats + 256, n2, EXTB);
    k_final<<<ewBlocks16, 256, 0, stream>>>(y2, gamma2, beta2, stats + 256,
                                            (float*)d_out, n2);
}

// Round 13
// 230.222 us; speedup vs baseline: 1.0845x; 1.0223x over previous
//
#include <hip/hip_runtime.h>

// Round 22: exact revert to R17 (best verified: 222.6us, absmax 0.03125).
// R21 (EXTB 256) regressed +13us by exceeding the 3-blocks/CU co-residency
// limit (805 > 768 blocks -> extra scheduling round). Session model: in the
// latency regime, dispatch time ~= co-residency rounds x slowest-block
// critical path; EXTB=128 keeps all 658 pair blocks co-resident. Register-
// prefetch fixes for the MFMA B-operand chain all break the 85-VGPR /
// 6-wave-per-SIMD boundary and reduce blocks/CU -- net negative.

typedef short bf16x4 __attribute__((ext_vector_type(4)));
typedef short bf16x8 __attribute__((ext_vector_type(8)));
typedef float f32x16 __attribute__((ext_vector_type(16)));

#define ROWM 0xFFFFF
#define RFLAG (1 << 30)

__device__ __forceinline__ short f2bf(float f) {
    unsigned u = __float_as_uint(f);
    u += 0x7fffu + ((u >> 16) & 1u);
    return (short)(u >> 16);
}
__device__ __forceinline__ float bf2f(short s) {
    return __uint_as_float(((unsigned)(unsigned short)s) << 16);
}

// ---------------- setup: geometry + {wupp, f1bf} pack (vec8) ----------------
__global__ __launch_bounds__(256) void k_setup(
    const float* __restrict__ w_up, const float* __restrict__ f1,
    const int* __restrict__ up_kidx,
    short* __restrict__ wupp, short* __restrict__ f1bf,
    int* __restrict__ pmask, int* __restrict__ perm_rows,
    int* __restrict__ rank, int* __restrict__ cnt,
    int n1, int nbGeom)
{
    int tid = threadIdx.x;
    int bid = blockIdx.x;
    if (bid < nbGeom) {
        int p = bid * 256 + tid;
        if (p >= n1) return;
        int4 kd = *(const int4*)(up_kidx + 4 * p);
        int a = kd.x * 4 + 0, b = kd.y * 4 + 1, c = kd.z * 4 + 2, d = kd.w * 4 + 3;
        int t;
        if (a > b) { t = a; a = b; b = t; }
        if (c > d) { t = c; c = d; d = t; }
        if (a > c) { t = a; a = c; c = t; }
        if (b > d) { t = b; b = d; d = t; }
        if (b > c) { t = b; b = c; c = t; }
        perm_rows[4 * p + 0] = 4 * p + (a & 3);
        perm_rows[4 * p + 1] = 4 * p + (b & 3);
        perm_rows[4 * p + 2] = 4 * p + (c & 3);
        perm_rows[4 * p + 3] = 4 * p + (d & 3);
        int mask = (1 << (a >> 2)) | (1 << (b >> 2)) | (1 << (c >> 2)) | (1 << (d >> 2));
        pmask[p] = mask;
        rank[p] = atomicAdd(&cnt[mask], 1);
    } else {
        const int nup8 = 8192;
        int tot = nup8 + n1 * 16;
        int gs = (gridDim.x - nbGeom) * 256;
        for (int e8 = (bid - nbGeom) * 256 + tid; e8 < tot; e8 += gs) {
            if (e8 < nup8) {        // Wcat[128][512] -> [ks8][nt16][64][8]
                int l = e8 & 63, nt = (e8 >> 6) & 15, ks = e8 >> 10;
                int kb = ks * 16 + (l >> 5) * 8;
                int col = nt * 32 + (l & 31);
                const float* src = w_up + (size_t)(col >> 6) * 8192 + (size_t)kb * 64 + (col & 63);
                bf16x8 o;
                #pragma unroll
                for (int j = 0; j < 8; ++j) o[j] = f2bf(src[(size_t)j * 64]);
                *(bf16x8*)(wupp + (size_t)e8 * 8) = o;
            } else {
                int g = e8 - nup8;
                const float* src = f1 + (size_t)g * 8;
                float4 a = *(const float4*)src;
                float4 b = *(const float4*)(src + 4);
                bf16x8 o;
                o[0] = f2bf(a.x); o[1] = f2bf(a.y); o[2] = f2bf(a.z); o[3] = f2bf(a.w);
                o[4] = f2bf(b.x); o[5] = f2bf(b.y); o[6] = f2bf(b.z); o[7] = f2bf(b.w);
                *(bf16x8*)(f1bf + (size_t)g * 8) = o;
            }
        }
    }
}

// ------- dense up-GEMM + masked BN stats; block 0 = scan; aux role-blocks ----
__global__ __launch_bounds__(256) void k_up(
    const short* __restrict__ f1bf, const short* __restrict__ wupp,
    const int* __restrict__ pmask, const int* __restrict__ cnt,
    const int* __restrict__ rank, int* __restrict__ perm_par,
    int4* __restrict__ tiles, int* __restrict__ ntl,
    short* __restrict__ yup8, float* __restrict__ stats,
    const float* __restrict__ w1, const float* __restrict__ w2,
    short* __restrict__ w1p, short* __restrict__ w2p,
    const int* __restrict__ nbr, int2* __restrict__ ext,
    int* __restrict__ extc, unsigned* __restrict__ flagbits,
    float* __restrict__ y1, float* __restrict__ y2,
    int n1, int n2, int nt, int nbExt)
{
    int gemmEnd = 1 + 2 * nt;
    if (blockIdx.x == 0) {
        __shared__ int sA[256], sB[256], bb[256];
        int t = threadIdx.x;
        int c = cnt[t], tc = (c + 31) >> 5;
        sA[t] = c; sB[t] = tc;
        __syncthreads();
        for (int off = 1; off < 256; off <<= 1) {
            int a = (t >= off) ? sA[t - off] : 0;
            int b = (t >= off) ? sB[t - off] : 0;
            __syncthreads();
            sA[t] += a; sB[t] += b;
            __syncthreads();
        }
        int base = sA[t] - c, toff = sB[t] - tc;
        bb[t] = base;
        for (int j = 0; j < tc; ++j) tiles[toff + j] = make_int4(t, base, j * 32, c);
        if (t == 255) ntl[0] = sB[255];
        __syncthreads();
        for (int p = t; p < n1; p += 256)
            perm_par[bb[pmask[p]] + rank[p]] = p;
        return;
    }
    if (blockIdx.x >= gemmEnd) {
        int ab = blockIdx.x - gemmEnd;
        int tid = threadIdx.x;
        if (ab < 256) {
            long long tot = (long long)n2 * 16;
            float4 z = make_float4(0.f, 0.f, 0.f, 0.f);
            for (long long e = (long long)ab * 256 + tid; e < tot; e += 256LL * 256) {
                ((float4*)y1)[e] = z;
                ((float4*)y2)[e] = z;
            }
        } else if (ab < 320) {
            const int nw18 = 27648, tot = 27648 + 13824;
            for (int e8 = (ab - 256) * 256 + tid; e8 < tot; e8 += 64 * 256) {
                if (e8 < nw18) {     // [27][8][2][64][8]
                    int l = e8 & 63, ch = (e8 >> 6) & 1, ks = (e8 >> 7) & 7, t = e8 >> 10;
                    int kb = ks * 16 + (l >> 5) * 8;
                    int col = ch * 32 + (l & 31);
                    const float* src = w1 + (size_t)t * 8192 + (size_t)kb * 64 + col;
                    bf16x8 o;
                    #pragma unroll
                    for (int j = 0; j < 8; ++j) o[j] = f2bf(src[(size_t)j * 64]);
                    *(bf16x8*)(w1p + (size_t)e8 * 8) = o;
                } else {             // [27][4][2][64][8]
                    int g = e8 - nw18;
                    int l = g & 63, ch = (g >> 6) & 1, ks = (g >> 7) & 3, t = g >> 9;
                    int kb = ks * 16 + (l >> 5) * 8;
                    int col = ch * 32 + (l & 31);
                    const float* src = w2 + (size_t)t * 4096 + (size_t)kb * 64 + col;
                    bf16x8 o;
                    #pragma unroll
                    for (int j = 0; j < 8; ++j) o[j] = f2bf(src[(size_t)j * 64]);
                    *(bf16x8*)(w2p + (size_t)g * 8) = o;
                }
            }
        } else {
            // 27-tap ext scan -> compacted ext list + per-row flag bit
            int i = (ab - 320) * 256 + tid;
            unsigned hm = 0;
            if (i < n2) {
                #pragma unroll
                for (int t = 0; t < 27; ++t) {
                    int s = nbr[(size_t)t * n2 + i];
                    if (s < n2 && (s >> 2) != (i >> 2)) hm |= 1u << t;
                }
            }
            if (hm) atomicOr(&flagbits[i >> 5], 1u << (i & 31));
            __shared__ int lcnt, lbase;
            if (tid == 0) lcnt = 0;
            __syncthreads();
            int nh = __popc(hm);
            int myofs = 0;
            if (nh) myofs = atomicAdd(&lcnt, nh);
            __syncthreads();
            if (tid == 0 && lcnt) lbase = atomicAdd(extc, lcnt);
            __syncthreads();
            if (nh) {
                int pos = lbase + myofs;
                unsigned m = hm;
                while (m) {
                    int t = __ffs(m) - 1;
                    m &= m - 1;
                    int s = nbr[(size_t)t * n2 + i];
                    ext[pos++] = make_int2(i, s | (t << 16));
                }
            }
        }
        return;
    }
    __shared__ short lds[32 * 136];                  // stride 68 words ≡ 4 mod 32
    __shared__ float bs[64], bq[64];
    int bid = blockIdx.x - 1;
    int tile = bid >> 1;
    int w = threadIdx.x >> 6, lane = threadIdx.x & 63;
    int na = (bid & 1) * 8 + w, nb = na + 4;
    if (threadIdx.x < 64) { bs[threadIdx.x] = 0.f; bq[threadIdx.x] = 0.f; }
    #pragma unroll
    for (int it = 0; it < 2; ++it) {
        int c = it * 256 + threadIdx.x;
        int row = c >> 4, col8 = c & 15;
        int gr = tile * 32 + row; if (gr >= n1) gr = n1 - 1;
        int4 g = *(const int4*)(f1bf + (size_t)gr * 128 + col8 * 8);
        short* d = &lds[row * 136 + col8 * 8];
        *(int2*)d = make_int2(g.x, g.y);
        *(int2*)(d + 4) = make_int2(g.z, g.w);
    }
    int m = lane & 31, half = lane >> 5;
    int pm_l = (tile * 32 + m < n1) ? pmask[tile * 32 + m] : 0;
    __syncthreads();
    f32x16 a0, a1;
    #pragma unroll
    for (int i = 0; i < 16; ++i) { a0[i] = 0.f; a1[i] = 0.f; }
    const bf16x8* bp = (const bf16x8*)wupp;
    #pragma unroll
    for (int ks = 0; ks < 8; ++ks) {
        const short* ap = &lds[m * 136 + ks * 16 + half * 8];
        bf16x4 lo = *(const bf16x4*)ap, hi = *(const bf16x4*)(ap + 4);
        bf16x8 a = __builtin_shufflevector(lo, hi, 0, 1, 2, 3, 4, 5, 6, 7);
        bf16x8 b0 = bp[(size_t)(ks * 16 + na) * 64 + lane];
        bf16x8 b1 = bp[(size_t)(ks * 16 + nb) * 64 + lane];
        a0 = __builtin_amdgcn_mfma_f32_32x32x16_bf16(a, b0, a0, 0, 0, 0);
        a1 = __builtin_amdgcn_mfma_f32_32x32x16_bf16(a, b1, a1, 0, 0, 0);
    }
    int col = lane & 31;
    #pragma unroll
    for (int pass = 0; pass < 2; ++pass) {
        const f32x16& acc = pass ? a1 : a0;
        int n = pass ? nb : na;
        int slot = n >> 1, c = (n & 1) * 32 + col;
        float s0 = 0.f, q0 = 0.f;
        #pragma unroll
        for (int reg = 0; reg < 16; ++reg) {
            int r = (reg & 3) + 8 * (reg >> 2) + 4 * half;
            int p = tile * 32 + r;
            float v = acc[reg];
            int mk = __shfl(pm_l, r);
            if (p < n1) {
                yup8[(size_t)p * 512 + n * 32 + col] = f2bf(v);
                if ((mk >> slot) & 1) { s0 += v; q0 += v * v; }
            }
        }
        s0 += __shfl_xor(s0, 32);
        q0 += __shfl_xor(q0, 32);
        if (lane < 32) { atomicAdd(&bs[c], s0); atomicAdd(&bq[c], q0); }
    }
    __syncthreads();
    if (threadIdx.x < 64) {
        atomicAdd(&stats[threadIdx.x], bs[threadIdx.x]);
        atomicAdd(&stats[64 + threadIdx.x], bq[threadIdx.x]);
    }
}

// ---- conv epilogue (1 acc/wave): overwrite unflagged; atomic+q-corr flagged -
__device__ __forceinline__ void pair_epi1(const f32x16& av, int outrow,
                                          int lane, int ch,
                                          float* __restrict__ y,
                                          float* __restrict__ bs,
                                          float* __restrict__ bq)
{
    int col = lane & 31;
    int c = ch * 32 + col;
    float s0 = 0.f, q0 = 0.f;
    #pragma unroll
    for (int reg = 0; reg < 16; ++reg) {
        int r = (reg & 3) + 8 * (reg >> 2) + 4 * (lane >> 5);
        int r0 = __shfl(outrow, r);
        if (r0 >= 0) {
            float v = av[reg];
            size_t ad = (size_t)(r0 & ROWM) * 64 + c;
            if (r0 & RFLAG) {
                float old = atomicAdd(&y[ad], v);
                s0 += v; q0 += v * (v + 2.f * old);
            } else {
                y[ad] = v; s0 += v; q0 += v * v;
            }
        }
    }
    s0 += __shfl_xor(s0, 32);
    q0 += __shfl_xor(q0, 32);
    if (lane < 32) { atomicAdd(&bs[c], s0); atomicAdd(&bq[c], q0); }
}

__device__ __forceinline__ int tap27(int pa, int pb) {
    int di = ((pb >> 2) & 1) - ((pa >> 2) & 1);
    int dj = ((pb >> 1) & 1) - ((pa >> 1) & 1);
    int dk = (pb & 1) - (pa & 1);
    return (di + 1) * 9 + (dj + 1) * 3 + (dk + 1);
}

// conv1: blocks [0,nExtB) = vectorized ext gather; rest = 8-wave MFMA tiles
__global__ __launch_bounds__(512) void k_pairA(
    const short* __restrict__ yup8, const float* __restrict__ f2,
    const int* __restrict__ up_kidx, const short* __restrict__ wp,
    const float* __restrict__ gamma, const float* __restrict__ beta,
    const float* __restrict__ stats, const int* __restrict__ perm_par,
    const int* __restrict__ perm_rows, const int4* __restrict__ tiles,
    const int* __restrict__ n_tiles, const int2* __restrict__ ext,
    const int* __restrict__ extc, const unsigned* __restrict__ flagbits,
    float* __restrict__ y, float* __restrict__ ostats, int n2, int nExtB)
{
    constexpr int LP = 520;                   // 260 words ≡ 4 mod 32: b128-clean
    __shared__ short lds[32 * LP];
    __shared__ int srows[128], soff[128];
    __shared__ float scs[64], shs[64], bs[64], bq[64];
    int tid = threadIdx.x;
    if (blockIdx.x < nExtB) {                 // ---- ext role (order-free) ----
        if (tid < 64) {
            float inv = 1.0f / (float)n2;
            float mean = stats[tid] * inv;
            float var = stats[64 + tid] * inv - mean * mean;
            float s = gamma[tid] * rsqrtf(var + 1e-5f);
            scs[tid] = s; shs[tid] = beta[tid] - mean * s;
            bs[tid] = 0.f; bq[tid] = 0.f;
        }
        __syncthreads();
        int gw = (blockIdx.x * 512 + tid) >> 6;
        int nw = nExtB * 8;
        int c = tid & 63;
        int ch = c >> 5, lcol = c & 31;
        int ec = extc[0];
        const bf16x8* wb = (const bf16x8*)wp;
        for (int e = gw; e < ec; e += nw) {
            int2 en = ext[e];
            int i = en.x, s = en.y & 0xFFFF, t = en.y >> 16;
            const short* xr = yup8 + (size_t)(s >> 2) * 512 + up_kidx[s] * 64;
            const float* fr = f2 + (size_t)s * 64;
            float acc = 0.f;
            #pragma unroll
            for (int ks = 0; ks < 8; ++ks) {
                #pragma unroll
                for (int hf = 0; hf < 2; ++hf) {
                    int kb = ks * 16 + hf * 8;
                    float xv[8];
                    if (kb < 64) {            // bn_relu(yup8) half
                        bf16x8 g = *(const bf16x8*)(xr + kb);
                        #pragma unroll
                        for (int j = 0; j < 8; ++j)
                            xv[j] = fmaxf(bf2f(g[j]) * scs[kb + j] + shs[kb + j], 0.f);
                    } else {                  // raw f2 half
                        float4 g0 = *(const float4*)(fr + kb - 64);
                        float4 g1 = *(const float4*)(fr + kb - 60);
                        xv[0] = g0.x; xv[1] = g0.y; xv[2] = g0.z; xv[3] = g0.w;
                        xv[4] = g1.x; xv[5] = g1.y; xv[6] = g1.z; xv[7] = g1.w;
                    }
                    bf16x8 wv = wb[((size_t)(t * 8 + ks) * 2 + ch) * 64 + hf * 32 + lcol];
                    #pragma unroll
                    for (int j = 0; j < 8; ++j)
                        acc += xv[j] * bf2f(wv[j]);
                }
            }
            float old = atomicAdd(&y[(size_t)i * 64 + c], acc);
            atomicAdd(&bs[c], acc);
            atomicAdd(&bq[c], acc * (acc + 2.f * old));
        }
        __syncthreads();
        if (tid < 64) {
            atomicAdd(&ostats[tid], bs[tid]);
            atomicAdd(&ostats[64 + tid], bq[tid]);
        }
        return;
    }
    int bt = blockIdx.x - nExtB;
    if (bt >= n_tiles[0]) return;
    int4 td = tiles[bt];
    int mask = td.x, p_start = td.y, lt = td.z, cntb = td.w;
    if (tid < 128) {
        int li = lt + (tid >> 2);
        int pid = perm_par[p_start + ((li < cntb) ? li : 0)];
        int i = perm_rows[pid * 4 + (tid & 3)];
        unsigned fb = (flagbits[i >> 5] >> (i & 31)) & 1u;
        srows[tid] = i | (int)(fb << 30);
        soff[tid] = (i >> 2) * 512 + up_kidx[i] * 64;
    } else if (tid < 192) {
        int cc = tid - 128;
        float inv = 1.0f / (float)n2;
        float mean = stats[cc] * inv;
        float var = stats[64 + cc] * inv - mean * mean;
        float s = gamma[cc] * rsqrtf(var + 1e-5f);
        scs[cc] = s; shs[cc] = beta[cc] - mean * s;
    } else if (tid < 256) {
        int cc = tid - 192;
        bs[cc] = 0.f; bq[cc] = 0.f;
    }
    __syncthreads();
    #pragma unroll
    for (int it = 0; it < 4; ++it) {
        int c0 = it * 512 + tid;
        int pl = c0 >> 6, w8 = c0 & 63;
        int j = w8 >> 4, col8 = w8 & 15;
        short* d = &lds[pl * LP + j * 128 + col8 * 8];
        if (col8 < 8) {
            bf16x8 g = *(const bf16x8*)(yup8 + (size_t)soff[pl * 4 + j] + col8 * 8);
            short o[8];
            #pragma unroll
            for (int u = 0; u < 8; ++u) {
                int cc = col8 * 8 + u;
                o[u] = f2bf(fmaxf(bf2f(g[u]) * scs[cc] + shs[cc], 0.f));
            }
            *(int2*)d = make_int2(((int)(unsigned short)o[0]) | ((int)o[1] << 16),
                                  ((int)(unsigned short)o[2]) | ((int)o[3] << 16));
            *(int2*)(d + 4) = make_int2(((int)(unsigned short)o[4]) | ((int)o[5] << 16),
                                        ((int)(unsigned short)o[6]) | ((int)o[7] << 16));
        } else {
            const float* fr = f2 + (size_t)(srows[pl * 4 + j] & ROWM) * 64 + (col8 - 8) * 8;
            float4 f0 = *(const float4*)fr;
            float4 f1v = *(const float4*)(fr + 4);
            short o[8] = {f2bf(f0.x), f2bf(f0.y), f2bf(f0.z), f2bf(f0.w),
                          f2bf(f1v.x), f2bf(f1v.y), f2bf(f1v.z), f2bf(f1v.w)};
            *(int2*)d = make_int2(((int)(unsigned short)o[0]) | ((int)o[1] << 16),
                                  ((int)(unsigned short)o[2]) | ((int)o[3] << 16));
            *(int2*)(d + 4) = make_int2(((int)(unsigned short)o[4]) | ((int)o[5] << 16),
                                        ((int)(unsigned short)o[6]) | ((int)o[7] << 16));
        }
    }
    int p0 = -1, p1 = -1, p2 = -1, p3 = -1;
    #pragma unroll
    for (int b = 7; b >= 0; --b)
        if ((mask >> b) & 1) { p3 = p2; p2 = p1; p1 = p0; p0 = b; }
    int w = tid >> 6, lane = tid & 63;
    int asub = w >> 1, ch = w & 1;
    int pa = (asub == 0) ? p0 : (asub == 1) ? p1 : (asub == 2) ? p2 : p3;
    int t0 = tap27(pa, p0), t1 = tap27(pa, p1), t2 = tap27(pa, p2), t3 = tap27(pa, p3);
    int m = lane & 31, half = lane >> 5;
    int li = lt + m;
    bool vp = li < cntb;
    int outrow = vp ? srows[m * 4 + asub] : -1;
    __syncthreads();
    f32x16 acc;
    #pragma unroll
    for (int i = 0; i < 16; ++i) acc[i] = 0.f;
    const bf16x8* bp = (const bf16x8*)wp;
    #pragma unroll
    for (int b = 0; b < 4; ++b) {
        int tb = (b == 0) ? t0 : (b == 1) ? t1 : (b == 2) ? t2 : t3;
        #pragma unroll
        for (int kk = 0; kk < 8; ++kk) {
            int ks = b * 8 + kk;
            const short* ap = &lds[m * LP + ks * 16 + half * 8];
            bf16x4 lo = *(const bf16x4*)ap, hi = *(const bf16x4*)(ap + 4);
            bf16x8 a = __builtin_shufflevector(lo, hi, 0, 1, 2, 3, 4, 5, 6, 7);
            bf16x8 b0 = bp[((size_t)(tb * 8 + kk) * 2 + ch) * 64 + lane];
            acc = __builtin_amdgcn_mfma_f32_32x32x16_bf16(a, b0, acc, 0, 0, 0);
        }
    }
    pair_epi1(acc, outrow, lane, ch, y, bs, bq);
    __syncthreads();
    if (tid < 64) {
        atomicAdd(&ostats[tid], bs[tid]);
        atomicAdd(&ostats[64 + tid], bq[tid]);
    }
}

// conv2: blocks [0,nExtB) = vectorized ext gather; rest = 8-wave MFMA tiles
__global__ __launch_bounds__(512) void k_pairB(
    const float* __restrict__ y1, const short* __restrict__ wp,
    const float* __restrict__ gamma, const float* __restrict__ beta,
    const float* __restrict__ stats, const int* __restrict__ perm_par,
    const int* __restrict__ perm_rows, const int4* __restrict__ tiles,
    const int* __restrict__ n_tiles, const int2* __restrict__ ext,
    const int* __restrict__ extc, const unsigned* __restrict__ flagbits,
    float* __restrict__ y, float* __restrict__ ostats, int n2, int nExtB)
{
    constexpr int LP = 264;                   // 132 words ≡ 4 mod 32
    __shared__ short lds[32 * LP];
    __shared__ int srows[128];
    __shared__ float scs[64], shs[64], bs[64], bq[64];
    int tid = threadIdx.x;
    if (blockIdx.x < nExtB) {                 // ---- ext role (order-free) ----
        if (tid < 64) {
            float inv = 1.0f / (float)n2;
            float mean = stats[tid] * inv;
            float var = stats[64 + tid] * inv - mean * mean;
            float s = gamma[tid] * rsqrtf(var + 1e-5f);
            scs[tid] = s; shs[tid] = beta[tid] - mean * s;
            bs[tid] = 0.f; bq[tid] = 0.f;
        }
        __syncthreads();
        int gw = (blockIdx.x * 512 + tid) >> 6;
        int nw = nExtB * 8;
        int c = tid & 63;
        int ch = c >> 5, lcol = c & 31;
        int ec = extc[0];
        const bf16x8* wb = (const bf16x8*)wp;
        for (int e = gw; e < ec; e += nw) {
            int2 en = ext[e];
            int i = en.x, s = en.y & 0xFFFF, t = en.y >> 16;
            const float* hr = y1 + (size_t)s * 64;
            float acc = 0.f;
            #pragma unroll
            for (int ks = 0; ks < 4; ++ks) {
                #pragma unroll
                for (int hf = 0; hf < 2; ++hf) {
                    int kb = ks * 16 + hf * 8;
                    float4 g0 = *(const float4*)(hr + kb);
                    float4 g1 = *(const float4*)(hr + kb + 4);
                    float xv[8];
                    xv[0] = g0.x; xv[1] = g0.y; xv[2] = g0.z; xv[3] = g0.w;
                    xv[4] = g1.x; xv[5] = g1.y; xv[6] = g1.z; xv[7] = g1.w;
                    #pragma unroll
                    for (int j = 0; j < 8; ++j)
                        xv[j] = fmaxf(xv[j] * scs[kb + j] + shs[kb + j], 0.f);
                    bf16x8 wv = wb[((size_t)(t * 4 + ks) * 2 + ch) * 64 + hf * 32 + lcol];
                    #pragma unroll
                    for (int j = 0; j < 8; ++j)
                        acc += xv[j] * bf2f(wv[j]);
                }
            }
            float old = atomicAdd(&y[(size_t)i * 64 + c], acc);
            atomicAdd(&bs[c], acc);
            atomicAdd(&bq[c], acc * (acc + 2.f * old));
        }
        __syncthreads();
        if (tid < 64) {
            atomicAdd(&ostats[tid], bs[tid]);
            atomicAdd(&ostats[64 + tid], bq[tid]);
        }
        return;
    }
    int bt = blockIdx.x - nExtB;
    if (bt >= n_tiles[0]) return;
    int4 td = tiles[bt];
    int mask = td.x, p_start = td.y, lt = td.z, cntb = td.w;
    if (tid < 128) {
        int li = lt + (tid >> 2);
        int pid = perm_par[p_start + ((li < cntb) ? li : 0)];
        int i = perm_rows[pid * 4 + (tid & 3)];
        unsigned fb = (flagbits[i >> 5] >> (i & 31)) & 1u;
        srows[tid] = i | (int)(fb << 30);
    } else if (tid < 192) {
        int cc = tid - 128;
        float inv = 1.0f / (float)n2;
        float mean = stats[cc] * inv;
        float var = stats[64 + cc] * inv - mean * mean;
        float s = gamma[cc] * rsqrtf(var + 1e-5f);
        scs[cc] = s; shs[cc] = beta[cc] - mean * s;
    } else if (tid < 256) {
        int cc = tid - 192;
        bs[cc] = 0.f; bq[cc] = 0.f;
    }
    __syncthreads();
    #pragma unroll
    for (int it = 0; it < 2; ++it) {
        int c0 = it * 512 + tid;
        int pl = c0 >> 5, w8 = c0 & 31;
        int j = w8 >> 3, col8 = w8 & 7;
        const float* fr = y1 + (size_t)(srows[pl * 4 + j] & ROWM) * 64 + col8 * 8;
        float4 f0 = *(const float4*)fr;
        float4 f1v = *(const float4*)(fr + 4);
        short o[8];
        #pragma unroll
        for (int u = 0; u < 4; ++u) {
            int cc = col8 * 8 + u;
            float v = (u == 0) ? f0.x : (u == 1) ? f0.y : (u == 2) ? f0.z : f0.w;
            o[u] = f2bf(fmaxf(v * scs[cc] + shs[cc], 0.f));
        }
        #pragma unroll
        for (int u = 0; u < 4; ++u) {
            int cc = col8 * 8 + 4 + u;
            float v = (u == 0) ? f1v.x : (u == 1) ? f1v.y : (u == 2) ? f1v.z : f1v.w;
            o[4 + u] = f2bf(fmaxf(v * scs[cc] + shs[cc], 0.f));
        }
        short* d = &lds[pl * LP + j * 64 + col8 * 8];
        *(int2*)d = make_int2(((int)(unsigned short)o[0]) | ((int)o[1] << 16),
                              ((int)(unsigned short)o[2]) | ((int)o[3] << 16));
        *(int2*)(d + 4) = make_int2(((int)(unsigned short)o[4]) | ((int)o[5] << 16),
                                    ((int)(unsigned short)o[6]) | ((int)o[7] << 16));
    }
    int p0 = -1, p1 = -1, p2 = -1, p3 = -1;
    #pragma unroll
    for (int b = 7; b >= 0; --b)
        if ((mask >> b) & 1) { p3 = p2; p2 = p1; p1 = p0; p0 = b; }
    int w = tid >> 6, lane = tid & 63;
    int asub = w >> 1, ch = w & 1;
    int pa = (asub == 0) ? p0 : (asub == 1) ? p1 : (asub == 2) ? p2 : p3;
    int t0 = tap27(pa, p0), t1 = tap27(pa, p1), t2 = tap27(pa, p2), t3 = tap27(pa, p3);
    int m = lane & 31, half = lane >> 5;
    int li = lt + m;
    bool vp = li < cntb;
    int outrow = vp ? srows[m * 4 + asub] : -1;
    __syncthreads();
    f32x16 acc;
    #pragma unroll
    for (int i = 0; i < 16; ++i) acc[i] = 0.f;
    const bf16x8* bp = (const bf16x8*)wp;
    #pragma unroll
    for (int b = 0; b < 4; ++b) {
        int tb = (b == 0) ? t0 : (b == 1) ? t1 : (b == 2) ? t2 : t3;
        #pragma unroll
        for (int kk = 0; kk < 4; ++kk) {
            int ks = b * 4 + kk;
            const short* ap = &lds[m * LP + ks * 16 + half * 8];
            bf16x4 lo = *(const bf16x4*)ap, hi = *(const bf16x4*)(ap + 4);
            bf16x8 a = __builtin_shufflevector(lo, hi, 0, 1, 2, 3, 4, 5, 6, 7);
            bf16x8 b0 = bp[((size_t)(tb * 4 + kk) * 2 + ch) * 64 + lane];
            acc = __builtin_amdgcn_mfma_f32_32x32x16_bf16(a, b0, acc, 0, 0, 0);
        }
    }
    pair_epi1(acc, outrow, lane, ch, y, bs, bq);
    __syncthreads();
    if (tid < 64) {
        atomicAdd(&ostats[tid], bs[tid]);
        atomicAdd(&ostats[64 + tid], bq[tid]);
    }
}

// ---------------- BN finalize + ReLU -> f32 output ---------------------------
__global__ __launch_bounds__(256) void k_final(
    const float* __restrict__ y, const float* __restrict__ gamma,
    const float* __restrict__ beta, const float* __restrict__ stats,
    float* __restrict__ out, int n2)
{
    __shared__ float sc[64], sh[64];
    int tid = threadIdx.x;
    if (tid < 64) {
        float inv = 1.0f / (float)n2;
        float mean = stats[tid] * inv;
        float var = stats[64 + tid] * inv - mean * mean;
        float s = gamma[tid] * rsqrtf(var + 1e-5f);
        sc[tid] = s;
        sh[tid] = beta[tid] - mean * s;
    }
    __syncthreads();
    long long total = (long long)n2 * 16;
    long long stride = (long long)gridDim.x * blockDim.x;
    for (long long idx = (long long)blockIdx.x * blockDim.x + tid; idx < total; idx += stride) {
        int i = (int)(idx >> 4);
        int c4 = ((int)idx & 15) * 4;
        const float* src = y + (size_t)i * 64 + c4;
        float4 o;
        o.x = fmaxf(src[0] * sc[c4 + 0] + sh[c4 + 0], 0.f);
        o.y = fmaxf(src[1] * sc[c4 + 1] + sh[c4 + 1], 0.f);
        o.z = fmaxf(src[2] * sc[c4 + 2] + sh[c4 + 2], 0.f);
        o.w = fmaxf(src[3] * sc[c4 + 3] + sh[c4 + 3], 0.f);
        *(float4*)(out + (size_t)i * 64 + c4) = o;
    }
}

extern "C" void kernel_launch(void* const* d_in, const int* in_sizes, int n_in,
                              void* d_out, int out_size, void* d_ws, size_t ws_size,
                              hipStream_t stream)
{
    const float* feats1   = (const float*)d_in[0];
    const float* feats2   = (const float*)d_in[1];
    const float* w_up     = (const float*)d_in[2];
    const float* gamma_up = (const float*)d_in[3];
    const float* beta_up  = (const float*)d_in[4];
    const float* w1       = (const float*)d_in[5];
    const float* gamma1   = (const float*)d_in[6];
    const float* beta1    = (const float*)d_in[7];
    const float* w2       = (const float*)d_in[8];
    const float* gamma2   = (const float*)d_in[9];
    const float* beta2    = (const float*)d_in[10];
    const int* up_src     = (const int*)d_in[11];  (void)up_src;
    const int* up_kidx    = (const int*)d_in[12];
    const int* nbr_src    = (const int*)d_in[13];
    // d_in[14] nbr_dst unused: nbr_dst[t,i] ∈ {i, N2} by construction

    int n1 = in_sizes[0] / 128;
    int n2 = in_sizes[1] / 64;

    char* p = (char*)d_ws;
    auto alloc = [&](size_t bytes) {
        char* r = p;
        p += (bytes + 255) & ~(size_t)255;
        return r;
    };
    float* stats    = (float*)alloc(384 * 4);
    int*   cnt      = (int*)alloc(256 * 4);
    int*   extc     = (int*)alloc(16);
    int*   ntl      = (int*)alloc(16);
    unsigned* flagbits = (unsigned*)alloc(((size_t)(n2 + 31) / 32) * 4);
    size_t headBytes = (size_t)(p - (char*)d_ws);
    int maxTiles    = (n1 + 31) / 32 + 80;
    int4*  tiles    = (int4*)alloc((size_t)maxTiles * 16);
    short* wupp     = (short*)alloc((size_t)65536 * 2);
    short* w1p      = (short*)alloc((size_t)221184 * 2);
    short* w2p      = (short*)alloc((size_t)110592 * 2);
    short* f1bf     = (short*)alloc((size_t)n1 * 128 * 2);
    int*   pmask    = (int*)alloc((size_t)n1 * 4);
    int*   rank     = (int*)alloc((size_t)n1 * 4);
    int*   perm_par = (int*)alloc((size_t)n1 * 4);
    int*   perm_rows= (int*)alloc((size_t)4 * n1 * 4);
    int2*  ext      = (int2*)alloc((size_t)27 * n2 * 8);
    short* yup8     = (short*)alloc((size_t)n1 * 512 * 2);
    float* y1       = (float*)alloc((size_t)n2 * 64 * 4);
    float* y2       = (float*)alloc((size_t)n2 * 64 * 4);

    int nbExt  = (n2 + 255) / 256;
    int nbGeom = (n1 + 255) / 256;
    int nbPack = 128;
    int nbSetup = nbGeom + nbPack;
    int nt = (n1 + 31) / 32;
    int upBlocks = 1 + 2 * nt + 256 + 64 + nbExt;
    int ewBlocks16 = (int)(((long long)n2 * 16 + 255) / 256);
    const int EXTB = 128;   // R17 optimum: 658 total pair blocks, co-resident

    hipMemsetAsync(d_ws, 0, headBytes, stream);
    k_setup<<<nbSetup, 256, 0, stream>>>(w_up, feats1, up_kidx, wupp, f1bf,
                                         pmask, perm_rows, rank, cnt,
                                         n1, nbGeom);
    k_up<<<upBlocks, 256, 0, stream>>>(f1bf, wupp, pmask, cnt, rank, perm_par,
                                       tiles, ntl, yup8, stats,
                                       w1, w2, w1p, w2p, nbr_src, ext, extc,
                                       flagbits, y1, y2, n1, n2, nt, nbExt);
    k_pairA<<<EXTB + maxTiles, 512, 0, stream>>>(yup8, feats2, up_kidx, w1p,
                                                 gamma_up, beta_up, stats,
                                                 perm_par, perm_rows, tiles, ntl,
                                                 ext, extc, flagbits,
                                                 y1, stats + 128, n2, EXTB);
    k_pairB<<<EXTB + maxTiles, 512, 0, stream>>>(y1, w2p, gamma1, beta1,
                                                 stats + 128, perm_par,
                                                 perm_rows, tiles, ntl,
                                                 ext, extc, flagbits,
                                                 y2, stats + 256, n2, EXTB);
    k_final<<<ewBlocks16, 256, 0, stream>>>(y2, gamma2, beta2, stats + 256,
                                            (float*)d_out, n2);
}

// Round 14
// 226.716 us; speedup vs baseline: 1.1012x; 1.0155x over previous
//
#include <hip/hip_runtime.h>

// Round 23: co-residency compaction of k_up (R21's lesson applied to the
// other over-subscribed dispatch). k_up grid 1494 -> 1249 blocks: zero role
// 256->128 blocks (2x grid-stride), ext-scan role 235->118 blocks (2 row
// chunks per block, compaction protocol looped with per-trip barriers).
// k_final 3750 -> 1024 blocks (grid-stride). Everything else verbatim R17
// (best verified 222.6us, absmax 0.03125; R22 re-measure 230.2 = noise).

typedef short bf16x4 __attribute__((ext_vector_type(4)));
typedef short bf16x8 __attribute__((ext_vector_type(8)));
typedef float f32x16 __attribute__((ext_vector_type(16)));

#define ROWM 0xFFFFF
#define RFLAG (1 << 30)

__device__ __forceinline__ short f2bf(float f) {
    unsigned u = __float_as_uint(f);
    u += 0x7fffu + ((u >> 16) & 1u);
    return (short)(u >> 16);
}
__device__ __forceinline__ float bf2f(short s) {
    return __uint_as_float(((unsigned)(unsigned short)s) << 16);
}

// ---------------- setup: geometry + {wupp, f1bf} pack (vec8) ----------------
__global__ __launch_bounds__(256) void k_setup(
    const float* __restrict__ w_up, const float* __restrict__ f1,
    const int* __restrict__ up_kidx,
    short* __restrict__ wupp, short* __restrict__ f1bf,
    int* __restrict__ pmask, int* __restrict__ perm_rows,
    int* __restrict__ rank, int* __restrict__ cnt,
    int n1, int nbGeom)
{
    int tid = threadIdx.x;
    int bid = blockIdx.x;
    if (bid < nbGeom) {
        int p = bid * 256 + tid;
        if (p >= n1) return;
        int4 kd = *(const int4*)(up_kidx + 4 * p);
        int a = kd.x * 4 + 0, b = kd.y * 4 + 1, c = kd.z * 4 + 2, d = kd.w * 4 + 3;
        int t;
        if (a > b) { t = a; a = b; b = t; }
        if (c > d) { t = c; c = d; d = t; }
        if (a > c) { t = a; a = c; c = t; }
        if (b > d) { t = b; b = d; d = t; }
        if (b > c) { t = b; b = c; c = t; }
        perm_rows[4 * p + 0] = 4 * p + (a & 3);
        perm_rows[4 * p + 1] = 4 * p + (b & 3);
        perm_rows[4 * p + 2] = 4 * p + (c & 3);
        perm_rows[4 * p + 3] = 4 * p + (d & 3);
        int mask = (1 << (a >> 2)) | (1 << (b >> 2)) | (1 << (c >> 2)) | (1 << (d >> 2));
        pmask[p] = mask;
        rank[p] = atomicAdd(&cnt[mask], 1);
    } else {
        const int nup8 = 8192;
        int tot = nup8 + n1 * 16;
        int gs = (gridDim.x - nbGeom) * 256;
        for (int e8 = (bid - nbGeom) * 256 + tid; e8 < tot; e8 += gs) {
            if (e8 < nup8) {        // Wcat[128][512] -> [ks8][nt16][64][8]
                int l = e8 & 63, nt = (e8 >> 6) & 15, ks = e8 >> 10;
                int kb = ks * 16 + (l >> 5) * 8;
                int col = nt * 32 + (l & 31);
                const float* src = w_up + (size_t)(col >> 6) * 8192 + (size_t)kb * 64 + (col & 63);
                bf16x8 o;
                #pragma unroll
                for (int j = 0; j < 8; ++j) o[j] = f2bf(src[(size_t)j * 64]);
                *(bf16x8*)(wupp + (size_t)e8 * 8) = o;
            } else {
                int g = e8 - nup8;
                const float* src = f1 + (size_t)g * 8;
                float4 a = *(const float4*)src;
                float4 b = *(const float4*)(src + 4);
                bf16x8 o;
                o[0] = f2bf(a.x); o[1] = f2bf(a.y); o[2] = f2bf(a.z); o[3] = f2bf(a.w);
                o[4] = f2bf(b.x); o[5] = f2bf(b.y); o[6] = f2bf(b.z); o[7] = f2bf(b.w);
                *(bf16x8*)(f1bf + (size_t)g * 8) = o;
            }
        }
    }
}

// ------- dense up-GEMM + masked BN stats; block 0 = scan; aux role-blocks ----
// Aux roles compacted (R23): zero=128 blocks, pack=64, ext-scan=ceil(n2/512).
__global__ __launch_bounds__(256) void k_up(
    const short* __restrict__ f1bf, const short* __restrict__ wupp,
    const int* __restrict__ pmask, const int* __restrict__ cnt,
    const int* __restrict__ rank, int* __restrict__ perm_par,
    int4* __restrict__ tiles, int* __restrict__ ntl,
    short* __restrict__ yup8, float* __restrict__ stats,
    const float* __restrict__ w1, const float* __restrict__ w2,
    short* __restrict__ w1p, short* __restrict__ w2p,
    const int* __restrict__ nbr, int2* __restrict__ ext,
    int* __restrict__ extc, unsigned* __restrict__ flagbits,
    float* __restrict__ y1, float* __restrict__ y2,
    int n1, int n2, int nt)
{
    int gemmEnd = 1 + 2 * nt;
    if (blockIdx.x == 0) {
        __shared__ int sA[256], sB[256], bb[256];
        int t = threadIdx.x;
        int c = cnt[t], tc = (c + 31) >> 5;
        sA[t] = c; sB[t] = tc;
        __syncthreads();
        for (int off = 1; off < 256; off <<= 1) {
            int a = (t >= off) ? sA[t - off] : 0;
            int b = (t >= off) ? sB[t - off] : 0;
            __syncthreads();
            sA[t] += a; sB[t] += b;
            __syncthreads();
        }
        int base = sA[t] - c, toff = sB[t] - tc;
        bb[t] = base;
        for (int j = 0; j < tc; ++j) tiles[toff + j] = make_int4(t, base, j * 32, c);
        if (t == 255) ntl[0] = sB[255];
        __syncthreads();
        for (int p = t; p < n1; p += 256)
            perm_par[bb[pmask[p]] + rank[p]] = p;
        return;
    }
    if (blockIdx.x >= gemmEnd) {
        int ab = blockIdx.x - gemmEnd;
        int tid = threadIdx.x;
        if (ab < 128) {
            // zero y1/y2 (float4 grid-stride, 128 blocks)
            long long tot = (long long)n2 * 16;
            float4 z = make_float4(0.f, 0.f, 0.f, 0.f);
            for (long long e = (long long)ab * 256 + tid; e < tot; e += 128LL * 256) {
                ((float4*)y1)[e] = z;
                ((float4*)y2)[e] = z;
            }
        } else if (ab < 192) {
            const int nw18 = 27648, tot = 27648 + 13824;
            for (int e8 = (ab - 128) * 256 + tid; e8 < tot; e8 += 64 * 256) {
                if (e8 < nw18) {     // [27][8][2][64][8]
                    int l = e8 & 63, ch = (e8 >> 6) & 1, ks = (e8 >> 7) & 7, t = e8 >> 10;
                    int kb = ks * 16 + (l >> 5) * 8;
                    int col = ch * 32 + (l & 31);
                    const float* src = w1 + (size_t)t * 8192 + (size_t)kb * 64 + col;
                    bf16x8 o;
                    #pragma unroll
                    for (int j = 0; j < 8; ++j) o[j] = f2bf(src[(size_t)j * 64]);
                    *(bf16x8*)(w1p + (size_t)e8 * 8) = o;
                } else {             // [27][4][2][64][8]
                    int g = e8 - nw18;
                    int l = g & 63, ch = (g >> 6) & 1, ks = (g >> 7) & 3, t = g >> 9;
                    int kb = ks * 16 + (l >> 5) * 8;
                    int col = ch * 32 + (l & 31);
                    const float* src = w2 + (size_t)t * 4096 + (size_t)kb * 64 + col;
                    bf16x8 o;
                    #pragma unroll
                    for (int j = 0; j < 8; ++j) o[j] = f2bf(src[(size_t)j * 64]);
                    *(bf16x8*)(w2p + (size_t)g * 8) = o;
                }
            }
        } else {
            // 27-tap ext scan: 2 row-chunks per block, per-trip barriers
            __shared__ int lcnt, lbase;
            int base = (ab - 192) * 512;
            #pragma unroll
            for (int rep = 0; rep < 2; ++rep) {
                int i = base + rep * 256 + tid;
                unsigned hm = 0;
                if (i < n2) {
                    #pragma unroll
                    for (int t = 0; t < 27; ++t) {
                        int s = nbr[(size_t)t * n2 + i];
                        if (s < n2 && (s >> 2) != (i >> 2)) hm |= 1u << t;
                    }
                }
                if (hm) atomicOr(&flagbits[i >> 5], 1u << (i & 31));
                if (tid == 0) lcnt = 0;
                __syncthreads();
                int nh = __popc(hm);
                int myofs = 0;
                if (nh) myofs = atomicAdd(&lcnt, nh);
                __syncthreads();
                if (tid == 0 && lcnt) lbase = atomicAdd(extc, lcnt);
                __syncthreads();
                if (nh) {
                    int pos = lbase + myofs;
                    unsigned m = hm;
                    while (m) {
                        int t = __ffs(m) - 1;
                        m &= m - 1;
                        int s = nbr[(size_t)t * n2 + i];
                        ext[pos++] = make_int2(i, s | (t << 16));
                    }
                }
                __syncthreads();
            }
        }
        return;
    }
    __shared__ short lds[32 * 136];                  // stride 68 words ≡ 4 mod 32
    __shared__ float bs[64], bq[64];
    int bid = blockIdx.x - 1;
    int tile = bid >> 1;
    int w = threadIdx.x >> 6, lane = threadIdx.x & 63;
    int na = (bid & 1) * 8 + w, nb = na + 4;
    if (threadIdx.x < 64) { bs[threadIdx.x] = 0.f; bq[threadIdx.x] = 0.f; }
    #pragma unroll
    for (int it = 0; it < 2; ++it) {
        int c = it * 256 + threadIdx.x;
        int row = c >> 4, col8 = c & 15;
        int gr = tile * 32 + row; if (gr >= n1) gr = n1 - 1;
        int4 g = *(const int4*)(f1bf + (size_t)gr * 128 + col8 * 8);
        short* d = &lds[row * 136 + col8 * 8];
        *(int2*)d = make_int2(g.x, g.y);
        *(int2*)(d + 4) = make_int2(g.z, g.w);
    }
    int m = lane & 31, half = lane >> 5;
    int pm_l = (tile * 32 + m < n1) ? pmask[tile * 32 + m] : 0;
    __syncthreads();
    f32x16 a0, a1;
    #pragma unroll
    for (int i = 0; i < 16; ++i) { a0[i] = 0.f; a1[i] = 0.f; }
    const bf16x8* bp = (const bf16x8*)wupp;
    #pragma unroll
    for (int ks = 0; ks < 8; ++ks) {
        const short* ap = &lds[m * 136 + ks * 16 + half * 8];
        bf16x4 lo = *(const bf16x4*)ap, hi = *(const bf16x4*)(ap + 4);
        bf16x8 a = __builtin_shufflevector(lo, hi, 0, 1, 2, 3, 4, 5, 6, 7);
        bf16x8 b0 = bp[(size_t)(ks * 16 + na) * 64 + lane];
        bf16x8 b1 = bp[(size_t)(ks * 16 + nb) * 64 + lane];
        a0 = __builtin_amdgcn_mfma_f32_32x32x16_bf16(a, b0, a0, 0, 0, 0);
        a1 = __builtin_amdgcn_mfma_f32_32x32x16_bf16(a, b1, a1, 0, 0, 0);
    }
    int col = lane & 31;
    #pragma unroll
    for (int pass = 0; pass < 2; ++pass) {
        const f32x16& acc = pass ? a1 : a0;
        int n = pass ? nb : na;
        int slot = n >> 1, c = (n & 1) * 32 + col;
        float s0 = 0.f, q0 = 0.f;
        #pragma unroll
        for (int reg = 0; reg < 16; ++reg) {
            int r = (reg & 3) + 8 * (reg >> 2) + 4 * half;
            int p = tile * 32 + r;
            float v = acc[reg];
            int mk = __shfl(pm_l, r);
            if (p < n1) {
                yup8[(size_t)p * 512 + n * 32 + col] = f2bf(v);
                if ((mk >> slot) & 1) { s0 += v; q0 += v * v; }
            }
        }
        s0 += __shfl_xor(s0, 32);
        q0 += __shfl_xor(q0, 32);
        if (lane < 32) { atomicAdd(&bs[c], s0); atomicAdd(&bq[c], q0); }
    }
    __syncthreads();
    if (threadIdx.x < 64) {
        atomicAdd(&stats[threadIdx.x], bs[threadIdx.x]);
        atomicAdd(&stats[64 + threadIdx.x], bq[threadIdx.x]);
    }
}

// ---- conv epilogue (1 acc/wave): overwrite unflagged; atomic+q-corr flagged -
__device__ __forceinline__ void pair_epi1(const f32x16& av, int outrow,
                                          int lane, int ch,
                                          float* __restrict__ y,
                                          float* __restrict__ bs,
                                          float* __restrict__ bq)
{
    int col = lane & 31;
    int c = ch * 32 + col;
    float s0 = 0.f, q0 = 0.f;
    #pragma unroll
    for (int reg = 0; reg < 16; ++reg) {
        int r = (reg & 3) + 8 * (reg >> 2) + 4 * (lane >> 5);
        int r0 = __shfl(outrow, r);
        if (r0 >= 0) {
            float v = av[reg];
            size_t ad = (size_t)(r0 & ROWM) * 64 + c;
            if (r0 & RFLAG) {
                float old = atomicAdd(&y[ad], v);
                s0 += v; q0 += v * (v + 2.f * old);
            } else {
                y[ad] = v; s0 += v; q0 += v * v;
            }
        }
    }
    s0 += __shfl_xor(s0, 32);
    q0 += __shfl_xor(q0, 32);
    if (lane < 32) { atomicAdd(&bs[c], s0); atomicAdd(&bq[c], q0); }
}

__device__ __forceinline__ int tap27(int pa, int pb) {
    int di = ((pb >> 2) & 1) - ((pa >> 2) & 1);
    int dj = ((pb >> 1) & 1) - ((pa >> 1) & 1);
    int dk = (pb & 1) - (pa & 1);
    return (di + 1) * 9 + (dj + 1) * 3 + (dk + 1);
}

// conv1: blocks [0,nExtB) = vectorized ext gather; rest = 8-wave MFMA tiles
__global__ __launch_bounds__(512) void k_pairA(
    const short* __restrict__ yup8, const float* __restrict__ f2,
    const int* __restrict__ up_kidx, const short* __restrict__ wp,
    const float* __restrict__ gamma, const float* __restrict__ beta,
    const float* __restrict__ stats, const int* __restrict__ perm_par,
    const int* __restrict__ perm_rows, const int4* __restrict__ tiles,
    const int* __restrict__ n_tiles, const int2* __restrict__ ext,
    const int* __restrict__ extc, const unsigned* __restrict__ flagbits,
    float* __restrict__ y, float* __restrict__ ostats, int n2, int nExtB)
{
    constexpr int LP = 520;                   // 260 words ≡ 4 mod 32: b128-clean
    __shared__ short lds[32 * LP];
    __shared__ int srows[128], soff[128];
    __shared__ float scs[64], shs[64], bs[64], bq[64];
    int tid = threadIdx.x;
    if (blockIdx.x < nExtB) {                 // ---- ext role (order-free) ----
        if (tid < 64) {
            float inv = 1.0f / (float)n2;
            float mean = stats[tid] * inv;
            float var = stats[64 + tid] * inv - mean * mean;
            float s = gamma[tid] * rsqrtf(var + 1e-5f);
            scs[tid] = s; shs[tid] = beta[tid] - mean * s;
            bs[tid] = 0.f; bq[tid] = 0.f;
        }
        __syncthreads();
        int gw = (blockIdx.x * 512 + tid) >> 6;
        int nw = nExtB * 8;
        int c = tid & 63;
        int ch = c >> 5, lcol = c & 31;
        int ec = extc[0];
        const bf16x8* wb = (const bf16x8*)wp;
        for (int e = gw; e < ec; e += nw) {
            int2 en = ext[e];
            int i = en.x, s = en.y & 0xFFFF, t = en.y >> 16;
            const short* xr = yup8 + (size_t)(s >> 2) * 512 + up_kidx[s] * 64;
            const float* fr = f2 + (size_t)s * 64;
            float acc = 0.f;
            #pragma unroll
            for (int ks = 0; ks < 8; ++ks) {
                #pragma unroll
                for (int hf = 0; hf < 2; ++hf) {
                    int kb = ks * 16 + hf * 8;
                    float xv[8];
                    if (kb < 64) {            // bn_relu(yup8) half
                        bf16x8 g = *(const bf16x8*)(xr + kb);
                        #pragma unroll
                        for (int j = 0; j < 8; ++j)
                            xv[j] = fmaxf(bf2f(g[j]) * scs[kb + j] + shs[kb + j], 0.f);
                    } else {                  // raw f2 half
                        float4 g0 = *(const float4*)(fr + kb - 64);
                        float4 g1 = *(const float4*)(fr + kb - 60);
                        xv[0] = g0.x; xv[1] = g0.y; xv[2] = g0.z; xv[3] = g0.w;
                        xv[4] = g1.x; xv[5] = g1.y; xv[6] = g1.z; xv[7] = g1.w;
                    }
                    bf16x8 wv = wb[((size_t)(t * 8 + ks) * 2 + ch) * 64 + hf * 32 + lcol];
                    #pragma unroll
                    for (int j = 0; j < 8; ++j)
                        acc += xv[j] * bf2f(wv[j]);
                }
            }
            float old = atomicAdd(&y[(size_t)i * 64 + c], acc);
            atomicAdd(&bs[c], acc);
            atomicAdd(&bq[c], acc * (acc + 2.f * old));
        }
        __syncthreads();
        if (tid < 64) {
            atomicAdd(&ostats[tid], bs[tid]);
            atomicAdd(&ostats[64 + tid], bq[tid]);
        }
        return;
    }
    int bt = blockIdx.x - nExtB;
    if (bt >= n_tiles[0]) return;
    int4 td = tiles[bt];
    int mask = td.x, p_start = td.y, lt = td.z, cntb = td.w;
    if (tid < 128) {
        int li = lt + (tid >> 2);
        int pid = perm_par[p_start + ((li < cntb) ? li : 0)];
        int i = perm_rows[pid * 4 + (tid & 3)];
        unsigned fb = (flagbits[i >> 5] >> (i & 31)) & 1u;
        srows[tid] = i | (int)(fb << 30);
        soff[tid] = (i >> 2) * 512 + up_kidx[i] * 64;
    } else if (tid < 192) {
        int cc = tid - 128;
        float inv = 1.0f / (float)n2;
        float mean = stats[cc] * inv;
        float var = stats[64 + cc] * inv - mean * mean;
        float s = gamma[cc] * rsqrtf(var + 1e-5f);
        scs[cc] = s; shs[cc] = beta[cc] - mean * s;
    } else if (tid < 256) {
        int cc = tid - 192;
        bs[cc] = 0.f; bq[cc] = 0.f;
    }
    __syncthreads();
    #pragma unroll
    for (int it = 0; it < 4; ++it) {
        int c0 = it * 512 + tid;
        int pl = c0 >> 6, w8 = c0 & 63;
        int j = w8 >> 4, col8 = w8 & 15;
        short* d = &lds[pl * LP + j * 128 + col8 * 8];
        if (col8 < 8) {
            bf16x8 g = *(const bf16x8*)(yup8 + (size_t)soff[pl * 4 + j] + col8 * 8);
            short o[8];
            #pragma unroll
            for (int u = 0; u < 8; ++u) {
                int cc = col8 * 8 + u;
                o[u] = f2bf(fmaxf(bf2f(g[u]) * scs[cc] + shs[cc], 0.f));
            }
            *(int2*)d = make_int2(((int)(unsigned short)o[0]) | ((int)o[1] << 16),
                                  ((int)(unsigned short)o[2]) | ((int)o[3] << 16));
            *(int2*)(d + 4) = make_int2(((int)(unsigned short)o[4]) | ((int)o[5] << 16),
                                        ((int)(unsigned short)o[6]) | ((int)o[7] << 16));
        } else {
            const float* fr = f2 + (size_t)(srows[pl * 4 + j] & ROWM) * 64 + (col8 - 8) * 8;
            float4 f0 = *(const float4*)fr;
            float4 f1v = *(const float4*)(fr + 4);
            short o[8] = {f2bf(f0.x), f2bf(f0.y), f2bf(f0.z), f2bf(f0.w),
                          f2bf(f1v.x), f2bf(f1v.y), f2bf(f1v.z), f2bf(f1v.w)};
            *(int2*)d = make_int2(((int)(unsigned short)o[0]) | ((int)o[1] << 16),
                                  ((int)(unsigned short)o[2]) | ((int)o[3] << 16));
            *(int2*)(d + 4) = make_int2(((int)(unsigned short)o[4]) | ((int)o[5] << 16),
                                        ((int)(unsigned short)o[6]) | ((int)o[7] << 16));
        }
    }
    int p0 = -1, p1 = -1, p2 = -1, p3 = -1;
    #pragma unroll
    for (int b = 7; b >= 0; --b)
        if ((mask >> b) & 1) { p3 = p2; p2 = p1; p1 = p0; p0 = b; }
    int w = tid >> 6, lane = tid & 63;
    int asub = w >> 1, ch = w & 1;
    int pa = (asub == 0) ? p0 : (asub == 1) ? p1 : (asub == 2) ? p2 : p3;
    int t0 = tap27(pa, p0), t1 = tap27(pa, p1), t2 = tap27(pa, p2), t3 = tap27(pa, p3);
    int m = lane & 31, half = lane >> 5;
    int li = lt + m;
    bool vp = li < cntb;
    int outrow = vp ? srows[m * 4 + asub] : -1;
    __syncthreads();
    f32x16 acc;
    #pragma unroll
    for (int i = 0; i < 16; ++i) acc[i] = 0.f;
    const bf16x8* bp = (const bf16x8*)wp;
    #pragma unroll
    for (int b = 0; b < 4; ++b) {
        int tb = (b == 0) ? t0 : (b == 1) ? t1 : (b == 2) ? t2 : t3;
        #pragma unroll
        for (int kk = 0; kk < 8; ++kk) {
            int ks = b * 8 + kk;
            const short* ap = &lds[m * LP + ks * 16 + half * 8];
            bf16x4 lo = *(const bf16x4*)ap, hi = *(const bf16x4*)(ap + 4);
            bf16x8 a = __builtin_shufflevector(lo, hi, 0, 1, 2, 3, 4, 5, 6, 7);
            bf16x8 b0 = bp[((size_t)(tb * 8 + kk) * 2 + ch) * 64 + lane];
            acc = __builtin_amdgcn_mfma_f32_32x32x16_bf16(a, b0, acc, 0, 0, 0);
        }
    }
    pair_epi1(acc, outrow, lane, ch, y, bs, bq);
    __syncthreads();
    if (tid < 64) {
        atomicAdd(&ostats[tid], bs[tid]);
        atomicAdd(&ostats[64 + tid], bq[tid]);
    }
}

// conv2: blocks [0,nExtB) = vectorized ext gather; rest = 8-wave MFMA tiles
__global__ __launch_bounds__(512) void k_pairB(
    const float* __restrict__ y1, const short* __restrict__ wp,
    const float* __restrict__ gamma, const float* __restrict__ beta,
    const float* __restrict__ stats, const int* __restrict__ perm_par,
    const int* __restrict__ perm_rows, const int4* __restrict__ tiles,
    const int* __restrict__ n_tiles, const int2* __restrict__ ext,
    const int* __restrict__ extc, const unsigned* __restrict__ flagbits,
    float* __restrict__ y, float* __restrict__ ostats, int n2, int nExtB)
{
    constexpr int LP = 264;                   // 132 words ≡ 4 mod 32
    __shared__ short lds[32 * LP];
    __shared__ int srows[128];
    __shared__ float scs[64], shs[64], bs[64], bq[64];
    int tid = threadIdx.x;
    if (blockIdx.x < nExtB) {                 // ---- ext role (order-free) ----
        if (tid < 64) {
            float inv = 1.0f / (float)n2;
            float mean = stats[tid] * inv;
            float var = stats[64 + tid] * inv - mean * mean;
            float s = gamma[tid] * rsqrtf(var + 1e-5f);
            scs[tid] = s; shs[tid] = beta[tid] - mean * s;
            bs[tid] = 0.f; bq[tid] = 0.f;
        }
        __syncthreads();
        int gw = (blockIdx.x * 512 + tid) >> 6;
        int nw = nExtB * 8;
        int c = tid & 63;
        int ch = c >> 5, lcol = c & 31;
        int ec = extc[0];
        const bf16x8* wb = (const bf16x8*)wp;
        for (int e = gw; e < ec; e += nw) {
            int2 en = ext[e];
            int i = en.x, s = en.y & 0xFFFF, t = en.y >> 16;
            const float* hr = y1 + (size_t)s * 64;
            float acc = 0.f;
            #pragma unroll
            for (int ks = 0; ks < 4; ++ks) {
                #pragma unroll
                for (int hf = 0; hf < 2; ++hf) {
                    int kb = ks * 16 + hf * 8;
                    float4 g0 = *(const float4*)(hr + kb);
                    float4 g1 = *(const float4*)(hr + kb + 4);
                    float xv[8];
                    xv[0] = g0.x; xv[1] = g0.y; xv[2] = g0.z; xv[3] = g0.w;
                    xv[4] = g1.x; xv[5] = g1.y; xv[6] = g1.z; xv[7] = g1.w;
                    #pragma unroll
                    for (int j = 0; j < 8; ++j)
                        xv[j] = fmaxf(xv[j] * scs[kb + j] + shs[kb + j], 0.f);
                    bf16x8 wv = wb[((size_t)(t * 4 + ks) * 2 + ch) * 64 + hf * 32 + lcol];
                    #pragma unroll
                    for (int j = 0; j < 8; ++j)
                        acc += xv[j] * bf2f(wv[j]);
                }
            }
            float old = atomicAdd(&y[(size_t)i * 64 + c], acc);
            atomicAdd(&bs[c], acc);
            atomicAdd(&bq[c], acc * (acc + 2.f * old));
        }
        __syncthreads();
        if (tid < 64) {
            atomicAdd(&ostats[tid], bs[tid]);
            atomicAdd(&ostats[64 + tid], bq[tid]);
        }
        return;
    }
    int bt = blockIdx.x - nExtB;
    if (bt >= n_tiles[0]) return;
    int4 td = tiles[bt];
    int mask = td.x, p_start = td.y, lt = td.z, cntb = td.w;
    if (tid < 128) {
        int li = lt + (tid >> 2);
        int pid = perm_par[p_start + ((li < cntb) ? li : 0)];
        int i = perm_rows[pid * 4 + (tid & 3)];
        unsigned fb = (flagbits[i >> 5] >> (i & 31)) & 1u;
        srows[tid] = i | (int)(fb << 30);
    } else if (tid < 192) {
        int cc = tid - 128;
        float inv = 1.0f / (float)n2;
        float mean = stats[cc] * inv;
        float var = stats[64 + cc] * inv - mean * mean;
        float s = gamma[cc] * rsqrtf(var + 1e-5f);
        scs[cc] = s; shs[cc] = beta[cc] - mean * s;
    } else if (tid < 256) {
        int cc = tid - 192;
        bs[cc] = 0.f; bq[cc] = 0.f;
    }
    __syncthreads();
    #pragma unroll
    for (int it = 0; it < 2; ++it) {
        int c0 = it * 512 + tid;
        int pl = c0 >> 5, w8 = c0 & 31;
        int j = w8 >> 3, col8 = w8 & 7;
        const float* fr = y1 + (size_t)(srows[pl * 4 + j] & ROWM) * 64 + col8 * 8;
        float4 f0 = *(const float4*)fr;
        float4 f1v = *(const float4*)(fr + 4);
        short o[8];
        #pragma unroll
        for (int u = 0; u < 4; ++u) {
            int cc = col8 * 8 + u;
            float v = (u == 0) ? f0.x : (u == 1) ? f0.y : (u == 2) ? f0.z : f0.w;
            o[u] = f2bf(fmaxf(v * scs[cc] + shs[cc], 0.f));
        }
        #pragma unroll
        for (int u = 0; u < 4; ++u) {
            int cc = col8 * 8 + 4 + u;
            float v = (u == 0) ? f1v.x : (u == 1) ? f1v.y : (u == 2) ? f1v.z : f1v.w;
            o[4 + u] = f2bf(fmaxf(v * scs[cc] + shs[cc], 0.f));
        }
        short* d = &lds[pl * LP + j * 64 + col8 * 8];
        *(int2*)d = make_int2(((int)(unsigned short)o[0]) | ((int)o[1] << 16),
                              ((int)(unsigned short)o[2]) | ((int)o[3] << 16));
        *(int2*)(d + 4) = make_int2(((int)(unsigned short)o[4]) | ((int)o[5] << 16),
                                    ((int)(unsigned short)o[6]) | ((int)o[7] << 16));
    }
    int p0 = -1, p1 = -1, p2 = -1, p3 = -1;
    #pragma unroll
    for (int b = 7; b >= 0; --b)
        if ((mask >> b) & 1) { p3 = p2; p2 = p1; p1 = p0; p0 = b; }
    int w = tid >> 6, lane = tid & 63;
    int asub = w >> 1, ch = w & 1;
    int pa = (asub == 0) ? p0 : (asub == 1) ? p1 : (asub == 2) ? p2 : p3;
    int t0 = tap27(pa, p0), t1 = tap27(pa, p1), t2 = tap27(pa, p2), t3 = tap27(pa, p3);
    int m = lane & 31, half = lane >> 5;
    int li = lt + m;
    bool vp = li < cntb;
    int outrow = vp ? srows[m * 4 + asub] : -1;
    __syncthreads();
    f32x16 acc;
    #pragma unroll
    for (int i = 0; i < 16; ++i) acc[i] = 0.f;
    const bf16x8* bp = (const bf16x8*)wp;
    #pragma unroll
    for (int b = 0; b < 4; ++b) {
        int tb = (b == 0) ? t0 : (b == 1) ? t1 : (b == 2) ? t2 : t3;
        #pragma unroll
        for (int kk = 0; kk < 4; ++kk) {
            int ks = b * 4 + kk;
            const short* ap = &lds[m * LP + ks * 16 + half * 8];
            bf16x4 lo = *(const bf16x4*)ap, hi = *(const bf16x4*)(ap + 4);
            bf16x8 a = __builtin_shufflevector(lo, hi, 0, 1, 2, 3, 4, 5, 6, 7);
            bf16x8 b0 = bp[((size_t)(tb * 4 + kk) * 2 + ch) * 64 + lane];
            acc = __builtin_amdgcn_mfma_f32_32x32x16_bf16(a, b0, acc, 0, 0, 0);
        }
    }
    pair_epi1(acc, outrow, lane, ch, y, bs, bq);
    __syncthreads();
    if (tid < 64) {
        atomicAdd(&ostats[tid], bs[tid]);
        atomicAdd(&ostats[64 + tid], bq[tid]);
    }
}

// ---------------- BN finalize + ReLU -> f32 output ---------------------------
__global__ __launch_bounds__(256) void k_final(
    const float* __restrict__ y, const float* __restrict__ gamma,
    const float* __restrict__ beta, const float* __restrict__ stats,
    float* __restrict__ out, int n2)
{
    __shared__ float sc[64], sh[64];
    int tid = threadIdx.x;
    if (tid < 64) {
        float inv = 1.0f / (float)n2;
        float mean = stats[tid] * inv;
        float var = stats[64 + tid] * inv - mean * mean;
        float s = gamma[tid] * rsqrtf(var + 1e-5f);
        sc[tid] = s;
        sh[tid] = beta[tid] - mean * s;
    }
    __syncthreads();
    long long total = (long long)n2 * 16;
    long long stride = (long long)gridDim.x * blockDim.x;
    for (long long idx = (long long)blockIdx.x * blockDim.x + tid; idx < total; idx += stride) {
        int i = (int)(idx >> 4);
        int c4 = ((int)idx & 15) * 4;
        const float* src = y + (size_t)i * 64 + c4;
        float4 o;
        o.x = fmaxf(src[0] * sc[c4 + 0] + sh[c4 + 0], 0.f);
        o.y = fmaxf(src[1] * sc[c4 + 1] + sh[c4 + 1], 0.f);
        o.z = fmaxf(src[2] * sc[c4 + 2] + sh[c4 + 2], 0.f);
        o.w = fmaxf(src[3] * sc[c4 + 3] + sh[c4 + 3], 0.f);
        *(float4*)(out + (size_t)i * 64 + c4) = o;
    }
}

extern "C" void kernel_launch(void* const* d_in, const int* in_sizes, int n_in,
                              void* d_out, int out_size, void* d_ws, size_t ws_size,
                              hipStream_t stream)
{
    const float* feats1   = (const float*)d_in[0];
    const float* feats2   = (const float*)d_in[1];
    const float* w_up     = (const float*)d_in[2];
    const float* gamma_up = (const float*)d_in[3];
    const float* beta_up  = (const float*)d_in[4];
    const float* w1       = (const float*)d_in[5];
    const float* gamma1   = (const float*)d_in[6];
    const float* beta1    = (const float*)d_in[7];
    const float* w2       = (const float*)d_in[8];
    const float* gamma2   = (const float*)d_in[9];
    const float* beta2    = (const float*)d_in[10];
    const int* up_src     = (const int*)d_in[11];  (void)up_src;
    const int* up_kidx    = (const int*)d_in[12];
    const int* nbr_src    = (const int*)d_in[13];
    // d_in[14] nbr_dst unused: nbr_dst[t,i] ∈ {i, N2} by construction

    int n1 = in_sizes[0] / 128;
    int n2 = in_sizes[1] / 64;

    char* p = (char*)d_ws;
    auto alloc = [&](size_t bytes) {
        char* r = p;
        p += (bytes + 255) & ~(size_t)255;
        return r;
    };
    float* stats    = (float*)alloc(384 * 4);
    int*   cnt      = (int*)alloc(256 * 4);
    int*   extc     = (int*)alloc(16);
    int*   ntl      = (int*)alloc(16);
    unsigned* flagbits = (unsigned*)alloc(((size_t)(n2 + 31) / 32) * 4);
    size_t headBytes = (size_t)(p - (char*)d_ws);
    int maxTiles    = (n1 + 31) / 32 + 80;
    int4*  tiles    = (int4*)alloc((size_t)maxTiles * 16);
    short* wupp     = (short*)alloc((size_t)65536 * 2);
    short* w1p      = (short*)alloc((size_t)221184 * 2);
    short* w2p      = (short*)alloc((size_t)110592 * 2);
    short* f1bf     = (short*)alloc((size_t)n1 * 128 * 2);
    int*   pmask    = (int*)alloc((size_t)n1 * 4);
    int*   rank     = (int*)alloc((size_t)n1 * 4);
    int*   perm_par = (int*)alloc((size_t)n1 * 4);
    int*   perm_rows= (int*)alloc((size_t)4 * n1 * 4);
    int2*  ext      = (int2*)alloc((size_t)27 * n2 * 8);
    short* yup8     = (short*)alloc((size_t)n1 * 512 * 2);
    float* y1       = (float*)alloc((size_t)n2 * 64 * 4);
    float* y2       = (float*)alloc((size_t)n2 * 64 * 4);

    int nbGeom = (n1 + 255) / 256;
    int nbPack = 128;
    int nbSetup = nbGeom + nbPack;
    int nt = (n1 + 31) / 32;
    int nbExt2 = (n2 + 511) / 512;            // ext-scan: 2 chunks/block
    int upBlocks = 1 + 2 * nt + 128 + 64 + nbExt2;   // 1249 @ n1=15000
    const int EXTB = 128;   // R17 optimum: 658 total pair blocks, co-resident

    hipMemsetAsync(d_ws, 0, headBytes, stream);
    k_setup<<<nbSetup, 256, 0, stream>>>(w_up, feats1, up_kidx, wupp, f1bf,
                                         pmask, perm_rows, rank, cnt,
                                         n1, nbGeom);
    k_up<<<upBlocks, 256, 0, stream>>>(f1bf, wupp, pmask, cnt, rank, perm_par,
                                       tiles, ntl, yup8, stats,
                                       w1, w2, w1p, w2p, nbr_src, ext, extc,
                                       flagbits, y1, y2, n1, n2, nt);
    k_pairA<<<EXTB + maxTiles, 512, 0, stream>>>(yup8, feats2, up_kidx, w1p,
                                                 gamma_up, beta_up, stats,
                                                 perm_par, perm_rows, tiles, ntl,
                                                 ext, extc, flagbits,
                                                 y1, stats + 128, n2, EXTB);
    k_pairB<<<EXTB + maxTiles, 512, 0, stream>>>(y1, w2p, gamma1, beta1,
                                                 stats + 128, perm_par,
                                                 perm_rows, tiles, ntl,
                                                 ext, extc, flagbits,
                                                 y2, stats + 256, n2, EXTB);
    k_final<<<1024, 256, 0, stream>>>(y2, gamma2, beta2, stats + 256,
                                      (float*)d_out, n2);
}

// Round 15
// 222.017 us; speedup vs baseline: 1.1245x; 1.0212x over previous
//
#include <hip/hip_runtime.h>

// Round 24: fold the f1 f32->bf16 conversion into k_up's GEMM staging
// (latency-idle dispatch) and delete the f1bf pack from k_setup (was its
// dominant role: 240K vec8 groups vs 8K for wupp). k_setup grid 187->91
// blocks; 7.7 MB of pack traffic removed. Numerics identical (same f2bf,
// applied at staging time). Everything else verbatim R23 (226.7us, passing):
// compacted k_up aux roles (1249 blocks), EXTB=128 co-resident pair grids,
// 8-wave tile blocks, order-free atomic ext merge.

typedef short bf16x4 __attribute__((ext_vector_type(4)));
typedef short bf16x8 __attribute__((ext_vector_type(8)));
typedef float f32x16 __attribute__((ext_vector_type(16)));

#define ROWM 0xFFFFF
#define RFLAG (1 << 30)

__device__ __forceinline__ short f2bf(float f) {
    unsigned u = __float_as_uint(f);
    u += 0x7fffu + ((u >> 16) & 1u);
    return (short)(u >> 16);
}
__device__ __forceinline__ float bf2f(short s) {
    return __uint_as_float(((unsigned)(unsigned short)s) << 16);
}

// ---------------- setup: geometry + wupp pack (vec8) ------------------------
__global__ __launch_bounds__(256) void k_setup(
    const float* __restrict__ w_up, const int* __restrict__ up_kidx,
    short* __restrict__ wupp,
    int* __restrict__ pmask, int* __restrict__ perm_rows,
    int* __restrict__ rank, int* __restrict__ cnt,
    int n1, int nbGeom)
{
    int tid = threadIdx.x;
    int bid = blockIdx.x;
    if (bid < nbGeom) {
        int p = bid * 256 + tid;
        if (p >= n1) return;
        int4 kd = *(const int4*)(up_kidx + 4 * p);
        int a = kd.x * 4 + 0, b = kd.y * 4 + 1, c = kd.z * 4 + 2, d = kd.w * 4 + 3;
        int t;
        if (a > b) { t = a; a = b; b = t; }
        if (c > d) { t = c; c = d; d = t; }
        if (a > c) { t = a; a = c; c = t; }
        if (b > d) { t = b; b = d; d = t; }
        if (b > c) { t = b; b = c; c = t; }
        perm_rows[4 * p + 0] = 4 * p + (a & 3);
        perm_rows[4 * p + 1] = 4 * p + (b & 3);
        perm_rows[4 * p + 2] = 4 * p + (c & 3);
        perm_rows[4 * p + 3] = 4 * p + (d & 3);
        int mask = (1 << (a >> 2)) | (1 << (b >> 2)) | (1 << (c >> 2)) | (1 << (d >> 2));
        pmask[p] = mask;
        rank[p] = atomicAdd(&cnt[mask], 1);
    } else {
        const int nup8 = 8192;      // Wcat[128][512] -> [ks8][nt16][64][8]
        int gs = (gridDim.x - nbGeom) * 256;
        for (int e8 = (bid - nbGeom) * 256 + tid; e8 < nup8; e8 += gs) {
            int l = e8 & 63, nt = (e8 >> 6) & 15, ks = e8 >> 10;
            int kb = ks * 16 + (l >> 5) * 8;
            int col = nt * 32 + (l & 31);
            const float* src = w_up + (size_t)(col >> 6) * 8192 + (size_t)kb * 64 + (col & 63);
            bf16x8 o;
            #pragma unroll
            for (int j = 0; j < 8; ++j) o[j] = f2bf(src[(size_t)j * 64]);
            *(bf16x8*)(wupp + (size_t)e8 * 8) = o;
        }
    }
}

// ------- dense up-GEMM + masked BN stats; block 0 = scan; aux role-blocks ----
__global__ __launch_bounds__(256) void k_up(
    const float* __restrict__ f1, const short* __restrict__ wupp,
    const int* __restrict__ pmask, const int* __restrict__ cnt,
    const int* __restrict__ rank, int* __restrict__ perm_par,
    int4* __restrict__ tiles, int* __restrict__ ntl,
    short* __restrict__ yup8, float* __restrict__ stats,
    const float* __restrict__ w1, const float* __restrict__ w2,
    short* __restrict__ w1p, short* __restrict__ w2p,
    const int* __restrict__ nbr, int2* __restrict__ ext,
    int* __restrict__ extc, unsigned* __restrict__ flagbits,
    float* __restrict__ y1, float* __restrict__ y2,
    int n1, int n2, int nt)
{
    int gemmEnd = 1 + 2 * nt;
    if (blockIdx.x == 0) {
        __shared__ int sA[256], sB[256], bb[256];
        int t = threadIdx.x;
        int c = cnt[t], tc = (c + 31) >> 5;
        sA[t] = c; sB[t] = tc;
        __syncthreads();
        for (int off = 1; off < 256; off <<= 1) {
            int a = (t >= off) ? sA[t - off] : 0;
            int b = (t >= off) ? sB[t - off] : 0;
            __syncthreads();
            sA[t] += a; sB[t] += b;
            __syncthreads();
        }
        int base = sA[t] - c, toff = sB[t] - tc;
        bb[t] = base;
        for (int j = 0; j < tc; ++j) tiles[toff + j] = make_int4(t, base, j * 32, c);
        if (t == 255) ntl[0] = sB[255];
        __syncthreads();
        for (int p = t; p < n1; p += 256)
            perm_par[bb[pmask[p]] + rank[p]] = p;
        return;
    }
    if (blockIdx.x >= gemmEnd) {
        int ab = blockIdx.x - gemmEnd;
        int tid = threadIdx.x;
        if (ab < 128) {
            long long tot = (long long)n2 * 16;
            float4 z = make_float4(0.f, 0.f, 0.f, 0.f);
            for (long long e = (long long)ab * 256 + tid; e < tot; e += 128LL * 256) {
                ((float4*)y1)[e] = z;
                ((float4*)y2)[e] = z;
            }
        } else if (ab < 192) {
            const int nw18 = 27648, tot = 27648 + 13824;
            for (int e8 = (ab - 128) * 256 + tid; e8 < tot; e8 += 64 * 256) {
                if (e8 < nw18) {     // [27][8][2][64][8]
                    int l = e8 & 63, ch = (e8 >> 6) & 1, ks = (e8 >> 7) & 7, t = e8 >> 10;
                    int kb = ks * 16 + (l >> 5) * 8;
                    int col = ch * 32 + (l & 31);
                    const float* src = w1 + (size_t)t * 8192 + (size_t)kb * 64 + col;
                    bf16x8 o;
                    #pragma unroll
                    for (int j = 0; j < 8; ++j) o[j] = f2bf(src[(size_t)j * 64]);
                    *(bf16x8*)(w1p + (size_t)e8 * 8) = o;
                } else {             // [27][4][2][64][8]
                    int g = e8 - nw18;
                    int l = g & 63, ch = (g >> 6) & 1, ks = (g >> 7) & 3, t = g >> 9;
                    int kb = ks * 16 + (l >> 5) * 8;
                    int col = ch * 32 + (l & 31);
                    const float* src = w2 + (size_t)t * 4096 + (size_t)kb * 64 + col;
                    bf16x8 o;
                    #pragma unroll
                    for (int j = 0; j < 8; ++j) o[j] = f2bf(src[(size_t)j * 64]);
                    *(bf16x8*)(w2p + (size_t)g * 8) = o;
                }
            }
        } else {
            // 27-tap ext scan: 2 row-chunks per block, per-trip barriers
            __shared__ int lcnt, lbase;
            int base = (ab - 192) * 512;
            #pragma unroll
            for (int rep = 0; rep < 2; ++rep) {
                int i = base + rep * 256 + tid;
                unsigned hm = 0;
                if (i < n2) {
                    #pragma unroll
                    for (int t = 0; t < 27; ++t) {
                        int s = nbr[(size_t)t * n2 + i];
                        if (s < n2 && (s >> 2) != (i >> 2)) hm |= 1u << t;
                    }
                }
                if (hm) atomicOr(&flagbits[i >> 5], 1u << (i & 31));
                if (tid == 0) lcnt = 0;
                __syncthreads();
                int nh = __popc(hm);
                int myofs = 0;
                if (nh) myofs = atomicAdd(&lcnt, nh);
                __syncthreads();
                if (tid == 0 && lcnt) lbase = atomicAdd(extc, lcnt);
                __syncthreads();
                if (nh) {
                    int pos = lbase + myofs;
                    unsigned m = hm;
                    while (m) {
                        int t = __ffs(m) - 1;
                        m &= m - 1;
                        int s = nbr[(size_t)t * n2 + i];
                        ext[pos++] = make_int2(i, s | (t << 16));
                    }
                }
                __syncthreads();
            }
        }
        return;
    }
    __shared__ short lds[32 * 136];                  // stride 68 words ≡ 4 mod 32
    __shared__ float bs[64], bq[64];
    int bid = blockIdx.x - 1;
    int tile = bid >> 1;
    int w = threadIdx.x >> 6, lane = threadIdx.x & 63;
    int na = (bid & 1) * 8 + w, nb = na + 4;
    if (threadIdx.x < 64) { bs[threadIdx.x] = 0.f; bq[threadIdx.x] = 0.f; }
    #pragma unroll
    for (int it = 0; it < 2; ++it) {
        int c = it * 256 + threadIdx.x;
        int row = c >> 4, col8 = c & 15;
        int gr = tile * 32 + row; if (gr >= n1) gr = n1 - 1;
        const float* src = f1 + (size_t)gr * 128 + col8 * 8;   // [R24] direct f1
        float4 ga = *(const float4*)src;
        float4 gb = *(const float4*)(src + 4);
        short o[8] = {f2bf(ga.x), f2bf(ga.y), f2bf(ga.z), f2bf(ga.w),
                      f2bf(gb.x), f2bf(gb.y), f2bf(gb.z), f2bf(gb.w)};
        short* d = &lds[row * 136 + col8 * 8];
        *(int2*)d = make_int2(((int)(unsigned short)o[0]) | ((int)o[1] << 16),
                              ((int)(unsigned short)o[2]) | ((int)o[3] << 16));
        *(int2*)(d + 4) = make_int2(((int)(unsigned short)o[4]) | ((int)o[5] << 16),
                                    ((int)(unsigned short)o[6]) | ((int)o[7] << 16));
    }
    int m = lane & 31, half = lane >> 5;
    int pm_l = (tile * 32 + m < n1) ? pmask[tile * 32 + m] : 0;
    __syncthreads();
    f32x16 a0, a1;
    #pragma unroll
    for (int i = 0; i < 16; ++i) { a0[i] = 0.f; a1[i] = 0.f; }
    const bf16x8* bp = (const bf16x8*)wupp;
    #pragma unroll
    for (int ks = 0; ks < 8; ++ks) {
        const short* ap = &lds[m * 136 + ks * 16 + half * 8];
        bf16x4 lo = *(const bf16x4*)ap, hi = *(const bf16x4*)(ap + 4);
        bf16x8 a = __builtin_shufflevector(lo, hi, 0, 1, 2, 3, 4, 5, 6, 7);
        bf16x8 b0 = bp[(size_t)(ks * 16 + na) * 64 + lane];
        bf16x8 b1 = bp[(size_t)(ks * 16 + nb) * 64 + lane];
        a0 = __builtin_amdgcn_mfma_f32_32x32x16_bf16(a, b0, a0, 0, 0, 0);
        a1 = __builtin_amdgcn_mfma_f32_32x32x16_bf16(a, b1, a1, 0, 0, 0);
    }
    int col = lane & 31;
    #pragma unroll
    for (int pass = 0; pass < 2; ++pass) {
        const f32x16& acc = pass ? a1 : a0;
        int n = pass ? nb : na;
        int slot = n >> 1, c = (n & 1) * 32 + col;
        float s0 = 0.f, q0 = 0.f;
        #pragma unroll
        for (int reg = 0; reg < 16; ++reg) {
            int r = (reg & 3) + 8 * (reg >> 2) + 4 * half;
            int p = tile * 32 + r;
            float v = acc[reg];
            int mk = __shfl(pm_l, r);
            if (p < n1) {
                yup8[(size_t)p * 512 + n * 32 + col] = f2bf(v);
                if ((mk >> slot) & 1) { s0 += v; q0 += v * v; }
            }
        }
        s0 += __shfl_xor(s0, 32);
        q0 += __shfl_xor(q0, 32);
        if (lane < 32) { atomicAdd(&bs[c], s0); atomicAdd(&bq[c], q0); }
    }
    __syncthreads();
    if (threadIdx.x < 64) {
        atomicAdd(&stats[threadIdx.x], bs[threadIdx.x]);
        atomicAdd(&stats[64 + threadIdx.x], bq[threadIdx.x]);
    }
}

// ---- conv epilogue (1 acc/wave): overwrite unflagged; atomic+q-corr flagged -
__device__ __forceinline__ void pair_epi1(const f32x16& av, int outrow,
                                          int lane, int ch,
                                          float* __restrict__ y,
                                          float* __restrict__ bs,
                                          float* __restrict__ bq)
{
    int col = lane & 31;
    int c = ch * 32 + col;
    float s0 = 0.f, q0 = 0.f;
    #pragma unroll
    for (int reg = 0; reg < 16; ++reg) {
        int r = (reg & 3) + 8 * (reg >> 2) + 4 * (lane >> 5);
        int r0 = __shfl(outrow, r);
        if (r0 >= 0) {
            float v = av[reg];
            size_t ad = (size_t)(r0 & ROWM) * 64 + c;
            if (r0 & RFLAG) {
                float old = atomicAdd(&y[ad], v);
                s0 += v; q0 += v * (v + 2.f * old);
            } else {
                y[ad] = v; s0 += v; q0 += v * v;
            }
        }
    }
    s0 += __shfl_xor(s0, 32);
    q0 += __shfl_xor(q0, 32);
    if (lane < 32) { atomicAdd(&bs[c], s0); atomicAdd(&bq[c], q0); }
}

__device__ __forceinline__ int tap27(int pa, int pb) {
    int di = ((pb >> 2) & 1) - ((pa >> 2) & 1);
    int dj = ((pb >> 1) & 1) - ((pa >> 1) & 1);
    int dk = (pb & 1) - (pa & 1);
    return (di + 1) * 9 + (dj + 1) * 3 + (dk + 1);
}

// conv1: blocks [0,nExtB) = vectorized ext gather; rest = 8-wave MFMA tiles
__global__ __launch_bounds__(512) void k_pairA(
    const short* __restrict__ yup8, const float* __restrict__ f2,
    const int* __restrict__ up_kidx, const short* __restrict__ wp,
    const float* __restrict__ gamma, const float* __restrict__ beta,
    const float* __restrict__ stats, const int* __restrict__ perm_par,
    const int* __restrict__ perm_rows, const int4* __restrict__ tiles,
    const int* __restrict__ n_tiles, const int2* __restrict__ ext,
    const int* __restrict__ extc, const unsigned* __restrict__ flagbits,
    float* __restrict__ y, float* __restrict__ ostats, int n2, int nExtB)
{
    constexpr int LP = 520;                   // 260 words ≡ 4 mod 32: b128-clean
    __shared__ short lds[32 * LP];
    __shared__ int srows[128], soff[128];
    __shared__ float scs[64], shs[64], bs[64], bq[64];
    int tid = threadIdx.x;
    if (blockIdx.x < nExtB) {                 // ---- ext role (order-free) ----
        if (tid < 64) {
            float inv = 1.0f / (float)n2;
            float mean = stats[tid] * inv;
            float var = stats[64 + tid] * inv - mean * mean;
            float s = gamma[tid] * rsqrtf(var + 1e-5f);
            scs[tid] = s; shs[tid] = beta[tid] - mean * s;
            bs[tid] = 0.f; bq[tid] = 0.f;
        }
        __syncthreads();
        int gw = (blockIdx.x * 512 + tid) >> 6;
        int nw = nExtB * 8;
        int c = tid & 63;
        int ch = c >> 5, lcol = c & 31;
        int ec = extc[0];
        const bf16x8* wb = (const bf16x8*)wp;
        for (int e = gw; e < ec; e += nw) {
            int2 en = ext[e];
            int i = en.x, s = en.y & 0xFFFF, t = en.y >> 16;
            const short* xr = yup8 + (size_t)(s >> 2) * 512 + up_kidx[s] * 64;
            const float* fr = f2 + (size_t)s * 64;
            float acc = 0.f;
            #pragma unroll
            for (int ks = 0; ks < 8; ++ks) {
                #pragma unroll
                for (int hf = 0; hf < 2; ++hf) {
                    int kb = ks * 16 + hf * 8;
                    float xv[8];
                    if (kb < 64) {            // bn_relu(yup8) half
                        bf16x8 g = *(const bf16x8*)(xr + kb);
                        #pragma unroll
                        for (int j = 0; j < 8; ++j)
                            xv[j] = fmaxf(bf2f(g[j]) * scs[kb + j] + shs[kb + j], 0.f);
                    } else {                  // raw f2 half
                        float4 g0 = *(const float4*)(fr + kb - 64);
                        float4 g1 = *(const float4*)(fr + kb - 60);
                        xv[0] = g0.x; xv[1] = g0.y; xv[2] = g0.z; xv[3] = g0.w;
                        xv[4] = g1.x; xv[5] = g1.y; xv[6] = g1.z; xv[7] = g1.w;
                    }
                    bf16x8 wv = wb[((size_t)(t * 8 + ks) * 2 + ch) * 64 + hf * 32 + lcol];
                    #pragma unroll
                    for (int j = 0; j < 8; ++j)
                        acc += xv[j] * bf2f(wv[j]);
                }
            }
            float old = atomicAdd(&y[(size_t)i * 64 + c], acc);
            atomicAdd(&bs[c], acc);
            atomicAdd(&bq[c], acc * (acc + 2.f * old));
        }
        __syncthreads();
        if (tid < 64) {
            atomicAdd(&ostats[tid], bs[tid]);
            atomicAdd(&ostats[64 + tid], bq[tid]);
        }
        return;
    }
    int bt = blockIdx.x - nExtB;
    if (bt >= n_tiles[0]) return;
    int4 td = tiles[bt];
    int mask = td.x, p_start = td.y, lt = td.z, cntb = td.w;
    if (tid < 128) {
        int li = lt + (tid >> 2);
        int pid = perm_par[p_start + ((li < cntb) ? li : 0)];
        int i = perm_rows[pid * 4 + (tid & 3)];
        unsigned fb = (flagbits[i >> 5] >> (i & 31)) & 1u;
        srows[tid] = i | (int)(fb << 30);
        soff[tid] = (i >> 2) * 512 + up_kidx[i] * 64;
    } else if (tid < 192) {
        int cc = tid - 128;
        float inv = 1.0f / (float)n2;
        float mean = stats[cc] * inv;
        float var = stats[64 + cc] * inv - mean * mean;
        float s = gamma[cc] * rsqrtf(var + 1e-5f);
        scs[cc] = s; shs[cc] = beta[cc] - mean * s;
    } else if (tid < 256) {
        int cc = tid - 192;
        bs[cc] = 0.f; bq[cc] = 0.f;
    }
    __syncthreads();
    #pragma unroll
    for (int it = 0; it < 4; ++it) {
        int c0 = it * 512 + tid;
        int pl = c0 >> 6, w8 = c0 & 63;
        int j = w8 >> 4, col8 = w8 & 15;
        short* d = &lds[pl * LP + j * 128 + col8 * 8];
        if (col8 < 8) {
            bf16x8 g = *(const bf16x8*)(yup8 + (size_t)soff[pl * 4 + j] + col8 * 8);
            short o[8];
            #pragma unroll
            for (int u = 0; u < 8; ++u) {
                int cc = col8 * 8 + u;
                o[u] = f2bf(fmaxf(bf2f(g[u]) * scs[cc] + shs[cc], 0.f));
            }
            *(int2*)d = make_int2(((int)(unsigned short)o[0]) | ((int)o[1] << 16),
                                  ((int)(unsigned short)o[2]) | ((int)o[3] << 16));
            *(int2*)(d + 4) = make_int2(((int)(unsigned short)o[4]) | ((int)o[5] << 16),
                                        ((int)(unsigned short)o[6]) | ((int)o[7] << 16));
        } else {
            const float* fr = f2 + (size_t)(srows[pl * 4 + j] & ROWM) * 64 + (col8 - 8) * 8;
            float4 f0 = *(const float4*)fr;
            float4 f1v = *(const float4*)(fr + 4);
            short o[8] = {f2bf(f0.x), f2bf(f0.y), f2bf(f0.z), f2bf(f0.w),
                          f2bf(f1v.x), f2bf(f1v.y), f2bf(f1v.z), f2bf(f1v.w)};
            *(int2*)d = make_int2(((int)(unsigned short)o[0]) | ((int)o[1] << 16),
                                  ((int)(unsigned short)o[2]) | ((int)o[3] << 16));
            *(int2*)(d + 4) = make_int2(((int)(unsigned short)o[4]) | ((int)o[5] << 16),
                                        ((int)(unsigned short)o[6]) | ((int)o[7] << 16));
        }
    }
    int p0 = -1, p1 = -1, p2 = -1, p3 = -1;
    #pragma unroll
    for (int b = 7; b >= 0; --b)
        if ((mask >> b) & 1) { p3 = p2; p2 = p1; p1 = p0; p0 = b; }
    int w = tid >> 6, lane = tid & 63;
    int asub = w >> 1, ch = w & 1;
    int pa = (asub == 0) ? p0 : (asub == 1) ? p1 : (asub == 2) ? p2 : p3;
    int t0 = tap27(pa, p0), t1 = tap27(pa, p1), t2 = tap27(pa, p2), t3 = tap27(pa, p3);
    int m = lane & 31, half = lane >> 5;
    int li = lt + m;
    bool vp = li < cntb;
    int outrow = vp ? srows[m * 4 + asub] : -1;
    __syncthreads();
    f32x16 acc;
    #pragma unroll
    for (int i = 0; i < 16; ++i) acc[i] = 0.f;
    const bf16x8* bp = (const bf16x8*)wp;
    #pragma unroll
    for (int b = 0; b < 4; ++b) {
        int tb = (b == 0) ? t0 : (b == 1) ? t1 : (b == 2) ? t2 : t3;
        #pragma unroll
        for (int kk = 0; kk < 8; ++kk) {
            int ks = b * 8 + kk;
            const short* ap = &lds[m * LP + ks * 16 + half * 8];
            bf16x4 lo = *(const bf16x4*)ap, hi = *(const bf16x4*)(ap + 4);
            bf16x8 a = __builtin_shufflevector(lo, hi, 0, 1, 2, 3, 4, 5, 6, 7);
            bf16x8 b0 = bp[((size_t)(tb * 8 + kk) * 2 + ch) * 64 + lane];
            acc = __builtin_amdgcn_mfma_f32_32x32x16_bf16(a, b0, acc, 0, 0, 0);
        }
    }
    pair_epi1(acc, outrow, lane, ch, y, bs, bq);
    __syncthreads();
    if (tid < 64) {
        atomicAdd(&ostats[tid], bs[tid]);
        atomicAdd(&ostats[64 + tid], bq[tid]);
    }
}

// conv2: blocks [0,nExtB) = vectorized ext gather; rest = 8-wave MFMA tiles
__global__ __launch_bounds__(512) void k_pairB(
    const float* __restrict__ y1, const short* __restrict__ wp,
    const float* __restrict__ gamma, const float* __restrict__ beta,
    const float* __restrict__ stats, const int* __restrict__ perm_par,
    const int* __restrict__ perm_rows, const int4* __restrict__ tiles,
    const int* __restrict__ n_tiles, const int2* __restrict__ ext,
    const int* __restrict__ extc, const unsigned* __restrict__ flagbits,
    float* __restrict__ y, float* __restrict__ ostats, int n2, int nExtB)
{
    constexpr int LP = 264;                   // 132 words ≡ 4 mod 32
    __shared__ short lds[32 * LP];
    __shared__ int srows[128];
    __shared__ float scs[64], shs[64], bs[64], bq[64];
    int tid = threadIdx.x;
    if (blockIdx.x < nExtB) {                 // ---- ext role (order-free) ----
        if (tid < 64) {
            float inv = 1.0f / (float)n2;
            float mean = stats[tid] * inv;
            float var = stats[64 + tid] * inv - mean * mean;
            float s = gamma[tid] * rsqrtf(var + 1e-5f);
            scs[tid] = s; shs[tid] = beta[tid] - mean * s;
            bs[tid] = 0.f; bq[tid] = 0.f;
        }
        __syncthreads();
        int gw = (blockIdx.x * 512 + tid) >> 6;
        int nw = nExtB * 8;
        int c = tid & 63;
        int ch = c >> 5, lcol = c & 31;
        int ec = extc[0];
        const bf16x8* wb = (const bf16x8*)wp;
        for (int e = gw; e < ec; e += nw) {
            int2 en = ext[e];
            int i = en.x, s = en.y & 0xFFFF, t = en.y >> 16;
            const float* hr = y1 + (size_t)s * 64;
            float acc = 0.f;
            #pragma unroll
            for (int ks = 0; ks < 4; ++ks) {
                #pragma unroll
                for (int hf = 0; hf < 2; ++hf) {
                    int kb = ks * 16 + hf * 8;
                    float4 g0 = *(const float4*)(hr + kb);
                    float4 g1 = *(const float4*)(hr + kb + 4);
                    float xv[8];
                    xv[0] = g0.x; xv[1] = g0.y; xv[2] = g0.z; xv[3] = g0.w;
                    xv[4] = g1.x; xv[5] = g1.y; xv[6] = g1.z; xv[7] = g1.w;
                    #pragma unroll
                    for (int j = 0; j < 8; ++j)
                        xv[j] = fmaxf(xv[j] * scs[kb + j] + shs[kb + j], 0.f);
                    bf16x8 wv = wb[((size_t)(t * 4 + ks) * 2 + ch) * 64 + hf * 32 + lcol];
                    #pragma unroll
                    for (int j = 0; j < 8; ++j)
                        acc += xv[j] * bf2f(wv[j]);
                }
            }
            float old = atomicAdd(&y[(size_t)i * 64 + c], acc);
            atomicAdd(&bs[c], acc);
            atomicAdd(&bq[c], acc * (acc + 2.f * old));
        }
        __syncthreads();
        if (tid < 64) {
            atomicAdd(&ostats[tid], bs[tid]);
            atomicAdd(&ostats[64 + tid], bq[tid]);
        }
        return;
    }
    int bt = blockIdx.x - nExtB;
    if (bt >= n_tiles[0]) return;
    int4 td = tiles[bt];
    int mask = td.x, p_start = td.y, lt = td.z, cntb = td.w;
    if (tid < 128) {
        int li = lt + (tid >> 2);
        int pid = perm_par[p_start + ((li < cntb) ? li : 0)];
        int i = perm_rows[pid * 4 + (tid & 3)];
        unsigned fb = (flagbits[i >> 5] >> (i & 31)) & 1u;
        srows[tid] = i | (int)(fb << 30);
    } else if (tid < 192) {
        int cc = tid - 128;
        float inv = 1.0f / (float)n2;
        float mean = stats[cc] * inv;
        float var = stats[64 + cc] * inv - mean * mean;
        float s = gamma[cc] * rsqrtf(var + 1e-5f);
        scs[cc] = s; shs[cc] = beta[cc] - mean * s;
    } else if (tid < 256) {
        int cc = tid - 192;
        bs[cc] = 0.f; bq[cc] = 0.f;
    }
    __syncthreads();
    #pragma unroll
    for (int it = 0; it < 2; ++it) {
        int c0 = it * 512 + tid;
        int pl = c0 >> 5, w8 = c0 & 31;
        int j = w8 >> 3, col8 = w8 & 7;
        const float* fr = y1 + (size_t)(srows[pl * 4 + j] & ROWM) * 64 + col8 * 8;
        float4 f0 = *(const float4*)fr;
        float4 f1v = *(const float4*)(fr + 4);
        short o[8];
        #pragma unroll
        for (int u = 0; u < 4; ++u) {
            int cc = col8 * 8 + u;
            float v = (u == 0) ? f0.x : (u == 1) ? f0.y : (u == 2) ? f0.z : f0.w;
            o[u] = f2bf(fmaxf(v * scs[cc] + shs[cc], 0.f));
        }
        #pragma unroll
        for (int u = 0; u < 4; ++u) {
            int cc = col8 * 8 + 4 + u;
            float v = (u == 0) ? f1v.x : (u == 1) ? f1v.y : (u == 2) ? f1v.z : f1v.w;
            o[4 + u] = f2bf(fmaxf(v * scs[cc] + shs[cc], 0.f));
        }
        short* d = &lds[pl * LP + j * 64 + col8 * 8];
        *(int2*)d = make_int2(((int)(unsigned short)o[0]) | ((int)o[1] << 16),
                              ((int)(unsigned short)o[2]) | ((int)o[3] << 16));
        *(int2*)(d + 4) = make_int2(((int)(unsigned short)o[4]) | ((int)o[5] << 16),
                                    ((int)(unsigned short)o[6]) | ((int)o[7] << 16));
    }
    int p0 = -1, p1 = -1, p2 = -1, p3 = -1;
    #pragma unroll
    for (int b = 7; b >= 0; --b)
        if ((mask >> b) & 1) { p3 = p2; p2 = p1; p1 = p0; p0 = b; }
    int w = tid >> 6, lane = tid & 63;
    int asub = w >> 1, ch = w & 1;
    int pa = (asub == 0) ? p0 : (asub == 1) ? p1 : (asub == 2) ? p2 : p3;
    int t0 = tap27(pa, p0), t1 = tap27(pa, p1), t2 = tap27(pa, p2), t3 = tap27(pa, p3);
    int m = lane & 31, half = lane >> 5;
    int li = lt + m;
    bool vp = li < cntb;
    int outrow = vp ? srows[m * 4 + asub] : -1;
    __syncthreads();
    f32x16 acc;
    #pragma unroll
    for (int i = 0; i < 16; ++i) acc[i] = 0.f;
    const bf16x8* bp = (const bf16x8*)wp;
    #pragma unroll
    for (int b = 0; b < 4; ++b) {
        int tb = (b == 0) ? t0 : (b == 1) ? t1 : (b == 2) ? t2 : t3;
        #pragma unroll
        for (int kk = 0; kk < 4; ++kk) {
            int ks = b * 4 + kk;
            const short* ap = &lds[m * LP + ks * 16 + half * 8];
            bf16x4 lo = *(const bf16x4*)ap, hi = *(const bf16x4*)(ap + 4);
            bf16x8 a = __builtin_shufflevector(lo, hi, 0, 1, 2, 3, 4, 5, 6, 7);
            bf16x8 b0 = bp[((size_t)(tb * 4 + kk) * 2 + ch) * 64 + lane];
            acc = __builtin_amdgcn_mfma_f32_32x32x16_bf16(a, b0, acc, 0, 0, 0);
        }
    }
    pair_epi1(acc, outrow, lane, ch, y, bs, bq);
    __syncthreads();
    if (tid < 64) {
        atomicAdd(&ostats[tid], bs[tid]);
        atomicAdd(&ostats[64 + tid], bq[tid]);
    }
}

// ---------------- BN finalize + ReLU -> f32 output ---------------------------
__global__ __launch_bounds__(256) void k_final(
    const float* __restrict__ y, const float* __restrict__ gamma,
    const float* __restrict__ beta, const float* __restrict__ stats,
    float* __restrict__ out, int n2)
{
    __shared__ float sc[64], sh[64];
    int tid = threadIdx.x;
    if (tid < 64) {
        float inv = 1.0f / (float)n2;
        float mean = stats[tid] * inv;
        float var = stats[64 + tid] * inv - mean * mean;
        float s = gamma[tid] * rsqrtf(var + 1e-5f);
        sc[tid] = s;
        sh[tid] = beta[tid] - mean * s;
    }
    __syncthreads();
    long long total = (long long)n2 * 16;
    long long stride = (long long)gridDim.x * blockDim.x;
    for (long long idx = (long long)blockIdx.x * blockDim.x + tid; idx < total; idx += stride) {
        int i = (int)(idx >> 4);
        int c4 = ((int)idx & 15) * 4;
        const float* src = y + (size_t)i * 64 + c4;
        float4 o;
        o.x = fmaxf(src[0] * sc[c4 + 0] + sh[c4 + 0], 0.f);
        o.y = fmaxf(src[1] * sc[c4 + 1] + sh[c4 + 1], 0.f);
        o.z = fmaxf(src[2] * sc[c4 + 2] + sh[c4 + 2], 0.f);
        o.w = fmaxf(src[3] * sc[c4 + 3] + sh[c4 + 3], 0.f);
        *(float4*)(out + (size_t)i * 64 + c4) = o;
    }
}

extern "C" void kernel_launch(void* const* d_in, const int* in_sizes, int n_in,
                              void* d_out, int out_size, void* d_ws, size_t ws_size,
                              hipStream_t stream)
{
    const float* feats1   = (const float*)d_in[0];
    const float* feats2   = (const float*)d_in[1];
    const float* w_up     = (const float*)d_in[2];
    const float* gamma_up = (const float*)d_in[3];
    const float* beta_up  = (const float*)d_in[4];
    const float* w1       = (const float*)d_in[5];
    const float* gamma1   = (const float*)d_in[6];
    const float* beta1    = (const float*)d_in[7];
    const float* w2       = (const float*)d_in[8];
    const float* gamma2   = (const float*)d_in[9];
    const float* beta2    = (const float*)d_in[10];
    const int* up_src     = (const int*)d_in[11];  (void)up_src;
    const int* up_kidx    = (const int*)d_in[12];
    const int* nbr_src    = (const int*)d_in[13];
    // d_in[14] nbr_dst unused: nbr_dst[t,i] ∈ {i, N2} by construction

    int n1 = in_sizes[0] / 128;
    int n2 = in_sizes[1] / 64;

    char* p = (char*)d_ws;
    auto alloc = [&](size_t bytes) {
        char* r = p;
        p += (bytes + 255) & ~(size_t)255;
        return r;
    };
    float* stats    = (float*)alloc(384 * 4);
    int*   cnt      = (int*)alloc(256 * 4);
    int*   extc     = (int*)alloc(16);
    int*   ntl      = (int*)alloc(16);
    unsigned* flagbits = (unsigned*)alloc(((size_t)(n2 + 31) / 32) * 4);
    size_t headBytes = (size_t)(p - (char*)d_ws);
    int maxTiles    = (n1 + 31) / 32 + 80;
    int4*  tiles    = (int4*)alloc((size_t)maxTiles * 16);
    short* wupp     = (short*)alloc((size_t)65536 * 2);
    short* w1p      = (short*)alloc((size_t)221184 * 2);
    short* w2p      = (short*)alloc((size_t)110592 * 2);
    int*   pmask    = (int*)alloc((size_t)n1 * 4);
    int*   rank     = (int*)alloc((size_t)n1 * 4);
    int*   perm_par = (int*)alloc((size_t)n1 * 4);
    int*   perm_rows= (int*)alloc((size_t)4 * n1 * 4);
    int2*  ext      = (int2*)alloc((size_t)27 * n2 * 8);
    short* yup8     = (short*)alloc((size_t)n1 * 512 * 2);
    float* y1       = (float*)alloc((size_t)n2 * 64 * 4);
    float* y2       = (float*)alloc((size_t)n2 * 64 * 4);

    int nbGeom = (n1 + 255) / 256;
    int nbPack = 32;                           // 8192 wupp groups only
    int nbSetup = nbGeom + nbPack;
    int nt = (n1 + 31) / 32;
    int nbExt2 = (n2 + 511) / 512;             // ext-scan: 2 chunks/block
    int upBlocks = 1 + 2 * nt + 128 + 64 + nbExt2;
    const int EXTB = 128;   // R17 optimum: 658 total pair blocks, co-resident

    hipMemsetAsync(d_ws, 0, headBytes, stream);
    k_setup<<<nbSetup, 256, 0, stream>>>(w_up, up_kidx, wupp,
                                         pmask, perm_rows, rank, cnt,
                                         n1, nbGeom);
    k_up<<<upBlocks, 256, 0, stream>>>(feats1, wupp, pmask, cnt, rank, perm_par,
                                       tiles, ntl, yup8, stats,
                                       w1, w2, w1p, w2p, nbr_src, ext, extc,
                                       flagbits, y1, y2, n1, n2, nt);
    k_pairA<<<EXTB + maxTiles, 512, 0, stream>>>(yup8, feats2, up_kidx, w1p,
                                                 gamma_up, beta_up, stats,
                                                 perm_par, perm_rows, tiles, ntl,
                                                 ext, extc, flagbits,
                                                 y1, stats + 128, n2, EXTB);
    k_pairB<<<EXTB + maxTiles, 512, 0, stream>>>(y1, w2p, gamma1, beta1,
                                                 stats + 128, perm_par,
                                                 perm_rows, tiles, ntl,
                                                 ext, extc, flagbits,
                                                 y2, stats + 256, n2, EXTB);
    k_final<<<1024, 256, 0, stream>>>(y2, gamma2, beta2, stats + 256,
                                      (float*)d_out, n2);
}

// Round 16
// 219.039 us; speedup vs baseline: 1.1398x; 1.0136x over previous
//
#include <hip/hip_runtime.h>

// Round 25: R24 (best measured, 222.0us) + s_setprio(1) around the tile-role
// MFMA chains in k_pairA/k_pairB (guide T5). Mechanism: 3 independent
// blocks/CU at different phases (ext gather vs staging vs MFMA) -> priority
// hint lets MFMA-phase waves preempt memory-phase waves' issue slots.
// Zero VGPR / numerics change; everything else verbatim R24.

typedef short bf16x4 __attribute__((ext_vector_type(4)));
typedef short bf16x8 __attribute__((ext_vector_type(8)));
typedef float f32x16 __attribute__((ext_vector_type(16)));

#define ROWM 0xFFFFF
#define RFLAG (1 << 30)

__device__ __forceinline__ short f2bf(float f) {
    unsigned u = __float_as_uint(f);
    u += 0x7fffu + ((u >> 16) & 1u);
    return (short)(u >> 16);
}
__device__ __forceinline__ float bf2f(short s) {
    return __uint_as_float(((unsigned)(unsigned short)s) << 16);
}

// ---------------- setup: geometry + wupp pack (vec8) ------------------------
__global__ __launch_bounds__(256) void k_setup(
    const float* __restrict__ w_up, const int* __restrict__ up_kidx,
    short* __restrict__ wupp,
    int* __restrict__ pmask, int* __restrict__ perm_rows,
    int* __restrict__ rank, int* __restrict__ cnt,
    int n1, int nbGeom)
{
    int tid = threadIdx.x;
    int bid = blockIdx.x;
    if (bid < nbGeom) {
        int p = bid * 256 + tid;
        if (p >= n1) return;
        int4 kd = *(const int4*)(up_kidx + 4 * p);
        int a = kd.x * 4 + 0, b = kd.y * 4 + 1, c = kd.z * 4 + 2, d = kd.w * 4 + 3;
        int t;
        if (a > b) { t = a; a = b; b = t; }
        if (c > d) { t = c; c = d; d = t; }
        if (a > c) { t = a; a = c; c = t; }
        if (b > d) { t = b; b = d; d = t; }
        if (b > c) { t = b; b = c; c = t; }
        perm_rows[4 * p + 0] = 4 * p + (a & 3);
        perm_rows[4 * p + 1] = 4 * p + (b & 3);
        perm_rows[4 * p + 2] = 4 * p + (c & 3);
        perm_rows[4 * p + 3] = 4 * p + (d & 3);
        int mask = (1 << (a >> 2)) | (1 << (b >> 2)) | (1 << (c >> 2)) | (1 << (d >> 2));
        pmask[p] = mask;
        rank[p] = atomicAdd(&cnt[mask], 1);
    } else {
        const int nup8 = 8192;      // Wcat[128][512] -> [ks8][nt16][64][8]
        int gs = (gridDim.x - nbGeom) * 256;
        for (int e8 = (bid - nbGeom) * 256 + tid; e8 < nup8; e8 += gs) {
            int l = e8 & 63, nt = (e8 >> 6) & 15, ks = e8 >> 10;
            int kb = ks * 16 + (l >> 5) * 8;
            int col = nt * 32 + (l & 31);
            const float* src = w_up + (size_t)(col >> 6) * 8192 + (size_t)kb * 64 + (col & 63);
            bf16x8 o;
            #pragma unroll
            for (int j = 0; j < 8; ++j) o[j] = f2bf(src[(size_t)j * 64]);
            *(bf16x8*)(wupp + (size_t)e8 * 8) = o;
        }
    }
}

// ------- dense up-GEMM + masked BN stats; block 0 = scan; aux role-blocks ----
__global__ __launch_bounds__(256) void k_up(
    const float* __restrict__ f1, const short* __restrict__ wupp,
    const int* __restrict__ pmask, const int* __restrict__ cnt,
    const int* __restrict__ rank, int* __restrict__ perm_par,
    int4* __restrict__ tiles, int* __restrict__ ntl,
    short* __restrict__ yup8, float* __restrict__ stats,
    const float* __restrict__ w1, const float* __restrict__ w2,
    short* __restrict__ w1p, short* __restrict__ w2p,
    const int* __restrict__ nbr, int2* __restrict__ ext,
    int* __restrict__ extc, unsigned* __restrict__ flagbits,
    float* __restrict__ y1, float* __restrict__ y2,
    int n1, int n2, int nt)
{
    int gemmEnd = 1 + 2 * nt;
    if (blockIdx.x == 0) {
        __shared__ int sA[256], sB[256], bb[256];
        int t = threadIdx.x;
        int c = cnt[t], tc = (c + 31) >> 5;
        sA[t] = c; sB[t] = tc;
        __syncthreads();
        for (int off = 1; off < 256; off <<= 1) {
            int a = (t >= off) ? sA[t - off] : 0;
            int b = (t >= off) ? sB[t - off] : 0;
            __syncthreads();
            sA[t] += a; sB[t] += b;
            __syncthreads();
        }
        int base = sA[t] - c, toff = sB[t] - tc;
        bb[t] = base;
        for (int j = 0; j < tc; ++j) tiles[toff + j] = make_int4(t, base, j * 32, c);
        if (t == 255) ntl[0] = sB[255];
        __syncthreads();
        for (int p = t; p < n1; p += 256)
            perm_par[bb[pmask[p]] + rank[p]] = p;
        return;
    }
    if (blockIdx.x >= gemmEnd) {
        int ab = blockIdx.x - gemmEnd;
        int tid = threadIdx.x;
        if (ab < 128) {
            long long tot = (long long)n2 * 16;
            float4 z = make_float4(0.f, 0.f, 0.f, 0.f);
            for (long long e = (long long)ab * 256 + tid; e < tot; e += 128LL * 256) {
                ((float4*)y1)[e] = z;
                ((float4*)y2)[e] = z;
            }
        } else if (ab < 192) {
            const int nw18 = 27648, tot = 27648 + 13824;
            for (int e8 = (ab - 128) * 256 + tid; e8 < tot; e8 += 64 * 256) {
                if (e8 < nw18) {     // [27][8][2][64][8]
                    int l = e8 & 63, ch = (e8 >> 6) & 1, ks = (e8 >> 7) & 7, t = e8 >> 10;
                    int kb = ks * 16 + (l >> 5) * 8;
                    int col = ch * 32 + (l & 31);
                    const float* src = w1 + (size_t)t * 8192 + (size_t)kb * 64 + col;
                    bf16x8 o;
                    #pragma unroll
                    for (int j = 0; j < 8; ++j) o[j] = f2bf(src[(size_t)j * 64]);
                    *(bf16x8*)(w1p + (size_t)e8 * 8) = o;
                } else {             // [27][4][2][64][8]
                    int g = e8 - nw18;
                    int l = g & 63, ch = (g >> 6) & 1, ks = (g >> 7) & 3, t = g >> 9;
                    int kb = ks * 16 + (l >> 5) * 8;
                    int col = ch * 32 + (l & 31);
                    const float* src = w2 + (size_t)t * 4096 + (size_t)kb * 64 + col;
                    bf16x8 o;
                    #pragma unroll
                    for (int j = 0; j < 8; ++j) o[j] = f2bf(src[(size_t)j * 64]);
                    *(bf16x8*)(w2p + (size_t)g * 8) = o;
                }
            }
        } else {
            // 27-tap ext scan: 2 row-chunks per block, per-trip barriers
            __shared__ int lcnt, lbase;
            int base = (ab - 192) * 512;
            #pragma unroll
            for (int rep = 0; rep < 2; ++rep) {
                int i = base + rep * 256 + tid;
                unsigned hm = 0;
                if (i < n2) {
                    #pragma unroll
                    for (int t = 0; t < 27; ++t) {
                        int s = nbr[(size_t)t * n2 + i];
                        if (s < n2 && (s >> 2) != (i >> 2)) hm |= 1u << t;
                    }
                }
                if (hm) atomicOr(&flagbits[i >> 5], 1u << (i & 31));
                if (tid == 0) lcnt = 0;
                __syncthreads();
                int nh = __popc(hm);
                int myofs = 0;
                if (nh) myofs = atomicAdd(&lcnt, nh);
                __syncthreads();
                if (tid == 0 && lcnt) lbase = atomicAdd(extc, lcnt);
                __syncthreads();
                if (nh) {
                    int pos = lbase + myofs;
                    unsigned m = hm;
                    while (m) {
                        int t = __ffs(m) - 1;
                        m &= m - 1;
                        int s = nbr[(size_t)t * n2 + i];
                        ext[pos++] = make_int2(i, s | (t << 16));
                    }
                }
                __syncthreads();
            }
        }
        return;
    }
    __shared__ short lds[32 * 136];                  // stride 68 words ≡ 4 mod 32
    __shared__ float bs[64], bq[64];
    int bid = blockIdx.x - 1;
    int tile = bid >> 1;
    int w = threadIdx.x >> 6, lane = threadIdx.x & 63;
    int na = (bid & 1) * 8 + w, nb = na + 4;
    if (threadIdx.x < 64) { bs[threadIdx.x] = 0.f; bq[threadIdx.x] = 0.f; }
    #pragma unroll
    for (int it = 0; it < 2; ++it) {
        int c = it * 256 + threadIdx.x;
        int row = c >> 4, col8 = c & 15;
        int gr = tile * 32 + row; if (gr >= n1) gr = n1 - 1;
        const float* src = f1 + (size_t)gr * 128 + col8 * 8;
        float4 ga = *(const float4*)src;
        float4 gb = *(const float4*)(src + 4);
        short o[8] = {f2bf(ga.x), f2bf(ga.y), f2bf(ga.z), f2bf(ga.w),
                      f2bf(gb.x), f2bf(gb.y), f2bf(gb.z), f2bf(gb.w)};
        short* d = &lds[row * 136 + col8 * 8];
        *(int2*)d = make_int2(((int)(unsigned short)o[0]) | ((int)o[1] << 16),
                              ((int)(unsigned short)o[2]) | ((int)o[3] << 16));
        *(int2*)(d + 4) = make_int2(((int)(unsigned short)o[4]) | ((int)o[5] << 16),
                                    ((int)(unsigned short)o[6]) | ((int)o[7] << 16));
    }
    int m = lane & 31, half = lane >> 5;
    int pm_l = (tile * 32 + m < n1) ? pmask[tile * 32 + m] : 0;
    __syncthreads();
    f32x16 a0, a1;
    #pragma unroll
    for (int i = 0; i < 16; ++i) { a0[i] = 0.f; a1[i] = 0.f; }
    const bf16x8* bp = (const bf16x8*)wupp;
    __builtin_amdgcn_s_setprio(1);
    #pragma unroll
    for (int ks = 0; ks < 8; ++ks) {
        const short* ap = &lds[m * 136 + ks * 16 + half * 8];
        bf16x4 lo = *(const bf16x4*)ap, hi = *(const bf16x4*)(ap + 4);
        bf16x8 a = __builtin_shufflevector(lo, hi, 0, 1, 2, 3, 4, 5, 6, 7);
        bf16x8 b0 = bp[(size_t)(ks * 16 + na) * 64 + lane];
        bf16x8 b1 = bp[(size_t)(ks * 16 + nb) * 64 + lane];
        a0 = __builtin_amdgcn_mfma_f32_32x32x16_bf16(a, b0, a0, 0, 0, 0);
        a1 = __builtin_amdgcn_mfma_f32_32x32x16_bf16(a, b1, a1, 0, 0, 0);
    }
    __builtin_amdgcn_s_setprio(0);
    int col = lane & 31;
    #pragma unroll
    for (int pass = 0; pass < 2; ++pass) {
        const f32x16& acc = pass ? a1 : a0;
        int n = pass ? nb : na;
        int slot = n >> 1, c = (n & 1) * 32 + col;
        float s0 = 0.f, q0 = 0.f;
        #pragma unroll
        for (int reg = 0; reg < 16; ++reg) {
            int r = (reg & 3) + 8 * (reg >> 2) + 4 * half;
            int p = tile * 32 + r;
            float v = acc[reg];
            int mk = __shfl(pm_l, r);
            if (p < n1) {
                yup8[(size_t)p * 512 + n * 32 + col] = f2bf(v);
                if ((mk >> slot) & 1) { s0 += v; q0 += v * v; }
            }
        }
        s0 += __shfl_xor(s0, 32);
        q0 += __shfl_xor(q0, 32);
        if (lane < 32) { atomicAdd(&bs[c], s0); atomicAdd(&bq[c], q0); }
    }
    __syncthreads();
    if (threadIdx.x < 64) {
        atomicAdd(&stats[threadIdx.x], bs[threadIdx.x]);
        atomicAdd(&stats[64 + threadIdx.x], bq[threadIdx.x]);
    }
}

// ---- conv epilogue (1 acc/wave): overwrite unflagged; atomic+q-corr flagged -
__device__ __forceinline__ void pair_epi1(const f32x16& av, int outrow,
                                          int lane, int ch,
                                          float* __restrict__ y,
                                          float* __restrict__ bs,
                                          float* __restrict__ bq)
{
    int col = lane & 31;
    int c = ch * 32 + col;
    float s0 = 0.f, q0 = 0.f;
    #pragma unroll
    for (int reg = 0; reg < 16; ++reg) {
        int r = (reg & 3) + 8 * (reg >> 2) + 4 * (lane >> 5);
        int r0 = __shfl(outrow, r);
        if (r0 >= 0) {
            float v = av[reg];
            size_t ad = (size_t)(r0 & ROWM) * 64 + c;
            if (r0 & RFLAG) {
                float old = atomicAdd(&y[ad], v);
                s0 += v; q0 += v * (v + 2.f * old);
            } else {
                y[ad] = v; s0 += v; q0 += v * v;
            }
        }
    }
    s0 += __shfl_xor(s0, 32);
    q0 += __shfl_xor(q0, 32);
    if (lane < 32) { atomicAdd(&bs[c], s0); atomicAdd(&bq[c], q0); }
}

__device__ __forceinline__ int tap27(int pa, int pb) {
    int di = ((pb >> 2) & 1) - ((pa >> 2) & 1);
    int dj = ((pb >> 1) & 1) - ((pa >> 1) & 1);
    int dk = (pb & 1) - (pa & 1);
    return (di + 1) * 9 + (dj + 1) * 3 + (dk + 1);
}

// conv1: blocks [0,nExtB) = vectorized ext gather; rest = 8-wave MFMA tiles
__global__ __launch_bounds__(512) void k_pairA(
    const short* __restrict__ yup8, const float* __restrict__ f2,
    const int* __restrict__ up_kidx, const short* __restrict__ wp,
    const float* __restrict__ gamma, const float* __restrict__ beta,
    const float* __restrict__ stats, const int* __restrict__ perm_par,
    const int* __restrict__ perm_rows, const int4* __restrict__ tiles,
    const int* __restrict__ n_tiles, const int2* __restrict__ ext,
    const int* __restrict__ extc, const unsigned* __restrict__ flagbits,
    float* __restrict__ y, float* __restrict__ ostats, int n2, int nExtB)
{
    constexpr int LP = 520;                   // 260 words ≡ 4 mod 32: b128-clean
    __shared__ short lds[32 * LP];
    __shared__ int srows[128], soff[128];
    __shared__ float scs[64], shs[64], bs[64], bq[64];
    int tid = threadIdx.x;
    if (blockIdx.x < nExtB) {                 // ---- ext role (order-free) ----
        if (tid < 64) {
            float inv = 1.0f / (float)n2;
            float mean = stats[tid] * inv;
            float var = stats[64 + tid] * inv - mean * mean;
            float s = gamma[tid] * rsqrtf(var + 1e-5f);
            scs[tid] = s; shs[tid] = beta[tid] - mean * s;
            bs[tid] = 0.f; bq[tid] = 0.f;
        }
        __syncthreads();
        int gw = (blockIdx.x * 512 + tid) >> 6;
        int nw = nExtB * 8;
        int c = tid & 63;
        int ch = c >> 5, lcol = c & 31;
        int ec = extc[0];
        const bf16x8* wb = (const bf16x8*)wp;
        for (int e = gw; e < ec; e += nw) {
            int2 en = ext[e];
            int i = en.x, s = en.y & 0xFFFF, t = en.y >> 16;
            const short* xr = yup8 + (size_t)(s >> 2) * 512 + up_kidx[s] * 64;
            const float* fr = f2 + (size_t)s * 64;
            float acc = 0.f;
            #pragma unroll
            for (int ks = 0; ks < 8; ++ks) {
                #pragma unroll
                for (int hf = 0; hf < 2; ++hf) {
                    int kb = ks * 16 + hf * 8;
                    float xv[8];
                    if (kb < 64) {            // bn_relu(yup8) half
                        bf16x8 g = *(const bf16x8*)(xr + kb);
                        #pragma unroll
                        for (int j = 0; j < 8; ++j)
                            xv[j] = fmaxf(bf2f(g[j]) * scs[kb + j] + shs[kb + j], 0.f);
                    } else {                  // raw f2 half
                        float4 g0 = *(const float4*)(fr + kb - 64);
                        float4 g1 = *(const float4*)(fr + kb - 60);
                        xv[0] = g0.x; xv[1] = g0.y; xv[2] = g0.z; xv[3] = g0.w;
                        xv[4] = g1.x; xv[5] = g1.y; xv[6] = g1.z; xv[7] = g1.w;
                    }
                    bf16x8 wv = wb[((size_t)(t * 8 + ks) * 2 + ch) * 64 + hf * 32 + lcol];
                    #pragma unroll
                    for (int j = 0; j < 8; ++j)
                        acc += xv[j] * bf2f(wv[j]);
                }
            }
            float old = atomicAdd(&y[(size_t)i * 64 + c], acc);
            atomicAdd(&bs[c], acc);
            atomicAdd(&bq[c], acc * (acc + 2.f * old));
        }
        __syncthreads();
        if (tid < 64) {
            atomicAdd(&ostats[tid], bs[tid]);
            atomicAdd(&ostats[64 + tid], bq[tid]);
        }
        return;
    }
    int bt = blockIdx.x - nExtB;
    if (bt >= n_tiles[0]) return;
    int4 td = tiles[bt];
    int mask = td.x, p_start = td.y, lt = td.z, cntb = td.w;
    if (tid < 128) {
        int li = lt + (tid >> 2);
        int pid = perm_par[p_start + ((li < cntb) ? li : 0)];
        int i = perm_rows[pid * 4 + (tid & 3)];
        unsigned fb = (flagbits[i >> 5] >> (i & 31)) & 1u;
        srows[tid] = i | (int)(fb << 30);
        soff[tid] = (i >> 2) * 512 + up_kidx[i] * 64;
    } else if (tid < 192) {
        int cc = tid - 128;
        float inv = 1.0f / (float)n2;
        float mean = stats[cc] * inv;
        float var = stats[64 + cc] * inv - mean * mean;
        float s = gamma[cc] * rsqrtf(var + 1e-5f);
        scs[cc] = s; shs[cc] = beta[cc] - mean * s;
    } else if (tid < 256) {
        int cc = tid - 192;
        bs[cc] = 0.f; bq[cc] = 0.f;
    }
    __syncthreads();
    #pragma unroll
    for (int it = 0; it < 4; ++it) {
        int c0 = it * 512 + tid;
        int pl = c0 >> 6, w8 = c0 & 63;
        int j = w8 >> 4, col8 = w8 & 15;
        short* d = &lds[pl * LP + j * 128 + col8 * 8];
        if (col8 < 8) {
            bf16x8 g = *(const bf16x8*)(yup8 + (size_t)soff[pl * 4 + j] + col8 * 8);
            short o[8];
            #pragma unroll
            for (int u = 0; u < 8; ++u) {
                int cc = col8 * 8 + u;
                o[u] = f2bf(fmaxf(bf2f(g[u]) * scs[cc] + shs[cc], 0.f));
            }
            *(int2*)d = make_int2(((int)(unsigned short)o[0]) | ((int)o[1] << 16),
                                  ((int)(unsigned short)o[2]) | ((int)o[3] << 16));
            *(int2*)(d + 4) = make_int2(((int)(unsigned short)o[4]) | ((int)o[5] << 16),
                                        ((int)(unsigned short)o[6]) | ((int)o[7] << 16));
        } else {
            const float* fr = f2 + (size_t)(srows[pl * 4 + j] & ROWM) * 64 + (col8 - 8) * 8;
            float4 f0 = *(const float4*)fr;
            float4 f1v = *(const float4*)(fr + 4);
            short o[8] = {f2bf(f0.x), f2bf(f0.y), f2bf(f0.z), f2bf(f0.w),
                          f2bf(f1v.x), f2bf(f1v.y), f2bf(f1v.z), f2bf(f1v.w)};
            *(int2*)d = make_int2(((int)(unsigned short)o[0]) | ((int)o[1] << 16),
                                  ((int)(unsigned short)o[2]) | ((int)o[3] << 16));
            *(int2*)(d + 4) = make_int2(((int)(unsigned short)o[4]) | ((int)o[5] << 16),
                                        ((int)(unsigned short)o[6]) | ((int)o[7] << 16));
        }
    }
    int p0 = -1, p1 = -1, p2 = -1, p3 = -1;
    #pragma unroll
    for (int b = 7; b >= 0; --b)
        if ((mask >> b) & 1) { p3 = p2; p2 = p1; p1 = p0; p0 = b; }
    int w = tid >> 6, lane = tid & 63;
    int asub = w >> 1, ch = w & 1;
    int pa = (asub == 0) ? p0 : (asub == 1) ? p1 : (asub == 2) ? p2 : p3;
    int t0 = tap27(pa, p0), t1 = tap27(pa, p1), t2 = tap27(pa, p2), t3 = tap27(pa, p3);
    int m = lane & 31, half = lane >> 5;
    int li = lt + m;
    bool vp = li < cntb;
    int outrow = vp ? srows[m * 4 + asub] : -1;
    __syncthreads();
    f32x16 acc;
    #pragma unroll
    for (int i = 0; i < 16; ++i) acc[i] = 0.f;
    const bf16x8* bp = (const bf16x8*)wp;
    __builtin_amdgcn_s_setprio(1);
    #pragma unroll
    for (int b = 0; b < 4; ++b) {
        int tb = (b == 0) ? t0 : (b == 1) ? t1 : (b == 2) ? t2 : t3;
        #pragma unroll
        for (int kk = 0; kk < 8; ++kk) {
            int ks = b * 8 + kk;
            const short* ap = &lds[m * LP + ks * 16 + half * 8];
            bf16x4 lo = *(const bf16x4*)ap, hi = *(const bf16x4*)(ap + 4);
            bf16x8 a = __builtin_shufflevector(lo, hi, 0, 1, 2, 3, 4, 5, 6, 7);
            bf16x8 b0 = bp[((size_t)(tb * 8 + kk) * 2 + ch) * 64 + lane];
            acc = __builtin_amdgcn_mfma_f32_32x32x16_bf16(a, b0, acc, 0, 0, 0);
        }
    }
    __builtin_amdgcn_s_setprio(0);
    pair_epi1(acc, outrow, lane, ch, y, bs, bq);
    __syncthreads();
    if (tid < 64) {
        atomicAdd(&ostats[tid], bs[tid]);
        atomicAdd(&ostats[64 + tid], bq[tid]);
    }
}

// conv2: blocks [0,nExtB) = vectorized ext gather; rest = 8-wave MFMA tiles
__global__ __launch_bounds__(512) void k_pairB(
    const float* __restrict__ y1, const short* __restrict__ wp,
    const float* __restrict__ gamma, const float* __restrict__ beta,
    const float* __restrict__ stats, const int* __restrict__ perm_par,
    const int* __restrict__ perm_rows, const int4* __restrict__ tiles,
    const int* __restrict__ n_tiles, const int2* __restrict__ ext,
    const int* __restrict__ extc, const unsigned* __restrict__ flagbits,
    float* __restrict__ y, float* __restrict__ ostats, int n2, int nExtB)
{
    constexpr int LP = 264;                   // 132 words ≡ 4 mod 32
    __shared__ short lds[32 * LP];
    __shared__ int srows[128];
    __shared__ float scs[64], shs[64], bs[64], bq[64];
    int tid = threadIdx.x;
    if (blockIdx.x < nExtB) {                 // ---- ext role (order-free) ----
        if (tid < 64) {
            float inv = 1.0f / (float)n2;
            float mean = stats[tid] * inv;
            float var = stats[64 + tid] * inv - mean * mean;
            float s = gamma[tid] * rsqrtf(var + 1e-5f);
            scs[tid] = s; shs[tid] = beta[tid] - mean * s;
            bs[tid] = 0.f; bq[tid] = 0.f;
        }
        __syncthreads();
        int gw = (blockIdx.x * 512 + tid) >> 6;
        int nw = nExtB * 8;
        int c = tid & 63;
        int ch = c >> 5, lcol = c & 31;
        int ec = extc[0];
        const bf16x8* wb = (const bf16x8*)wp;
        for (int e = gw; e < ec; e += nw) {
            int2 en = ext[e];
            int i = en.x, s = en.y & 0xFFFF, t = en.y >> 16;
            const float* hr = y1 + (size_t)s * 64;
            float acc = 0.f;
            #pragma unroll
            for (int ks = 0; ks < 4; ++ks) {
                #pragma unroll
                for (int hf = 0; hf < 2; ++hf) {
                    int kb = ks * 16 + hf * 8;
                    float4 g0 = *(const float4*)(hr + kb);
                    float4 g1 = *(const float4*)(hr + kb + 4);
                    float xv[8];
                    xv[0] = g0.x; xv[1] = g0.y; xv[2] = g0.z; xv[3] = g0.w;
                    xv[4] = g1.x; xv[5] = g1.y; xv[6] = g1.z; xv[7] = g1.w;
                    #pragma unroll
                    for (int j = 0; j < 8; ++j)
                        xv[j] = fmaxf(xv[j] * scs[kb + j] + shs[kb + j], 0.f);
                    bf16x8 wv = wb[((size_t)(t * 4 + ks) * 2 + ch) * 64 + hf * 32 + lcol];
                    #pragma unroll
                    for (int j = 0; j < 8; ++j)
                        acc += xv[j] * bf2f(wv[j]);
                }
            }
            float old = atomicAdd(&y[(size_t)i * 64 + c], acc);
            atomicAdd(&bs[c], acc);
            atomicAdd(&bq[c], acc * (acc + 2.f * old));
        }
        __syncthreads();
        if (tid < 64) {
            atomicAdd(&ostats[tid], bs[tid]);
            atomicAdd(&ostats[64 + tid], bq[tid]);
        }
        return;
    }
    int bt = blockIdx.x - nExtB;
    if (bt >= n_tiles[0]) return;
    int4 td = tiles[bt];
    int mask = td.x, p_start = td.y, lt = td.z, cntb = td.w;
    if (tid < 128) {
        int li = lt + (tid >> 2);
        int pid = perm_par[p_start + ((li < cntb) ? li : 0)];
        int i = perm_rows[pid * 4 + (tid & 3)];
        unsigned fb = (flagbits[i >> 5] >> (i & 31)) & 1u;
        srows[tid] = i | (int)(fb << 30);
    } else if (tid < 192) {
        int cc = tid - 128;
        float inv = 1.0f / (float)n2;
        float mean = stats[cc] * inv;
        float var = stats[64 + cc] * inv - mean * mean;
        float s = gamma[cc] * rsqrtf(var + 1e-5f);
        scs[cc] = s; shs[cc] = beta[cc] - mean * s;
    } else if (tid < 256) {
        int cc = tid - 192;
        bs[cc] = 0.f; bq[cc] = 0.f;
    }
    __syncthreads();
    #pragma unroll
    for (int it = 0; it < 2; ++it) {
        int c0 = it * 512 + tid;
        int pl = c0 >> 5, w8 = c0 & 31;
        int j = w8 >> 3, col8 = w8 & 7;
        const float* fr = y1 + (size_t)(srows[pl * 4 + j] & ROWM) * 64 + col8 * 8;
        float4 f0 = *(const float4*)fr;
        float4 f1v = *(const float4*)(fr + 4);
        short o[8];
        #pragma unroll
        for (int u = 0; u < 4; ++u) {
            int cc = col8 * 8 + u;
            float v = (u == 0) ? f0.x : (u == 1) ? f0.y : (u == 2) ? f0.z : f0.w;
            o[u] = f2bf(fmaxf(v * scs[cc] + shs[cc], 0.f));
        }
        #pragma unroll
        for (int u = 0; u < 4; ++u) {
            int cc = col8 * 8 + 4 + u;
            float v = (u == 0) ? f1v.x : (u == 1) ? f1v.y : (u == 2) ? f1v.z : f1v.w;
            o[4 + u] = f2bf(fmaxf(v * scs[cc] + shs[cc], 0.f));
        }
        short* d = &lds[pl * LP + j * 64 + col8 * 8];
        *(int2*)d = make_int2(((int)(unsigned short)o[0]) | ((int)o[1] << 16),
                              ((int)(unsigned short)o[2]) | ((int)o[3] << 16));
        *(int2*)(d + 4) = make_int2(((int)(unsigned short)o[4]) | ((int)o[5] << 16),
                                    ((int)(unsigned short)o[6]) | ((int)o[7] << 16));
    }
    int p0 = -1, p1 = -1, p2 = -1, p3 = -1;
    #pragma unroll
    for (int b = 7; b >= 0; --b)
        if ((mask >> b) & 1) { p3 = p2; p2 = p1; p1 = p0; p0 = b; }
    int w = tid >> 6, lane = tid & 63;
    int asub = w >> 1, ch = w & 1;
    int pa = (asub == 0) ? p0 : (asub == 1) ? p1 : (asub == 2) ? p2 : p3;
    int t0 = tap27(pa, p0), t1 = tap27(pa, p1), t2 = tap27(pa, p2), t3 = tap27(pa, p3);
    int m = lane & 31, half = lane >> 5;
    int li = lt + m;
    bool vp = li < cntb;
    int outrow = vp ? srows[m * 4 + asub] : -1;
    __syncthreads();
    f32x16 acc;
    #pragma unroll
    for (int i = 0; i < 16; ++i) acc[i] = 0.f;
    const bf16x8* bp = (const bf16x8*)wp;
    __builtin_amdgcn_s_setprio(1);
    #pragma unroll
    for (int b = 0; b < 4; ++b) {
        int tb = (b == 0) ? t0 : (b == 1) ? t1 : (b == 2) ? t2 : t3;
        #pragma unroll
        for (int kk = 0; kk < 4; ++kk) {
            int ks = b * 4 + kk;
            const short* ap = &lds[m * LP + ks * 16 + half * 8];
            bf16x4 lo = *(const bf16x4*)ap, hi = *(const bf16x4*)(ap + 4);
            bf16x8 a = __builtin_shufflevector(lo, hi, 0, 1, 2, 3, 4, 5, 6, 7);
            bf16x8 b0 = bp[((size_t)(tb * 4 + kk) * 2 + ch) * 64 + lane];
            acc = __builtin_amdgcn_mfma_f32_32x32x16_bf16(a, b0, acc, 0, 0, 0);
        }
    }
    __builtin_amdgcn_s_setprio(0);
    pair_epi1(acc, outrow, lane, ch, y, bs, bq);
    __syncthreads();
    if (tid < 64) {
        atomicAdd(&ostats[tid], bs[tid]);
        atomicAdd(&ostats[64 + tid], bq[tid]);
    }
}

// ---------------- BN finalize + ReLU -> f32 output ---------------------------
__global__ __launch_bounds__(256) void k_final(
    const float* __restrict__ y, const float* __restrict__ gamma,
    const float* __restrict__ beta, const float* __restrict__ stats,
    float* __restrict__ out, int n2)
{
    __shared__ float sc[64], sh[64];
    int tid = threadIdx.x;
    if (tid < 64) {
        float inv = 1.0f / (float)n2;
        float mean = stats[tid] * inv;
        float var = stats[64 + tid] * inv - mean * mean;
        float s = gamma[tid] * rsqrtf(var + 1e-5f);
        sc[tid] = s;
        sh[tid] = beta[tid] - mean * s;
    }
    __syncthreads();
    long long total = (long long)n2 * 16;
    long long stride = (long long)gridDim.x * blockDim.x;
    for (long long idx = (long long)blockIdx.x * blockDim.x + tid; idx < total; idx += stride) {
        int i = (int)(idx >> 4);
        int c4 = ((int)idx & 15) * 4;
        const float* src = y + (size_t)i * 64 + c4;
        float4 o;
        o.x = fmaxf(src[0] * sc[c4 + 0] + sh[c4 + 0], 0.f);
        o.y = fmaxf(src[1] * sc[c4 + 1] + sh[c4 + 1], 0.f);
        o.z = fmaxf(src[2] * sc[c4 + 2] + sh[c4 + 2], 0.f);
        o.w = fmaxf(src[3] * sc[c4 + 3] + sh[c4 + 3], 0.f);
        *(float4*)(out + (size_t)i * 64 + c4) = o;
    }
}

extern "C" void kernel_launch(void* const* d_in, const int* in_sizes, int n_in,
                              void* d_out, int out_size, void* d_ws, size_t ws_size,
                              hipStream_t stream)
{
    const float* feats1   = (const float*)d_in[0];
    const float* feats2   = (const float*)d_in[1];
    const float* w_up     = (const float*)d_in[2];
    const float* gamma_up = (const float*)d_in[3];
    const float* beta_up  = (const float*)d_in[4];
    const float* w1       = (const float*)d_in[5];
    const float* gamma1   = (const float*)d_in[6];
    const float* beta1    = (const float*)d_in[7];
    const float* w2       = (const float*)d_in[8];
    const float* gamma2   = (const float*)d_in[9];
    const float* beta2    = (const float*)d_in[10];
    const int* up_src     = (const int*)d_in[11];  (void)up_src;
    const int* up_kidx    = (const int*)d_in[12];
    const int* nbr_src    = (const int*)d_in[13];
    // d_in[14] nbr_dst unused: nbr_dst[t,i] ∈ {i, N2} by construction

    int n1 = in_sizes[0] / 128;
    int n2 = in_sizes[1] / 64;

    char* p = (char*)d_ws;
    auto alloc = [&](size_t bytes) {
        char* r = p;
        p += (bytes + 255) & ~(size_t)255;
        return r;
    };
    float* stats    = (float*)alloc(384 * 4);
    int*   cnt      = (int*)alloc(256 * 4);
    int*   extc     = (int*)alloc(16);
    int*   ntl      = (int*)alloc(16);
    unsigned* flagbits = (unsigned*)alloc(((size_t)(n2 + 31) / 32) * 4);
    size_t headBytes = (size_t)(p - (char*)d_ws);
    int maxTiles    = (n1 + 31) / 32 + 80;
    int4*  tiles    = (int4*)alloc((size_t)maxTiles * 16);
    short* wupp     = (short*)alloc((size_t)65536 * 2);
    short* w1p      = (short*)alloc((size_t)221184 * 2);
    short* w2p      = (short*)alloc((size_t)110592 * 2);
    int*   pmask    = (int*)alloc((size_t)n1 * 4);
    int*   rank     = (int*)alloc((size_t)n1 * 4);
    int*   perm_par = (int*)alloc((size_t)n1 * 4);
    int*   perm_rows= (int*)alloc((size_t)4 * n1 * 4);
    int2*  ext      = (int2*)alloc((size_t)27 * n2 * 8);
    short* yup8     = (short*)alloc((size_t)n1 * 512 * 2);
    float* y1       = (float*)alloc((size_t)n2 * 64 * 4);
    float* y2       = (float*)alloc((size_t)n2 * 64 * 4);

    int nbGeom = (n1 + 255) / 256;
    int nbPack = 32;                           // 8192 wupp groups only
    int nbSetup = nbGeom + nbPack;
    int nt = (n1 + 31) / 32;
    int nbExt2 = (n2 + 511) / 512;             // ext-scan: 2 chunks/block
    int upBlocks = 1 + 2 * nt + 128 + 64 + nbExt2;
    const int EXTB = 128;   // R17 optimum: 658 total pair blocks, co-resident

    hipMemsetAsync(d_ws, 0, headBytes, stream);
    k_setup<<<nbSetup, 256, 0, stream>>>(w_up, up_kidx, wupp,
                                         pmask, perm_rows, rank, cnt,
                                         n1, nbGeom);
    k_up<<<upBlocks, 256, 0, stream>>>(feats1, wupp, pmask, cnt, rank, perm_par,
                                       tiles, ntl, yup8, stats,
                                       w1, w2, w1p, w2p, nbr_src, ext, extc,
                                       flagbits, y1, y2, n1, n2, nt);
    k_pairA<<<EXTB + maxTiles, 512, 0, stream>>>(yup8, feats2, up_kidx, w1p,
                                                 gamma_up, beta_up, stats,
                                                 perm_par, perm_rows, tiles, ntl,
                                                 ext, extc, flagbits,
                                                 y1, stats + 128, n2, EXTB);
    k_pairB<<<EXTB + maxTiles, 512, 0, stream>>>(y1, w2p, gamma1, beta1,
                                                 stats + 128, perm_par,
                                                 perm_rows, tiles, ntl,
                                                 ext, extc, flagbits,
                                                 y2, stats + 256, n2, EXTB);
    k_final<<<1024, 256, 0, stream>>>(y2, gamma2, beta2, stats + 256,
                                      (float*)d_out, n2);
}